// Round 1
// baseline (2973.325 us; speedup 1.0000x reference)
//
#include <hip/hip_runtime.h>
#include <math.h>

#define N_NODES 10000
#define N_EDGES 160000
#define N_GRAPHS 64
#define D_INPUT 128
#define D_H 512
#define EPS 1e-7f
#define MAXV 10.0f
#define BN_EPS 1e-5f

// ---------------- degree (once) ----------------
__global__ void deg_kernel(const int* __restrict__ dst, float* __restrict__ deg) {
  int i = blockIdx.x * blockDim.x + threadIdx.x;
  if (i < N_EDGES) atomicAdd(&deg[dst[i]], 1.0f);
}

// ---------------- edge gather + scatter-add ----------------
// one wave (64 lanes) per edge; float4 per lane
__global__ __launch_bounds__(256) void edge_kernel(
    const float* __restrict__ h, const int* __restrict__ src,
    const int* __restrict__ dst, const float* __restrict__ p_ptr,
    float* __restrict__ agg, int d) {
  float p = *p_ptr;
  bool p1 = (p == 1.0f);
  int gtid = blockIdx.x * blockDim.x + threadIdx.x;
  int wave = gtid >> 6;
  int lane = threadIdx.x & 63;
  int nw = (gridDim.x * blockDim.x) >> 6;
  int nvec = d >> 2;
  for (int e = wave; e < N_EDGES; e += nw) {
    int s = src[e], t = dst[e];
    const float4* hs = (const float4*)(h + (size_t)s * d);
    float* at = agg + (size_t)t * d;
    for (int v = lane; v < nvec; v += 64) {
      float4 x = hs[v];
      float m0 = fminf(fmaxf(x.x, 0.f) + EPS, MAXV);
      float m1 = fminf(fmaxf(x.y, 0.f) + EPS, MAXV);
      float m2 = fminf(fmaxf(x.z, 0.f) + EPS, MAXV);
      float m3 = fminf(fmaxf(x.w, 0.f) + EPS, MAXV);
      if (!p1) { m0 = powf(m0, p); m1 = powf(m1, p); m2 = powf(m2, p); m3 = powf(m3, p); }
      atomicAdd(at + 4 * v + 0, m0);
      atomicAdd(at + 4 * v + 1, m1);
      atomicAdd(at + 4 * v + 2, m2);
      atomicAdd(at + 4 * v + 3, m3);
    }
  }
}

// ---------------- per-node message norm + residual ----------------
__global__ __launch_bounds__(256) void msgnorm_kernel(
    const float* __restrict__ h, const float* __restrict__ agg,
    const float* __restrict__ deg, const float* __restrict__ p_ptr,
    const float* __restrict__ scale_ptr, float* __restrict__ out, int d) {
  int n = blockIdx.x;
  int tid = threadIdx.x;
  float p = *p_ptr;
  float scale = *scale_ptr;
  float invp = 1.0f / p;
  bool p1 = (p == 1.0f);
  float inv_dg = 1.0f / fmaxf(deg[n], 1.0f);
  const float* hn = h + (size_t)n * d;
  const float* an = agg + (size_t)n * d;
  float sa = 0.f, sh = 0.f;
  for (int c = tid; c < d; c += 256) {
    float a = an[c] * inv_dg;
    a = fminf(fmaxf(a, EPS), MAXV);
    if (!p1) a = powf(a, invp);
    sa += a * a;
    float hv = hn[c];
    sh += hv * hv;
  }
  for (int off = 32; off; off >>= 1) {
    sa += __shfl_down(sa, off);
    sh += __shfl_down(sh, off);
  }
  __shared__ float red[2][4];
  __shared__ float tot[2];
  int wid = tid >> 6;
  if ((tid & 63) == 0) { red[0][wid] = sa; red[1][wid] = sh; }
  __syncthreads();
  if (tid == 0) {
    tot[0] = red[0][0] + red[0][1] + red[0][2] + red[0][3];
    tot[1] = red[1][0] + red[1][1] + red[1][2] + red[1][3];
  }
  __syncthreads();
  float norm_a = fmaxf(sqrtf(tot[0]), 1e-12f);
  float k = sqrtf(tot[1]) * scale / norm_a;
  for (int c = tid; c < d; c += 256) {
    float a = an[c] * inv_dg;
    a = fminf(fmaxf(a, EPS), MAXV);
    if (!p1) a = powf(a, invp);
    out[(size_t)n * d + c] = hn[c] + a * k;
  }
}

// ---------------- tiled fp32 matmul + bias: C[N,512] = A[N,K] @ W[K,512] + b ----------------
#define BM 64
#define BN 64
#define BK 16
__global__ __launch_bounds__(256) void matmul_bias(
    const float* __restrict__ A, const float* __restrict__ W,
    const float* __restrict__ bias, float* __restrict__ C, int N, int K) {
  __shared__ float As[BK][BM + 4];
  __shared__ float Ws[BK][BN + 4];
  int tid = threadIdx.x;
  int tx = tid & 15, ty = tid >> 4;
  int row0 = blockIdx.x * BM, col0 = blockIdx.y * BN;
  float acc[4][4] = {};
  int la_r = tid >> 2;
  int la_k = (tid & 3) * 4;
  int lw_k = tid >> 4;
  int lw_n = (tid & 15) * 4;
  for (int k0 = 0; k0 < K; k0 += BK) {
    int ar = row0 + la_r;
    float4 av = make_float4(0.f, 0.f, 0.f, 0.f);
    if (ar < N) av = *(const float4*)(A + (size_t)ar * K + k0 + la_k);
    As[la_k + 0][la_r] = av.x;
    As[la_k + 1][la_r] = av.y;
    As[la_k + 2][la_r] = av.z;
    As[la_k + 3][la_r] = av.w;
    float4 wv = *(const float4*)(W + (size_t)(k0 + lw_k) * D_H + col0 + lw_n);
    *(float4*)&Ws[lw_k][lw_n] = wv;
    __syncthreads();
#pragma unroll
    for (int kk = 0; kk < BK; kk++) {
      float a0 = As[kk][ty * 4 + 0], a1 = As[kk][ty * 4 + 1];
      float a2 = As[kk][ty * 4 + 2], a3 = As[kk][ty * 4 + 3];
      float w0 = Ws[kk][tx * 4 + 0], w1 = Ws[kk][tx * 4 + 1];
      float w2 = Ws[kk][tx * 4 + 2], w3 = Ws[kk][tx * 4 + 3];
      acc[0][0] += a0 * w0; acc[0][1] += a0 * w1; acc[0][2] += a0 * w2; acc[0][3] += a0 * w3;
      acc[1][0] += a1 * w0; acc[1][1] += a1 * w1; acc[1][2] += a1 * w2; acc[1][3] += a1 * w3;
      acc[2][0] += a2 * w0; acc[2][1] += a2 * w1; acc[2][2] += a2 * w2; acc[2][3] += a2 * w3;
      acc[3][0] += a3 * w0; acc[3][1] += a3 * w1; acc[3][2] += a3 * w2; acc[3][3] += a3 * w3;
    }
    __syncthreads();
  }
#pragma unroll
  for (int i = 0; i < 4; i++) {
    int row = row0 + ty * 4 + i;
    if (row < N) {
#pragma unroll
      for (int j = 0; j < 4; j++) {
        int col = col0 + tx * 4 + j;
        C[(size_t)row * D_H + col] = acc[i][j] + bias[col];
      }
    }
  }
}

// ---------------- per-column batch stats (sum, sumsq) ----------------
__global__ __launch_bounds__(256) void col_stats(const float* __restrict__ x,
                                                 float* __restrict__ stats, int N) {
  int tid = threadIdx.x;
  int rpb = (N + gridDim.x - 1) / gridDim.x;
  int r0 = blockIdx.x * rpb;
  int r1 = min(N, r0 + rpb);
  float s0 = 0.f, q0 = 0.f, s1 = 0.f, q1 = 0.f;
  for (int r = r0; r < r1; r++) {
    float a = x[(size_t)r * D_H + tid];
    float b = x[(size_t)r * D_H + tid + 256];
    s0 += a; q0 += a * a;
    s1 += b; q1 += b * b;
  }
  atomicAdd(&stats[tid], s0);
  atomicAdd(&stats[D_H + tid], q0);
  atomicAdd(&stats[tid + 256], s1);
  atomicAdd(&stats[D_H + tid + 256], q1);
}

// ---------------- BN + ReLU + JK-max ----------------
__global__ __launch_bounds__(256) void bn_relu_jk(
    const float* __restrict__ x, const float* __restrict__ stats,
    const float* __restrict__ gamma, const float* __restrict__ beta,
    float* __restrict__ h, float* __restrict__ jk, int layer) {
  const float invN = 1.0f / (float)N_NODES;
  int total = N_NODES * D_H;
  for (int idx = blockIdx.x * blockDim.x + threadIdx.x; idx < total;
       idx += gridDim.x * blockDim.x) {
    int c = idx & (D_H - 1);
    float mean = stats[c] * invN;
    float var = stats[D_H + c] * invN - mean * mean;
    float v = (x[idx] - mean) * rsqrtf(var + BN_EPS) * gamma[c] + beta[c];
    v = fmaxf(v, 0.f);
    h[idx] = v;
    jk[idx] = (layer == 0) ? v : fmaxf(jk[idx], v);
  }
}

// ---------------- per-graph max+mean pooling (batch sorted) ----------------
__device__ __forceinline__ int lower_bound_i(const int* a, int n, int v) {
  int lo = 0, hi = n;
  while (lo < hi) {
    int mid = (lo + hi) >> 1;
    if (a[mid] < v) lo = mid + 1; else hi = mid;
  }
  return lo;
}

__global__ __launch_bounds__(256) void pool_kernel(const float* __restrict__ jk,
                                                   const int* __restrict__ batch,
                                                   float* __restrict__ g) {
  int gid = blockIdx.x;
  __shared__ int s_lo, s_hi;
  if (threadIdx.x == 0) {
    s_lo = lower_bound_i(batch, N_NODES, gid);
    s_hi = lower_bound_i(batch, N_NODES, gid + 1);
  }
  __syncthreads();
  int lo = s_lo, hi = s_hi;
  float inv_cnt = 1.0f / fmaxf((float)(hi - lo), 1.0f);
  for (int c = threadIdx.x; c < D_H; c += 256) {
    float mx = 0.f, sm = 0.f;
    for (int r = lo; r < hi; r++) {
      float v = jk[(size_t)r * D_H + c];
      mx = fmaxf(mx, v);
      sm += v;
    }
    g[(size_t)gid * 1024 + c] = (hi > lo) ? mx : 0.f;
    g[(size_t)gid * 1024 + D_H + c] = sm * inv_cnt;
  }
}

// ---------------- fc1: [64,1024] @ [1024,512] + b ----------------
__global__ __launch_bounds__(512) void fc1_kernel(const float* __restrict__ g,
                                                  const float* __restrict__ W,
                                                  const float* __restrict__ b,
                                                  float* __restrict__ out) {
  __shared__ float sg[1024];
  int gid = blockIdx.x;
  for (int i = threadIdx.x; i < 1024; i += 512) sg[i] = g[(size_t)gid * 1024 + i];
  __syncthreads();
  int c = threadIdx.x;
  float acc = b[c];
  for (int k = 0; k < 1024; k++) acc += sg[k] * W[(size_t)k * D_H + c];
  out[(size_t)gid * D_H + c] = acc;
}

// ---------------- BN over 64 graphs + ReLU ----------------
__global__ __launch_bounds__(256) void bn4_kernel(const float* __restrict__ x,
                                                  const float* __restrict__ gmm,
                                                  const float* __restrict__ bb,
                                                  float* __restrict__ y) {
  int c = blockIdx.x * blockDim.x + threadIdx.x;
  if (c >= D_H) return;
  float s = 0.f, q = 0.f;
  for (int r = 0; r < N_GRAPHS; r++) {
    float v = x[(size_t)r * D_H + c];
    s += v; q += v * v;
  }
  float mean = s / (float)N_GRAPHS;
  float var = q / (float)N_GRAPHS - mean * mean;
  float rs = rsqrtf(var + BN_EPS) * gmm[c];
  for (int r = 0; r < N_GRAPHS; r++) {
    float v = (x[(size_t)r * D_H + c] - mean) * rs + bb[c];
    y[(size_t)r * D_H + c] = fmaxf(v, 0.f);
  }
}

// ---------------- fc2: [64,512] @ [512,2] + b ----------------
__global__ __launch_bounds__(64) void fc2_kernel(const float* __restrict__ y,
                                                 const float* __restrict__ W,
                                                 const float* __restrict__ b,
                                                 float* __restrict__ out) {
  int gid = blockIdx.x;
  int lane = threadIdx.x;
  float a0 = 0.f, a1 = 0.f;
  for (int k = lane; k < D_H; k += 64) {
    float v = y[(size_t)gid * D_H + k];
    a0 += v * W[k * 2 + 0];
    a1 += v * W[k * 2 + 1];
  }
  for (int off = 32; off; off >>= 1) {
    a0 += __shfl_down(a0, off);
    a1 += __shfl_down(a1, off);
  }
  if (lane == 0) {
    out[gid * 2 + 0] = a0 + b[0];
    out[gid * 2 + 1] = a1 + b[1];
  }
}

extern "C" void kernel_launch(void* const* d_in, const int* in_sizes, int n_in,
                              void* d_out, int out_size, void* d_ws, size_t ws_size,
                              hipStream_t stream) {
  const float* x       = (const float*)d_in[0];
  const float* W0      = (const float*)d_in[1];
  const float* Wrest   = (const float*)d_in[2];
  const float* bconv   = (const float*)d_in[3];
  const float* p       = (const float*)d_in[4];
  const float* mscale  = (const float*)d_in[5];
  const float* bn_g    = (const float*)d_in[6];
  const float* bn_b    = (const float*)d_in[7];
  const float* fc1_W   = (const float*)d_in[8];
  const float* fc1_b   = (const float*)d_in[9];
  const float* bn4_g   = (const float*)d_in[10];
  const float* bn4_b   = (const float*)d_in[11];
  const float* fc2_W   = (const float*)d_in[12];
  const float* fc2_b   = (const float*)d_in[13];
  const int*   eidx    = (const int*)d_in[14];
  const int*   batch   = (const int*)d_in[15];
  float* out = (float*)d_out;

  const int* src = eidx;
  const int* dst = eidx + N_EDGES;

  float* ws = (float*)d_ws;
  const size_t NH = (size_t)N_NODES * D_H;
  float* agg   = ws;            // also used as matmul output (hlin)
  float* resid = agg + NH;
  float* hbuf  = resid + NH;
  float* jk    = hbuf + NH;
  float* deg   = jk + NH;                 // N_NODES
  float* stats = deg + N_NODES;           // 1024
  float* g     = stats + 1024;            // 64*1024
  float* g2lin = g + 64 * 1024;           // 64*512
  float* g2    = g2lin + 64 * D_H;        // 64*512

  // degree (once)
  hipMemsetAsync(deg, 0, N_NODES * sizeof(float), stream);
  deg_kernel<<<(N_EDGES + 255) / 256, 256, 0, stream>>>(dst, deg);

  const float* h_cur = x;
  int d = D_INPUT;
  for (int layer = 0; layer < 3; layer++) {
    hipMemsetAsync(agg, 0, NH * sizeof(float), stream);
    edge_kernel<<<2048, 256, 0, stream>>>(h_cur, src, dst, p + layer, agg, d);
    msgnorm_kernel<<<N_NODES, 256, 0, stream>>>(h_cur, agg, deg, p + layer,
                                                mscale + layer, resid, d);
    const float* W = (layer == 0) ? W0 : (Wrest + (size_t)(layer - 1) * D_H * D_H);
    // matmul writes into agg (reused as hlin); agg no longer needed this layer
    matmul_bias<<<dim3((N_NODES + BM - 1) / BM, D_H / BN), 256, 0, stream>>>(
        resid, W, bconv + (size_t)layer * D_H, agg, N_NODES, d);
    hipMemsetAsync(stats, 0, 1024 * sizeof(float), stream);
    col_stats<<<64, 256, 0, stream>>>(agg, stats, N_NODES);
    bn_relu_jk<<<4096, 256, 0, stream>>>(agg, stats, bn_g + (size_t)layer * D_H,
                                         bn_b + (size_t)layer * D_H, hbuf, jk, layer);
    h_cur = hbuf;
    d = D_H;
  }

  pool_kernel<<<N_GRAPHS, 256, 0, stream>>>(jk, batch, g);
  fc1_kernel<<<N_GRAPHS, 512, 0, stream>>>(g, fc1_W, fc1_b, g2lin);
  bn4_kernel<<<2, 256, 0, stream>>>(g2lin, bn4_g, bn4_b, g2);
  fc2_kernel<<<N_GRAPHS, 64, 0, stream>>>(g2, fc2_W, fc2_b, out);
}

// Round 2
// 677.564 us; speedup vs baseline: 4.3883x; 4.3883x over previous
//
#include <hip/hip_runtime.h>
#include <math.h>

#define N_NODES 10000
#define N_EDGES 160000
#define N_GRAPHS 64
#define D_INPUT 128
#define D_H 512
#define EPS 1e-7f
#define MAXV 10.0f
#define BN_EPS 1e-5f

// ================= CSR build =================
__global__ __launch_bounds__(256) void hist_kernel(const int* __restrict__ dst,
                                                   int* __restrict__ cnt) {
  int i = blockIdx.x * blockDim.x + threadIdx.x;
  if (i < N_EDGES) atomicAdd(&cnt[dst[i]], 1);
}

// single-block exclusive scan over 10000 counts -> rowptr[0..N], rowptr[N]=E
__global__ __launch_bounds__(256) void scan_kernel(const int* __restrict__ cnt,
                                                   int* __restrict__ rowptr) {
  __shared__ int ps[256];
  int tid = threadIdx.x;
  const int CH = (N_NODES + 255) / 256;  // 40
  int b0 = tid * CH;
  int b1 = min(N_NODES, b0 + CH);
  int s = 0;
  for (int i = b0; i < b1; i++) s += cnt[i];
  ps[tid] = s;
  __syncthreads();
  // Hillis-Steele inclusive scan
  for (int off = 1; off < 256; off <<= 1) {
    int v = (tid >= off) ? ps[tid - off] : 0;
    __syncthreads();
    ps[tid] += v;
    __syncthreads();
  }
  int run = (tid == 0) ? 0 : ps[tid - 1];
  for (int i = b0; i < b1; i++) {
    rowptr[i] = run;
    run += cnt[i];
  }
  if (tid == 255) rowptr[N_NODES] = run;
}

__global__ __launch_bounds__(256) void scatter_kernel(
    const int* __restrict__ src, const int* __restrict__ dst,
    const int* __restrict__ rowptr, int* __restrict__ cursor,
    int* __restrict__ csr_src) {
  int i = blockIdx.x * blockDim.x + threadIdx.x;
  if (i < N_EDGES) {
    int t = dst[i];
    int pos = rowptr[t] + atomicAdd(&cursor[t], 1);
    csr_src[pos] = src[i];
  }
}

// ============ fused: CSR aggregation + power-mean + MessageNorm + residual ============
// one block per node; 256 threads; each thread owns float2 columns
template <int D>
__global__ __launch_bounds__(256) void agg_msgnorm_kernel(
    const float* __restrict__ h, const int* __restrict__ rowptr,
    const int* __restrict__ csr_src, const float* __restrict__ p_ptr,
    const float* __restrict__ scale_ptr, float* __restrict__ out) {
  constexpr int C = D / 2;  // float2 columns per row (64 or 256)
  int n = blockIdx.x;
  int tid = threadIdx.x;
  int lo = rowptr[n], hi = rowptr[n + 1];
  float p = *p_ptr;
  float scale = *scale_ptr;
  bool p1 = (p == 1.0f);
  float invp = 1.0f / p;
  float inv_dg = 1.0f / fmaxf((float)(hi - lo), 1.0f);
  const float2* h2 = (const float2*)h;

  __shared__ int s_src[256];
  float accx = 0.f, accy = 0.f;
  for (int base = lo; base < hi; base += 256) {
    int m = min(256, hi - base);
    __syncthreads();
    if (tid < m) s_src[tid] = csr_src[base + tid];
    __syncthreads();
    if (tid < C) {
      for (int j = 0; j < m; j++) {
        float2 x = h2[(size_t)s_src[j] * C + tid];
        float m0 = fminf(fmaxf(x.x, 0.f) + EPS, MAXV);
        float m1 = fminf(fmaxf(x.y, 0.f) + EPS, MAXV);
        if (!p1) { m0 = powf(m0, p); m1 = powf(m1, p); }
        accx += m0;
        accy += m1;
      }
    }
  }

  // finalize power-mean + gather norms
  float a0 = 0.f, a1 = 0.f, hv0 = 0.f, hv1 = 0.f, sa = 0.f, sh = 0.f;
  if (tid < C) {
    a0 = fminf(fmaxf(accx * inv_dg, EPS), MAXV);
    a1 = fminf(fmaxf(accy * inv_dg, EPS), MAXV);
    if (!p1) { a0 = powf(a0, invp); a1 = powf(a1, invp); }
    float2 hx = h2[(size_t)n * C + tid];
    hv0 = hx.x;
    hv1 = hx.y;
    sa = a0 * a0 + a1 * a1;
    sh = hv0 * hv0 + hv1 * hv1;
  }
  for (int off = 32; off; off >>= 1) {
    sa += __shfl_down(sa, off);
    sh += __shfl_down(sh, off);
  }
  __shared__ float red[2][4];
  __shared__ float tot[2];
  int wid = tid >> 6;
  if ((tid & 63) == 0) { red[0][wid] = sa; red[1][wid] = sh; }
  __syncthreads();
  if (tid == 0) {
    tot[0] = red[0][0] + red[0][1] + red[0][2] + red[0][3];
    tot[1] = red[1][0] + red[1][1] + red[1][2] + red[1][3];
  }
  __syncthreads();
  float k = sqrtf(tot[1]) * scale / fmaxf(sqrtf(tot[0]), 1e-12f);
  if (tid < C) {
    float2 o;
    o.x = hv0 + a0 * k;
    o.y = hv1 + a1 * k;
    ((float2*)out)[(size_t)n * C + tid] = o;
  }
}

// ---------------- tiled fp32 matmul + bias: C[N,512] = A[N,K] @ W[K,512] + b ----------------
#define BM 64
#define BN 64
#define BK 16
__global__ __launch_bounds__(256) void matmul_bias(
    const float* __restrict__ A, const float* __restrict__ W,
    const float* __restrict__ bias, float* __restrict__ C, int N, int K) {
  __shared__ float As[BK][BM + 4];
  __shared__ float Ws[BK][BN + 4];
  int tid = threadIdx.x;
  int tx = tid & 15, ty = tid >> 4;
  int row0 = blockIdx.x * BM, col0 = blockIdx.y * BN;
  float acc[4][4] = {};
  int la_r = tid >> 2;
  int la_k = (tid & 3) * 4;
  int lw_k = tid >> 4;
  int lw_n = (tid & 15) * 4;
  for (int k0 = 0; k0 < K; k0 += BK) {
    int ar = row0 + la_r;
    float4 av = make_float4(0.f, 0.f, 0.f, 0.f);
    if (ar < N) av = *(const float4*)(A + (size_t)ar * K + k0 + la_k);
    As[la_k + 0][la_r] = av.x;
    As[la_k + 1][la_r] = av.y;
    As[la_k + 2][la_r] = av.z;
    As[la_k + 3][la_r] = av.w;
    float4 wv = *(const float4*)(W + (size_t)(k0 + lw_k) * D_H + col0 + lw_n);
    *(float4*)&Ws[lw_k][lw_n] = wv;
    __syncthreads();
#pragma unroll
    for (int kk = 0; kk < BK; kk++) {
      float a0 = As[kk][ty * 4 + 0], a1 = As[kk][ty * 4 + 1];
      float a2 = As[kk][ty * 4 + 2], a3 = As[kk][ty * 4 + 3];
      float w0 = Ws[kk][tx * 4 + 0], w1 = Ws[kk][tx * 4 + 1];
      float w2 = Ws[kk][tx * 4 + 2], w3 = Ws[kk][tx * 4 + 3];
      acc[0][0] += a0 * w0; acc[0][1] += a0 * w1; acc[0][2] += a0 * w2; acc[0][3] += a0 * w3;
      acc[1][0] += a1 * w0; acc[1][1] += a1 * w1; acc[1][2] += a1 * w2; acc[1][3] += a1 * w3;
      acc[2][0] += a2 * w0; acc[2][1] += a2 * w1; acc[2][2] += a2 * w2; acc[2][3] += a2 * w3;
      acc[3][0] += a3 * w0; acc[3][1] += a3 * w1; acc[3][2] += a3 * w2; acc[3][3] += a3 * w3;
    }
    __syncthreads();
  }
#pragma unroll
  for (int i = 0; i < 4; i++) {
    int row = row0 + ty * 4 + i;
    if (row < N) {
#pragma unroll
      for (int j = 0; j < 4; j++) {
        int col = col0 + tx * 4 + j;
        C[(size_t)row * D_H + col] = acc[i][j] + bias[col];
      }
    }
  }
}

// ---------------- per-column batch stats (sum, sumsq) ----------------
__global__ __launch_bounds__(256) void col_stats(const float* __restrict__ x,
                                                 float* __restrict__ stats, int N) {
  int tid = threadIdx.x;
  int rpb = (N + gridDim.x - 1) / gridDim.x;
  int r0 = blockIdx.x * rpb;
  int r1 = min(N, r0 + rpb);
  float s0 = 0.f, q0 = 0.f, s1 = 0.f, q1 = 0.f;
  for (int r = r0; r < r1; r++) {
    float a = x[(size_t)r * D_H + tid];
    float b = x[(size_t)r * D_H + tid + 256];
    s0 += a; q0 += a * a;
    s1 += b; q1 += b * b;
  }
  atomicAdd(&stats[tid], s0);
  atomicAdd(&stats[D_H + tid], q0);
  atomicAdd(&stats[tid + 256], s1);
  atomicAdd(&stats[D_H + tid + 256], q1);
}

// ---------------- BN + ReLU + JK-max ----------------
__global__ __launch_bounds__(256) void bn_relu_jk(
    const float* __restrict__ x, const float* __restrict__ stats,
    const float* __restrict__ gamma, const float* __restrict__ beta,
    float* __restrict__ h, float* __restrict__ jk, int layer) {
  const float invN = 1.0f / (float)N_NODES;
  int total = N_NODES * D_H;
  for (int idx = blockIdx.x * blockDim.x + threadIdx.x; idx < total;
       idx += gridDim.x * blockDim.x) {
    int c = idx & (D_H - 1);
    float mean = stats[c] * invN;
    float var = stats[D_H + c] * invN - mean * mean;
    float v = (x[idx] - mean) * rsqrtf(var + BN_EPS) * gamma[c] + beta[c];
    v = fmaxf(v, 0.f);
    h[idx] = v;
    jk[idx] = (layer == 0) ? v : fmaxf(jk[idx], v);
  }
}

// ---------------- per-graph max+mean pooling (batch sorted) ----------------
__device__ __forceinline__ int lower_bound_i(const int* a, int n, int v) {
  int lo = 0, hi = n;
  while (lo < hi) {
    int mid = (lo + hi) >> 1;
    if (a[mid] < v) lo = mid + 1; else hi = mid;
  }
  return lo;
}

__global__ __launch_bounds__(256) void pool_kernel(const float* __restrict__ jk,
                                                   const int* __restrict__ batch,
                                                   float* __restrict__ g) {
  int gid = blockIdx.x;
  __shared__ int s_lo, s_hi;
  if (threadIdx.x == 0) {
    s_lo = lower_bound_i(batch, N_NODES, gid);
    s_hi = lower_bound_i(batch, N_NODES, gid + 1);
  }
  __syncthreads();
  int lo = s_lo, hi = s_hi;
  float inv_cnt = 1.0f / fmaxf((float)(hi - lo), 1.0f);
  for (int c = threadIdx.x; c < D_H; c += 256) {
    float mx = 0.f, sm = 0.f;
    for (int r = lo; r < hi; r++) {
      float v = jk[(size_t)r * D_H + c];
      mx = fmaxf(mx, v);
      sm += v;
    }
    g[(size_t)gid * 1024 + c] = (hi > lo) ? mx : 0.f;
    g[(size_t)gid * 1024 + D_H + c] = sm * inv_cnt;
  }
}

// ---------------- fc1: [64,1024] @ [1024,512] + b ----------------
__global__ __launch_bounds__(512) void fc1_kernel(const float* __restrict__ g,
                                                  const float* __restrict__ W,
                                                  const float* __restrict__ b,
                                                  float* __restrict__ out) {
  __shared__ float sg[1024];
  int gid = blockIdx.x;
  for (int i = threadIdx.x; i < 1024; i += 512) sg[i] = g[(size_t)gid * 1024 + i];
  __syncthreads();
  int c = threadIdx.x;
  float acc = b[c];
  for (int k = 0; k < 1024; k++) acc += sg[k] * W[(size_t)k * D_H + c];
  out[(size_t)gid * D_H + c] = acc;
}

// ---------------- BN over 64 graphs + ReLU ----------------
__global__ __launch_bounds__(256) void bn4_kernel(const float* __restrict__ x,
                                                  const float* __restrict__ gmm,
                                                  const float* __restrict__ bb,
                                                  float* __restrict__ y) {
  int c = blockIdx.x * blockDim.x + threadIdx.x;
  if (c >= D_H) return;
  float s = 0.f, q = 0.f;
  for (int r = 0; r < N_GRAPHS; r++) {
    float v = x[(size_t)r * D_H + c];
    s += v; q += v * v;
  }
  float mean = s / (float)N_GRAPHS;
  float var = q / (float)N_GRAPHS - mean * mean;
  float rs = rsqrtf(var + BN_EPS) * gmm[c];
  for (int r = 0; r < N_GRAPHS; r++) {
    float v = (x[(size_t)r * D_H + c] - mean) * rs + bb[c];
    y[(size_t)r * D_H + c] = fmaxf(v, 0.f);
  }
}

// ---------------- fc2: [64,512] @ [512,2] + b ----------------
__global__ __launch_bounds__(64) void fc2_kernel(const float* __restrict__ y,
                                                 const float* __restrict__ W,
                                                 const float* __restrict__ b,
                                                 float* __restrict__ out) {
  int gid = blockIdx.x;
  int lane = threadIdx.x;
  float a0 = 0.f, a1 = 0.f;
  for (int k = lane; k < D_H; k += 64) {
    float v = y[(size_t)gid * D_H + k];
    a0 += v * W[k * 2 + 0];
    a1 += v * W[k * 2 + 1];
  }
  for (int off = 32; off; off >>= 1) {
    a0 += __shfl_down(a0, off);
    a1 += __shfl_down(a1, off);
  }
  if (lane == 0) {
    out[gid * 2 + 0] = a0 + b[0];
    out[gid * 2 + 1] = a1 + b[1];
  }
}

extern "C" void kernel_launch(void* const* d_in, const int* in_sizes, int n_in,
                              void* d_out, int out_size, void* d_ws, size_t ws_size,
                              hipStream_t stream) {
  const float* x       = (const float*)d_in[0];
  const float* W0      = (const float*)d_in[1];
  const float* Wrest   = (const float*)d_in[2];
  const float* bconv   = (const float*)d_in[3];
  const float* p       = (const float*)d_in[4];
  const float* mscale  = (const float*)d_in[5];
  const float* bn_g    = (const float*)d_in[6];
  const float* bn_b    = (const float*)d_in[7];
  const float* fc1_W   = (const float*)d_in[8];
  const float* fc1_b   = (const float*)d_in[9];
  const float* bn4_g   = (const float*)d_in[10];
  const float* bn4_b   = (const float*)d_in[11];
  const float* fc2_W   = (const float*)d_in[12];
  const float* fc2_b   = (const float*)d_in[13];
  const int*   eidx    = (const int*)d_in[14];
  const int*   batch   = (const int*)d_in[15];
  float* out = (float*)d_out;

  const int* src = eidx;
  const int* dst = eidx + N_EDGES;

  float* ws = (float*)d_ws;
  const size_t NH = (size_t)N_NODES * D_H;
  float* resid = ws;
  float* hlin  = resid + NH;
  float* hbuf  = hlin + NH;
  float* jk    = hbuf + NH;
  float* stats = jk + NH;          // 1024
  float* tail  = stats + 1024;
  // CSR ints live in the tail during the conv phase...
  int* cnt     = (int*)tail;       // 10000 (also reused as scatter cursor)
  int* rowptr  = cnt + N_NODES;    // 10001
  int* csr_src = rowptr + N_NODES + 1;  // 160000
  // ...and the pooling/MLP buffers reuse the same tail afterwards (CSR dead by then)
  float* g     = tail;             // 64*1024
  float* g2lin = g + 64 * 1024;    // 64*512
  float* g2    = g2lin + 64 * D_H; // 64*512

  // ---- build CSR (deterministic work each call) ----
  hipMemsetAsync(cnt, 0, N_NODES * sizeof(int), stream);
  hist_kernel<<<(N_EDGES + 255) / 256, 256, 0, stream>>>(dst, cnt);
  scan_kernel<<<1, 256, 0, stream>>>(cnt, rowptr);
  hipMemsetAsync(cnt, 0, N_NODES * sizeof(int), stream);
  scatter_kernel<<<(N_EDGES + 255) / 256, 256, 0, stream>>>(src, dst, rowptr, cnt, csr_src);

  const float* h_cur = x;
  for (int layer = 0; layer < 3; layer++) {
    if (layer == 0)
      agg_msgnorm_kernel<D_INPUT><<<N_NODES, 256, 0, stream>>>(
          h_cur, rowptr, csr_src, p + layer, mscale + layer, resid);
    else
      agg_msgnorm_kernel<D_H><<<N_NODES, 256, 0, stream>>>(
          h_cur, rowptr, csr_src, p + layer, mscale + layer, resid);
    const float* W = (layer == 0) ? W0 : (Wrest + (size_t)(layer - 1) * D_H * D_H);
    int K = (layer == 0) ? D_INPUT : D_H;
    matmul_bias<<<dim3((N_NODES + BM - 1) / BM, D_H / BN), 256, 0, stream>>>(
        resid, W, bconv + (size_t)layer * D_H, hlin, N_NODES, K);
    hipMemsetAsync(stats, 0, 1024 * sizeof(float), stream);
    col_stats<<<64, 256, 0, stream>>>(hlin, stats, N_NODES);
    bn_relu_jk<<<4096, 256, 0, stream>>>(hlin, stats, bn_g + (size_t)layer * D_H,
                                         bn_b + (size_t)layer * D_H, hbuf, jk, layer);
    h_cur = hbuf;
  }

  pool_kernel<<<N_GRAPHS, 256, 0, stream>>>(jk, batch, g);
  fc1_kernel<<<N_GRAPHS, 512, 0, stream>>>(g, fc1_W, fc1_b, g2lin);
  bn4_kernel<<<2, 256, 0, stream>>>(g2lin, bn4_g, bn4_b, g2);
  fc2_kernel<<<N_GRAPHS, 64, 0, stream>>>(g2, fc2_W, fc2_b, out);
}

// Round 3
// 521.706 us; speedup vs baseline: 5.6992x; 1.2987x over previous
//
#include <hip/hip_runtime.h>
#include <hip/hip_bf16.h>
#include <math.h>

#define N_NODES 10000
#define N_GRAPHS 64
#define N_EDGES 160000
#define D_INPUT 128
#define D_H 512
#define EPS 1e-7f
#define MAXV 10.0f
#define BN_EPS 1e-5f
#define M_PAD 10112  // 79 * 128

typedef __attribute__((ext_vector_type(4))) float f32x4;
typedef __attribute__((ext_vector_type(8))) __bf16 bf16x8;

// ================= CSR build =================
__global__ __launch_bounds__(256) void hist_kernel(const int* __restrict__ dst,
                                                   int* __restrict__ cnt) {
  int i = blockIdx.x * blockDim.x + threadIdx.x;
  if (i < N_EDGES) atomicAdd(&cnt[dst[i]], 1);
}

__global__ __launch_bounds__(256) void scan_kernel(const int* __restrict__ cnt,
                                                   int* __restrict__ rowptr) {
  __shared__ int ps[256];
  int tid = threadIdx.x;
  const int CH = (N_NODES + 255) / 256;
  int b0 = tid * CH;
  int b1 = min(N_NODES, b0 + CH);
  int s = 0;
  for (int i = b0; i < b1; i++) s += cnt[i];
  ps[tid] = s;
  __syncthreads();
  for (int off = 1; off < 256; off <<= 1) {
    int v = (tid >= off) ? ps[tid - off] : 0;
    __syncthreads();
    ps[tid] += v;
    __syncthreads();
  }
  int run = (tid == 0) ? 0 : ps[tid - 1];
  for (int i = b0; i < b1; i++) {
    rowptr[i] = run;
    run += cnt[i];
  }
  if (tid == 255) rowptr[N_NODES] = run;
}

__global__ __launch_bounds__(256) void scatter_kernel(
    const int* __restrict__ src, const int* __restrict__ dst,
    const int* __restrict__ rowptr, int* __restrict__ cursor,
    int* __restrict__ csr_src) {
  int i = blockIdx.x * blockDim.x + threadIdx.x;
  if (i < N_EDGES) {
    int t = dst[i];
    int pos = rowptr[t] + atomicAdd(&cursor[t], 1);
    csr_src[pos] = src[i];
  }
}

// ============ fused: CSR aggregation + power-mean + MessageNorm + residual (bf16 out) ============
template <int D>
__global__ __launch_bounds__(256) void agg_msgnorm_kernel(
    const float* __restrict__ h, const int* __restrict__ rowptr,
    const int* __restrict__ csr_src, const float* __restrict__ p_ptr,
    const float* __restrict__ scale_ptr, __hip_bfloat16* __restrict__ out) {
  constexpr int C = D / 2;
  int n = blockIdx.x;
  int tid = threadIdx.x;
  int lo = rowptr[n], hi = rowptr[n + 1];
  float p = *p_ptr;
  float scale = *scale_ptr;
  bool p1 = (p == 1.0f);
  float invp = 1.0f / p;
  float inv_dg = 1.0f / fmaxf((float)(hi - lo), 1.0f);
  const float2* h2 = (const float2*)h;

  __shared__ int s_src[256];
  float accx = 0.f, accy = 0.f;
  for (int base = lo; base < hi; base += 256) {
    int m = min(256, hi - base);
    __syncthreads();
    if (tid < m) s_src[tid] = csr_src[base + tid];
    __syncthreads();
    if (tid < C) {
      for (int j = 0; j < m; j++) {
        float2 x = h2[(size_t)s_src[j] * C + tid];
        float m0 = fminf(fmaxf(x.x, 0.f) + EPS, MAXV);
        float m1 = fminf(fmaxf(x.y, 0.f) + EPS, MAXV);
        if (!p1) { m0 = powf(m0, p); m1 = powf(m1, p); }
        accx += m0;
        accy += m1;
      }
    }
  }

  float a0 = 0.f, a1 = 0.f, hv0 = 0.f, hv1 = 0.f, sa = 0.f, sh = 0.f;
  if (tid < C) {
    a0 = fminf(fmaxf(accx * inv_dg, EPS), MAXV);
    a1 = fminf(fmaxf(accy * inv_dg, EPS), MAXV);
    if (!p1) { a0 = powf(a0, invp); a1 = powf(a1, invp); }
    float2 hx = h2[(size_t)n * C + tid];
    hv0 = hx.x;
    hv1 = hx.y;
    sa = a0 * a0 + a1 * a1;
    sh = hv0 * hv0 + hv1 * hv1;
  }
  for (int off = 32; off; off >>= 1) {
    sa += __shfl_down(sa, off);
    sh += __shfl_down(sh, off);
  }
  __shared__ float red[2][4];
  __shared__ float tot[2];
  int wid = tid >> 6;
  if ((tid & 63) == 0) { red[0][wid] = sa; red[1][wid] = sh; }
  __syncthreads();
  if (tid == 0) {
    tot[0] = red[0][0] + red[0][1] + red[0][2] + red[0][3];
    tot[1] = red[1][0] + red[1][1] + red[1][2] + red[1][3];
  }
  __syncthreads();
  float k = sqrtf(tot[1]) * scale / fmaxf(sqrtf(tot[0]), 1e-12f);
  if (tid < C) {
    __hip_bfloat162 o2;
    o2.x = __float2bfloat16(hv0 + a0 * k);
    o2.y = __float2bfloat16(hv1 + a1 * k);
    ((__hip_bfloat162*)out)[(size_t)n * C + tid] = o2;
  }
}

// ============ convert + transpose weights: W[K][N] f32 -> Wt[N][K] bf16 ============
__global__ __launch_bounds__(256) void convert_wt(const float* __restrict__ W,
                                                  __hip_bfloat16* __restrict__ Wt,
                                                  int K, int N) {
  int i = blockIdx.x * 256 + threadIdx.x;
  if (i >= K * N) return;
  int n = i / K, k = i - n * K;
  Wt[i] = __float2bfloat16(W[(size_t)k * N + n]);
}

// ============ MFMA bf16 GEMM: C[M][512] = A[Mpad][K] @ Wt[512][K]^T + bias ============
// 128x128 tile, BK=64, 4 waves (2x2), each wave 64x64 via 4x4 frags of 16x16x32.
// LDS tiles linear [128][64] bf16 with XOR swizzle (byte ^= (row&7)<<4) applied on
// BOTH ds_write (staging) and ds_read (fragments) -> conflict-free ds_read_b128.
__global__ __launch_bounds__(256) void mfma_gemm(
    const __hip_bfloat16* __restrict__ A, const __hip_bfloat16* __restrict__ Bt,
    const float* __restrict__ bias, float* __restrict__ C, int M, int K) {
  __shared__ ushort As[128 * 64];
  __shared__ ushort Bs[128 * 64];
  int tid = threadIdx.x;
  int l = tid & 63;
  int w = tid >> 6;
  int wm = w >> 1, wn = w & 1;
  int row0 = blockIdx.x * 128;
  int col0 = blockIdx.y * 128;

  f32x4 acc[4][4];
#pragma unroll
  for (int m = 0; m < 4; m++)
#pragma unroll
    for (int n = 0; n < 4; n++) acc[m][n] = (f32x4){0.f, 0.f, 0.f, 0.f};

  const ushort* Ag = (const ushort*)A;
  const ushort* Bg = (const ushort*)Bt;
  char* AsB = (char*)As;
  char* BsB = (char*)Bs;

  // staging coords: chunk c = j*256 + tid covers (row = c>>3, 16B col = (c&7)*16)
  int srow = tid >> 3;          // + j*32 ; (j*32+srow)&7 == srow&7
  int scb = (tid & 7) * 16;     // byte col in 128B row
  int wbyte = scb ^ ((srow & 7) << 4);
  int scol = scb >> 1;          // element col

  // fragment read coords
  int lswz = (l & 7) << 4;
  int kb = (l >> 4) * 16;       // lane k-byte within 32-elem slice
  int arow = wm * 64 + (l & 15);
  int brow = wn * 64 + (l & 15);

  for (int k0 = 0; k0 < K; k0 += 64) {
    uint4 ra[4], rb[4];
#pragma unroll
    for (int j = 0; j < 4; j++) {
      int row = j * 32 + srow;
      ra[j] = *(const uint4*)(Ag + (size_t)(row0 + row) * K + k0 + scol);
      rb[j] = *(const uint4*)(Bg + (size_t)(col0 + row) * K + k0 + scol);
    }
#pragma unroll
    for (int j = 0; j < 4; j++) {
      int row = j * 32 + srow;
      *(uint4*)(AsB + row * 128 + wbyte) = ra[j];
      *(uint4*)(BsB + row * 128 + wbyte) = rb[j];
    }
    __syncthreads();
#pragma unroll
    for (int kk = 0; kk < 2; kk++) {
      bf16x8 af[4], bfr[4];
#pragma unroll
      for (int m = 0; m < 4; m++)
        af[m] = *(const bf16x8*)(AsB + (arow + m * 16) * 128 + ((kk * 64 + kb) ^ lswz));
#pragma unroll
      for (int n = 0; n < 4; n++)
        bfr[n] = *(const bf16x8*)(BsB + (brow + n * 16) * 128 + ((kk * 64 + kb) ^ lswz));
#pragma unroll
      for (int m = 0; m < 4; m++)
#pragma unroll
        for (int n = 0; n < 4; n++)
          acc[m][n] = __builtin_amdgcn_mfma_f32_16x16x32_bf16(af[m], bfr[n], acc[m][n], 0, 0, 0);
    }
    __syncthreads();
  }

  int crow0 = row0 + wm * 64 + (l >> 4) * 4;
  int ccol0 = col0 + wn * 64 + (l & 15);
#pragma unroll
  for (int n = 0; n < 4; n++) {
    int col = ccol0 + n * 16;
    float bv = bias[col];
#pragma unroll
    for (int m = 0; m < 4; m++) {
#pragma unroll
      for (int r = 0; r < 4; r++) {
        int rr = crow0 + m * 16 + r;
        if (rr < M) C[(size_t)rr * D_H + col] = acc[m][n][r] + bv;
      }
    }
  }
}

// ---------------- per-column batch stats (sum, sumsq) ----------------
__global__ __launch_bounds__(256) void col_stats(const float* __restrict__ x,
                                                 float* __restrict__ stats, int N) {
  int tid = threadIdx.x;
  int rpb = (N + gridDim.x - 1) / gridDim.x;
  int r0 = blockIdx.x * rpb;
  int r1 = min(N, r0 + rpb);
  float s0 = 0.f, q0 = 0.f, s1 = 0.f, q1 = 0.f;
  for (int r = r0; r < r1; r++) {
    float a = x[(size_t)r * D_H + tid];
    float b = x[(size_t)r * D_H + tid + 256];
    s0 += a; q0 += a * a;
    s1 += b; q1 += b * b;
  }
  atomicAdd(&stats[tid], s0);
  atomicAdd(&stats[D_H + tid], q0);
  atomicAdd(&stats[tid + 256], s1);
  atomicAdd(&stats[D_H + tid + 256], q1);
}

// ---------------- BN + ReLU + JK-max ----------------
__global__ __launch_bounds__(256) void bn_relu_jk(
    const float* __restrict__ x, const float* __restrict__ stats,
    const float* __restrict__ gamma, const float* __restrict__ beta,
    float* __restrict__ h, float* __restrict__ jk, int layer) {
  const float invN = 1.0f / (float)N_NODES;
  int total = N_NODES * D_H;
  for (int idx = blockIdx.x * blockDim.x + threadIdx.x; idx < total;
       idx += gridDim.x * blockDim.x) {
    int c = idx & (D_H - 1);
    float mean = stats[c] * invN;
    float var = stats[D_H + c] * invN - mean * mean;
    float v = (x[idx] - mean) * rsqrtf(var + BN_EPS) * gamma[c] + beta[c];
    v = fmaxf(v, 0.f);
    h[idx] = v;
    jk[idx] = (layer == 0) ? v : fmaxf(jk[idx], v);
  }
}

// ---------------- per-graph max+mean pooling: grid (graph, col-chunk) ----------------
__device__ __forceinline__ int lower_bound_i(const int* a, int n, int v) {
  int lo = 0, hi = n;
  while (lo < hi) {
    int mid = (lo + hi) >> 1;
    if (a[mid] < v) lo = mid + 1; else hi = mid;
  }
  return lo;
}

__global__ __launch_bounds__(64) void pool_kernel(const float* __restrict__ jk,
                                                  const int* __restrict__ batch,
                                                  float* __restrict__ g) {
  int gid = blockIdx.x;
  int col = blockIdx.y * 64 + threadIdx.x;
  int lo = lower_bound_i(batch, N_NODES, gid);
  int hi = lower_bound_i(batch, N_NODES, gid + 1);
  float inv_cnt = 1.0f / fmaxf((float)(hi - lo), 1.0f);
  float mx = 0.f, sm = 0.f;
  for (int r = lo; r < hi; r++) {
    float v = jk[(size_t)r * D_H + col];
    mx = fmaxf(mx, v);
    sm += v;
  }
  g[(size_t)gid * 1024 + col] = (hi > lo) ? mx : 0.f;
  g[(size_t)gid * 1024 + D_H + col] = sm * inv_cnt;
}

// ---------------- fc1: [64,1024] @ [1024,512] + b ----------------
__global__ __launch_bounds__(512) void fc1_kernel(const float* __restrict__ g,
                                                  const float* __restrict__ W,
                                                  const float* __restrict__ b,
                                                  float* __restrict__ out) {
  __shared__ float sg[1024];
  int gid = blockIdx.x;
  for (int i = threadIdx.x; i < 1024; i += 512) sg[i] = g[(size_t)gid * 1024 + i];
  __syncthreads();
  int c = threadIdx.x;
  float acc = b[c];
  for (int k = 0; k < 1024; k++) acc += sg[k] * W[(size_t)k * D_H + c];
  out[(size_t)gid * D_H + c] = acc;
}

// ---------------- BN over 64 graphs + ReLU ----------------
__global__ __launch_bounds__(256) void bn4_kernel(const float* __restrict__ x,
                                                  const float* __restrict__ gmm,
                                                  const float* __restrict__ bb,
                                                  float* __restrict__ y) {
  int c = blockIdx.x * blockDim.x + threadIdx.x;
  if (c >= D_H) return;
  float s = 0.f, q = 0.f;
  for (int r = 0; r < N_GRAPHS; r++) {
    float v = x[(size_t)r * D_H + c];
    s += v; q += v * v;
  }
  float mean = s / (float)N_GRAPHS;
  float var = q / (float)N_GRAPHS - mean * mean;
  float rs = rsqrtf(var + BN_EPS) * gmm[c];
  for (int r = 0; r < N_GRAPHS; r++) {
    float v = (x[(size_t)r * D_H + c] - mean) * rs + bb[c];
    y[(size_t)r * D_H + c] = fmaxf(v, 0.f);
  }
}

// ---------------- fc2: [64,512] @ [512,2] + b ----------------
__global__ __launch_bounds__(64) void fc2_kernel(const float* __restrict__ y,
                                                 const float* __restrict__ W,
                                                 const float* __restrict__ b,
                                                 float* __restrict__ out) {
  int gid = blockIdx.x;
  int lane = threadIdx.x;
  float a0 = 0.f, a1 = 0.f;
  for (int k = lane; k < D_H; k += 64) {
    float v = y[(size_t)gid * D_H + k];
    a0 += v * W[k * 2 + 0];
    a1 += v * W[k * 2 + 1];
  }
  for (int off = 32; off; off >>= 1) {
    a0 += __shfl_down(a0, off);
    a1 += __shfl_down(a1, off);
  }
  if (lane == 0) {
    out[gid * 2 + 0] = a0 + b[0];
    out[gid * 2 + 1] = a1 + b[1];
  }
}

extern "C" void kernel_launch(void* const* d_in, const int* in_sizes, int n_in,
                              void* d_out, int out_size, void* d_ws, size_t ws_size,
                              hipStream_t stream) {
  const float* x       = (const float*)d_in[0];
  const float* W0      = (const float*)d_in[1];
  const float* Wrest   = (const float*)d_in[2];
  const float* bconv   = (const float*)d_in[3];
  const float* p       = (const float*)d_in[4];
  const float* mscale  = (const float*)d_in[5];
  const float* bn_g    = (const float*)d_in[6];
  const float* bn_b    = (const float*)d_in[7];
  const float* fc1_W   = (const float*)d_in[8];
  const float* fc1_b   = (const float*)d_in[9];
  const float* bn4_g   = (const float*)d_in[10];
  const float* bn4_b   = (const float*)d_in[11];
  const float* fc2_W   = (const float*)d_in[12];
  const float* fc2_b   = (const float*)d_in[13];
  const int*   eidx    = (const int*)d_in[14];
  const int*   batch   = (const int*)d_in[15];
  float* out = (float*)d_out;

  const int* src = eidx;
  const int* dst = eidx + N_EDGES;

  float* ws = (float*)d_ws;
  const size_t NH = (size_t)N_NODES * D_H;
  float* hlin  = ws;
  float* hbuf  = hlin + NH;
  float* jk    = hbuf + NH;
  float* stats = jk + NH;                          // 1024
  __hip_bfloat16* residb = (__hip_bfloat16*)(stats + 1024);  // [M_PAD][512] bf16
  __hip_bfloat16* w0t = residb + (size_t)M_PAD * D_H;        // [512][128]
  __hip_bfloat16* w1t = w0t + 512 * 128;                     // [512][512]
  __hip_bfloat16* w2t = w1t + 512 * 512;
  int* cnt     = (int*)(w2t + 512 * 512);
  int* rowptr  = cnt + N_NODES;
  int* csr_src = rowptr + N_NODES + 1;
  float* g     = (float*)(csr_src + N_EDGES);      // 64*1024
  float* g2lin = g + 64 * 1024;
  float* g2    = g2lin + 64 * D_H;

  // ---- weight convert+transpose (bf16) ----
  convert_wt<<<(512 * 128 + 255) / 256, 256, 0, stream>>>(W0, w0t, D_INPUT, D_H);
  convert_wt<<<(512 * 512 + 255) / 256, 256, 0, stream>>>(Wrest, w1t, D_H, D_H);
  convert_wt<<<(512 * 512 + 255) / 256, 256, 0, stream>>>(Wrest + (size_t)D_H * D_H, w2t, D_H, D_H);

  // ---- build CSR ----
  hipMemsetAsync(cnt, 0, N_NODES * sizeof(int), stream);
  hist_kernel<<<(N_EDGES + 255) / 256, 256, 0, stream>>>(dst, cnt);
  scan_kernel<<<1, 256, 0, stream>>>(cnt, rowptr);
  hipMemsetAsync(cnt, 0, N_NODES * sizeof(int), stream);
  scatter_kernel<<<(N_EDGES + 255) / 256, 256, 0, stream>>>(src, dst, rowptr, cnt, csr_src);

  const float* h_cur = x;
  for (int layer = 0; layer < 3; layer++) {
    if (layer == 0)
      agg_msgnorm_kernel<D_INPUT><<<N_NODES, 256, 0, stream>>>(
          h_cur, rowptr, csr_src, p + layer, mscale + layer, residb);
    else
      agg_msgnorm_kernel<D_H><<<N_NODES, 256, 0, stream>>>(
          h_cur, rowptr, csr_src, p + layer, mscale + layer, residb);
    const __hip_bfloat16* Wt = (layer == 0) ? w0t : (layer == 1 ? w1t : w2t);
    int K = (layer == 0) ? D_INPUT : D_H;
    mfma_gemm<<<dim3(M_PAD / 128, D_H / 128), 256, 0, stream>>>(
        residb, Wt, bconv + (size_t)layer * D_H, hlin, N_NODES, K);
    hipMemsetAsync(stats, 0, 1024 * sizeof(float), stream);
    col_stats<<<64, 256, 0, stream>>>(hlin, stats, N_NODES);
    bn_relu_jk<<<4096, 256, 0, stream>>>(hlin, stats, bn_g + (size_t)layer * D_H,
                                         bn_b + (size_t)layer * D_H, hbuf, jk, layer);
    h_cur = hbuf;
  }

  pool_kernel<<<dim3(N_GRAPHS, 8), 64, 0, stream>>>(jk, batch, g);
  fc1_kernel<<<N_GRAPHS, 512, 0, stream>>>(g, fc1_W, fc1_b, g2lin);
  bn4_kernel<<<2, 256, 0, stream>>>(g2lin, bn4_g, bn4_b, g2);
  fc2_kernel<<<N_GRAPHS, 64, 0, stream>>>(g2, fc2_W, fc2_b, out);
}

// Round 4
// 365.585 us; speedup vs baseline: 8.1331x; 1.4270x over previous
//
#include <hip/hip_runtime.h>
#include <hip/hip_bf16.h>
#include <math.h>

#define N_NODES 10000
#define N_GRAPHS 64
#define N_EDGES 160000
#define D_INPUT 128
#define D_H 512
#define EPS 1e-7f
#define MAXV 10.0f
#define BN_EPS 1e-5f
#define M_PAD 10112  // 79 * 128

typedef __attribute__((ext_vector_type(4))) float f32x4;
typedef __attribute__((ext_vector_type(8))) __bf16 bf16x8;

// ================= CSR build =================
__global__ __launch_bounds__(256) void hist_kernel(const int* __restrict__ dst,
                                                   int* __restrict__ cnt) {
  int i = blockIdx.x * blockDim.x + threadIdx.x;
  if (i < N_EDGES) atomicAdd(&cnt[dst[i]], 1);
}

__global__ __launch_bounds__(256) void scan_kernel(const int* __restrict__ cnt,
                                                   int* __restrict__ rowptr) {
  __shared__ int ps[256];
  int tid = threadIdx.x;
  const int CH = (N_NODES + 255) / 256;
  int b0 = tid * CH;
  int b1 = min(N_NODES, b0 + CH);
  int s = 0;
  for (int i = b0; i < b1; i++) s += cnt[i];
  ps[tid] = s;
  __syncthreads();
  for (int off = 1; off < 256; off <<= 1) {
    int v = (tid >= off) ? ps[tid - off] : 0;
    __syncthreads();
    ps[tid] += v;
    __syncthreads();
  }
  int run = (tid == 0) ? 0 : ps[tid - 1];
  for (int i = b0; i < b1; i++) {
    rowptr[i] = run;
    run += cnt[i];
  }
  if (tid == 255) rowptr[N_NODES] = run;
}

__global__ __launch_bounds__(256) void scatter_kernel(
    const int* __restrict__ src, const int* __restrict__ dst,
    const int* __restrict__ rowptr, int* __restrict__ cursor,
    int* __restrict__ csr_src) {
  int i = blockIdx.x * blockDim.x + threadIdx.x;
  if (i < N_EDGES) {
    int t = dst[i];
    int pos = rowptr[t] + atomicAdd(&cursor[t], 1);
    csr_src[pos] = src[i];
  }
}

// ============ fused: CSR aggregation + power-mean + MessageNorm + residual (bf16 out) ============
// one block per node; SL edge-slices so all 256 threads are active even at D=128;
// edge loop unrolled x4 for memory-level parallelism.
template <int D>
__global__ __launch_bounds__(256) void agg_msgnorm_kernel(
    const float* __restrict__ h, const int* __restrict__ rowptr,
    const int* __restrict__ csr_src, const float* __restrict__ p_ptr,
    const float* __restrict__ scale_ptr, __hip_bfloat16* __restrict__ out) {
  constexpr int C = D / 2;        // float2 columns (64 or 256)
  constexpr int SL = 256 / C;     // edge slices (4 or 1)
  int n = blockIdx.x;
  int tid = threadIdx.x;
  int col = tid % C;
  int slice = tid / C;
  int lo = rowptr[n], hi = rowptr[n + 1];
  float p = *p_ptr;
  float scale = *scale_ptr;
  bool p1 = (p == 1.0f);
  float invp = 1.0f / p;
  float inv_dg = 1.0f / fmaxf((float)(hi - lo), 1.0f);
  const float2* h2 = (const float2*)h;

  __shared__ int s_src[256];
  float accx = 0.f, accy = 0.f;
  for (int base = lo; base < hi; base += 256) {
    int m = min(256, hi - base);
    __syncthreads();
    if (tid < m) s_src[tid] = csr_src[base + tid];
    __syncthreads();
    int j = slice;
    for (; j + 3 * SL < m; j += 4 * SL) {
      int s0 = s_src[j], s1 = s_src[j + SL], s2 = s_src[j + 2 * SL], s3 = s_src[j + 3 * SL];
      float2 x0 = h2[(size_t)s0 * C + col];
      float2 x1 = h2[(size_t)s1 * C + col];
      float2 x2 = h2[(size_t)s2 * C + col];
      float2 x3 = h2[(size_t)s3 * C + col];
      float m0x = fminf(fmaxf(x0.x, 0.f) + EPS, MAXV), m0y = fminf(fmaxf(x0.y, 0.f) + EPS, MAXV);
      float m1x = fminf(fmaxf(x1.x, 0.f) + EPS, MAXV), m1y = fminf(fmaxf(x1.y, 0.f) + EPS, MAXV);
      float m2x = fminf(fmaxf(x2.x, 0.f) + EPS, MAXV), m2y = fminf(fmaxf(x2.y, 0.f) + EPS, MAXV);
      float m3x = fminf(fmaxf(x3.x, 0.f) + EPS, MAXV), m3y = fminf(fmaxf(x3.y, 0.f) + EPS, MAXV);
      if (!p1) {
        m0x = powf(m0x, p); m0y = powf(m0y, p);
        m1x = powf(m1x, p); m1y = powf(m1y, p);
        m2x = powf(m2x, p); m2y = powf(m2y, p);
        m3x = powf(m3x, p); m3y = powf(m3y, p);
      }
      accx += (m0x + m1x) + (m2x + m3x);
      accy += (m0y + m1y) + (m2y + m3y);
    }
    for (; j < m; j += SL) {
      float2 x = h2[(size_t)s_src[j] * C + col];
      float mx = fminf(fmaxf(x.x, 0.f) + EPS, MAXV);
      float my = fminf(fmaxf(x.y, 0.f) + EPS, MAXV);
      if (!p1) { mx = powf(mx, p); my = powf(my, p); }
      accx += mx;
      accy += my;
    }
  }

  if constexpr (SL > 1) {
    __shared__ float sacc[2][256];
    sacc[0][tid] = accx;
    sacc[1][tid] = accy;
    __syncthreads();
    if (tid < C) {
#pragma unroll
      for (int s = 1; s < SL; s++) {
        accx += sacc[0][s * C + tid];
        accy += sacc[1][s * C + tid];
      }
    }
  }

  float a0 = 0.f, a1 = 0.f, hv0 = 0.f, hv1 = 0.f, sa = 0.f, sh = 0.f;
  if (tid < C) {
    a0 = fminf(fmaxf(accx * inv_dg, EPS), MAXV);
    a1 = fminf(fmaxf(accy * inv_dg, EPS), MAXV);
    if (!p1) { a0 = powf(a0, invp); a1 = powf(a1, invp); }
    float2 hx = h2[(size_t)n * C + tid];
    hv0 = hx.x;
    hv1 = hx.y;
    sa = a0 * a0 + a1 * a1;
    sh = hv0 * hv0 + hv1 * hv1;
  }
  for (int off = 32; off; off >>= 1) {
    sa += __shfl_down(sa, off);
    sh += __shfl_down(sh, off);
  }
  __shared__ float red[2][4];
  __shared__ float tot[2];
  int wid = tid >> 6;
  if ((tid & 63) == 0) { red[0][wid] = sa; red[1][wid] = sh; }
  __syncthreads();
  if (tid == 0) {
    tot[0] = red[0][0] + red[0][1] + red[0][2] + red[0][3];
    tot[1] = red[1][0] + red[1][1] + red[1][2] + red[1][3];
  }
  __syncthreads();
  float k = sqrtf(tot[1]) * scale / fmaxf(sqrtf(tot[0]), 1e-12f);
  if (tid < C) {
    __hip_bfloat162 o2;
    o2.x = __float2bfloat16(hv0 + a0 * k);
    o2.y = __float2bfloat16(hv1 + a1 * k);
    ((__hip_bfloat162*)out)[(size_t)n * C + tid] = o2;
  }
}

// ============ LDS-tiled convert + transpose: W[K][N] f32 -> Wt[N][K] bf16 ============
__global__ __launch_bounds__(256) void convert_wt(const float* __restrict__ W,
                                                  __hip_bfloat16* __restrict__ Wt,
                                                  int K, int N) {
  __shared__ float tile[32][33];
  int k0 = blockIdx.x * 32, n0 = blockIdx.y * 32;
  int tx = threadIdx.x & 31, ty = threadIdx.x >> 5;  // 8 rows of 32
  for (int i = ty; i < 32; i += 8)
    tile[i][tx] = W[(size_t)(k0 + i) * N + n0 + tx];  // coalesced over n
  __syncthreads();
  for (int i = ty; i < 32; i += 8)
    Wt[(size_t)(n0 + i) * K + k0 + tx] = __float2bfloat16(tile[tx][i]);  // coalesced over k
}

// ============ MFMA bf16 GEMM + fused column stats ============
// C[M][512] = A[Mpad][K] @ Wt[512][K]^T + bias; also atomically accumulates
// per-column sum/sumsq (rows < M only) into stats[1024].
__global__ __launch_bounds__(256) void mfma_gemm(
    const __hip_bfloat16* __restrict__ A, const __hip_bfloat16* __restrict__ Bt,
    const float* __restrict__ bias, float* __restrict__ C, float* __restrict__ stats,
    int M, int K) {
  __shared__ ushort As[128 * 64];
  __shared__ ushort Bs[128 * 64];
  __shared__ float sred[128][2];
  int tid = threadIdx.x;
  int l = tid & 63;
  int w = tid >> 6;
  int wm = w >> 1, wn = w & 1;
  int row0 = blockIdx.x * 128;
  int col0 = blockIdx.y * 128;

  f32x4 acc[4][4];
#pragma unroll
  for (int m = 0; m < 4; m++)
#pragma unroll
    for (int n = 0; n < 4; n++) acc[m][n] = (f32x4){0.f, 0.f, 0.f, 0.f};

  const ushort* Ag = (const ushort*)A;
  const ushort* Bg = (const ushort*)Bt;
  char* AsB = (char*)As;
  char* BsB = (char*)Bs;

  if (tid < 128) { sred[tid][0] = 0.f; sred[tid][1] = 0.f; }

  int srow = tid >> 3;
  int scb = (tid & 7) * 16;
  int wbyte = scb ^ ((srow & 7) << 4);
  int scol = scb >> 1;

  int lswz = (l & 7) << 4;
  int kb = (l >> 4) * 16;
  int arow = wm * 64 + (l & 15);
  int brow = wn * 64 + (l & 15);

  for (int k0 = 0; k0 < K; k0 += 64) {
    uint4 ra[4], rb[4];
#pragma unroll
    for (int j = 0; j < 4; j++) {
      int row = j * 32 + srow;
      ra[j] = *(const uint4*)(Ag + (size_t)(row0 + row) * K + k0 + scol);
      rb[j] = *(const uint4*)(Bg + (size_t)(col0 + row) * K + k0 + scol);
    }
#pragma unroll
    for (int j = 0; j < 4; j++) {
      int row = j * 32 + srow;
      *(uint4*)(AsB + row * 128 + wbyte) = ra[j];
      *(uint4*)(BsB + row * 128 + wbyte) = rb[j];
    }
    __syncthreads();
#pragma unroll
    for (int kk = 0; kk < 2; kk++) {
      bf16x8 af[4], bfr[4];
#pragma unroll
      for (int m = 0; m < 4; m++)
        af[m] = *(const bf16x8*)(AsB + (arow + m * 16) * 128 + ((kk * 64 + kb) ^ lswz));
#pragma unroll
      for (int n = 0; n < 4; n++)
        bfr[n] = *(const bf16x8*)(BsB + (brow + n * 16) * 128 + ((kk * 64 + kb) ^ lswz));
#pragma unroll
      for (int m = 0; m < 4; m++)
#pragma unroll
        for (int n = 0; n < 4; n++)
          acc[m][n] = __builtin_amdgcn_mfma_f32_16x16x32_bf16(af[m], bfr[n], acc[m][n], 0, 0, 0);
    }
    __syncthreads();
  }

  int crow0 = row0 + wm * 64 + (l >> 4) * 4;
  int ccol0 = col0 + wn * 64 + (l & 15);
#pragma unroll
  for (int n = 0; n < 4; n++) {
    int col = ccol0 + n * 16;
    float bv = bias[col];
    float ps = 0.f, pq = 0.f;
#pragma unroll
    for (int m = 0; m < 4; m++) {
#pragma unroll
      for (int r = 0; r < 4; r++) {
        int rr = crow0 + m * 16 + r;
        if (rr < M) {
          float v = acc[m][n][r] + bv;
          C[(size_t)rr * D_H + col] = v;
          ps += v;
          pq += v * v;
        }
      }
    }
    // reduce over the 4 row-groups (l>>4) sharing this column within the wave
    ps += __shfl_down(ps, 16); pq += __shfl_down(pq, 16);
    ps += __shfl_down(ps, 32); pq += __shfl_down(pq, 32);
    if ((l >> 4) == 0) {
      atomicAdd(&sred[wn * 64 + n * 16 + (l & 15)][0], ps);
      atomicAdd(&sred[wn * 64 + n * 16 + (l & 15)][1], pq);
    }
  }
  __syncthreads();
  if (tid < 128) {
    atomicAdd(&stats[col0 + tid], sred[tid][0]);
    atomicAdd(&stats[D_H + col0 + tid], sred[tid][1]);
  }
}

// ---------------- BN + ReLU + JK-max ----------------
__global__ __launch_bounds__(256) void bn_relu_jk(
    const float* __restrict__ x, const float* __restrict__ stats,
    const float* __restrict__ gamma, const float* __restrict__ beta,
    float* __restrict__ h, float* __restrict__ jk, int layer) {
  const float invN = 1.0f / (float)N_NODES;
  int total = N_NODES * D_H;
  for (int idx = blockIdx.x * blockDim.x + threadIdx.x; idx < total;
       idx += gridDim.x * blockDim.x) {
    int c = idx & (D_H - 1);
    float mean = stats[c] * invN;
    float var = stats[D_H + c] * invN - mean * mean;
    float v = (x[idx] - mean) * rsqrtf(var + BN_EPS) * gamma[c] + beta[c];
    v = fmaxf(v, 0.f);
    if (layer != 2) h[idx] = v;  // last layer: h never consumed (jk only)
    jk[idx] = (layer == 0) ? v : fmaxf(jk[idx], v);
  }
}

// ---------------- per-graph max+mean pooling: grid (graph, col-chunk) ----------------
__device__ __forceinline__ int lower_bound_i(const int* a, int n, int v) {
  int lo = 0, hi = n;
  while (lo < hi) {
    int mid = (lo + hi) >> 1;
    if (a[mid] < v) lo = mid + 1; else hi = mid;
  }
  return lo;
}

__global__ __launch_bounds__(64) void pool_kernel(const float* __restrict__ jk,
                                                  const int* __restrict__ batch,
                                                  float* __restrict__ g) {
  int gid = blockIdx.x;
  int col = blockIdx.y * 64 + threadIdx.x;
  int lo = lower_bound_i(batch, N_NODES, gid);
  int hi = lower_bound_i(batch, N_NODES, gid + 1);
  float inv_cnt = 1.0f / fmaxf((float)(hi - lo), 1.0f);
  float mx = 0.f, sm = 0.f;
  for (int r = lo; r < hi; r++) {
    float v = jk[(size_t)r * D_H + col];
    mx = fmaxf(mx, v);
    sm += v;
  }
  g[(size_t)gid * 1024 + col] = (hi > lo) ? mx : 0.f;
  g[(size_t)gid * 1024 + D_H + col] = sm * inv_cnt;
}

// ---------------- fc1: [64,1024] @ [1024,512] + b ----------------
__global__ __launch_bounds__(512) void fc1_kernel(const float* __restrict__ g,
                                                  const float* __restrict__ W,
                                                  const float* __restrict__ b,
                                                  float* __restrict__ out) {
  __shared__ float sg[1024];
  int gid = blockIdx.x;
  for (int i = threadIdx.x; i < 1024; i += 512) sg[i] = g[(size_t)gid * 1024 + i];
  __syncthreads();
  int c = threadIdx.x;
  float acc = b[c];
  for (int k = 0; k < 1024; k++) acc += sg[k] * W[(size_t)k * D_H + c];
  out[(size_t)gid * D_H + c] = acc;
}

// ---------------- BN over 64 graphs + ReLU ----------------
__global__ __launch_bounds__(256) void bn4_kernel(const float* __restrict__ x,
                                                  const float* __restrict__ gmm,
                                                  const float* __restrict__ bb,
                                                  float* __restrict__ y) {
  int c = blockIdx.x * blockDim.x + threadIdx.x;
  if (c >= D_H) return;
  float s = 0.f, q = 0.f;
  for (int r = 0; r < N_GRAPHS; r++) {
    float v = x[(size_t)r * D_H + c];
    s += v; q += v * v;
  }
  float mean = s / (float)N_GRAPHS;
  float var = q / (float)N_GRAPHS - mean * mean;
  float rs = rsqrtf(var + BN_EPS) * gmm[c];
  for (int r = 0; r < N_GRAPHS; r++) {
    float v = (x[(size_t)r * D_H + c] - mean) * rs + bb[c];
    y[(size_t)r * D_H + c] = fmaxf(v, 0.f);
  }
}

// ---------------- fc2: [64,512] @ [512,2] + b ----------------
__global__ __launch_bounds__(64) void fc2_kernel(const float* __restrict__ y,
                                                 const float* __restrict__ W,
                                                 const float* __restrict__ b,
                                                 float* __restrict__ out) {
  int gid = blockIdx.x;
  int lane = threadIdx.x;
  float a0 = 0.f, a1 = 0.f;
  for (int k = lane; k < D_H; k += 64) {
    float v = y[(size_t)gid * D_H + k];
    a0 += v * W[k * 2 + 0];
    a1 += v * W[k * 2 + 1];
  }
  for (int off = 32; off; off >>= 1) {
    a0 += __shfl_down(a0, off);
    a1 += __shfl_down(a1, off);
  }
  if (lane == 0) {
    out[gid * 2 + 0] = a0 + b[0];
    out[gid * 2 + 1] = a1 + b[1];
  }
}

extern "C" void kernel_launch(void* const* d_in, const int* in_sizes, int n_in,
                              void* d_out, int out_size, void* d_ws, size_t ws_size,
                              hipStream_t stream) {
  const float* x       = (const float*)d_in[0];
  const float* W0      = (const float*)d_in[1];
  const float* Wrest   = (const float*)d_in[2];
  const float* bconv   = (const float*)d_in[3];
  const float* p       = (const float*)d_in[4];
  const float* mscale  = (const float*)d_in[5];
  const float* bn_g    = (const float*)d_in[6];
  const float* bn_b    = (const float*)d_in[7];
  const float* fc1_W   = (const float*)d_in[8];
  const float* fc1_b   = (const float*)d_in[9];
  const float* bn4_g   = (const float*)d_in[10];
  const float* bn4_b   = (const float*)d_in[11];
  const float* fc2_W   = (const float*)d_in[12];
  const float* fc2_b   = (const float*)d_in[13];
  const int*   eidx    = (const int*)d_in[14];
  const int*   batch   = (const int*)d_in[15];
  float* out = (float*)d_out;

  const int* src = eidx;
  const int* dst = eidx + N_EDGES;

  float* ws = (float*)d_ws;
  const size_t NH = (size_t)N_NODES * D_H;
  float* hlin  = ws;
  float* hbuf  = hlin + NH;
  float* jk    = hbuf + NH;
  float* stats = jk + NH;                          // 1024
  __hip_bfloat16* residb = (__hip_bfloat16*)(stats + 1024);  // [M_PAD][512] bf16
  __hip_bfloat16* w0t = residb + (size_t)M_PAD * D_H;        // [512][128]
  __hip_bfloat16* w1t = w0t + 512 * 128;                     // [512][512]
  __hip_bfloat16* w2t = w1t + 512 * 512;
  int* cnt     = (int*)(w2t + 512 * 512);
  int* rowptr  = cnt + N_NODES;
  int* csr_src = rowptr + N_NODES + 1;
  float* g     = (float*)(csr_src + N_EDGES);      // 64*1024
  float* g2lin = g + 64 * 1024;
  float* g2    = g2lin + 64 * D_H;

  // ---- weight convert+transpose (bf16, LDS-tiled) ----
  convert_wt<<<dim3(D_INPUT / 32, D_H / 32), 256, 0, stream>>>(W0, w0t, D_INPUT, D_H);
  convert_wt<<<dim3(D_H / 32, D_H / 32), 256, 0, stream>>>(Wrest, w1t, D_H, D_H);
  convert_wt<<<dim3(D_H / 32, D_H / 32), 256, 0, stream>>>(Wrest + (size_t)D_H * D_H, w2t, D_H, D_H);

  // ---- build CSR ----
  hipMemsetAsync(cnt, 0, N_NODES * sizeof(int), stream);
  hist_kernel<<<(N_EDGES + 255) / 256, 256, 0, stream>>>(dst, cnt);
  scan_kernel<<<1, 256, 0, stream>>>(cnt, rowptr);
  hipMemsetAsync(cnt, 0, N_NODES * sizeof(int), stream);
  scatter_kernel<<<(N_EDGES + 255) / 256, 256, 0, stream>>>(src, dst, rowptr, cnt, csr_src);

  const float* h_cur = x;
  for (int layer = 0; layer < 3; layer++) {
    if (layer == 0)
      agg_msgnorm_kernel<D_INPUT><<<N_NODES, 256, 0, stream>>>(
          h_cur, rowptr, csr_src, p + layer, mscale + layer, residb);
    else
      agg_msgnorm_kernel<D_H><<<N_NODES, 256, 0, stream>>>(
          h_cur, rowptr, csr_src, p + layer, mscale + layer, residb);
    const __hip_bfloat16* Wt = (layer == 0) ? w0t : (layer == 1 ? w1t : w2t);
    int K = (layer == 0) ? D_INPUT : D_H;
    hipMemsetAsync(stats, 0, 1024 * sizeof(float), stream);
    mfma_gemm<<<dim3(M_PAD / 128, D_H / 128), 256, 0, stream>>>(
        residb, Wt, bconv + (size_t)layer * D_H, hlin, stats, N_NODES, K);
    bn_relu_jk<<<4096, 256, 0, stream>>>(hlin, stats, bn_g + (size_t)layer * D_H,
                                         bn_b + (size_t)layer * D_H, hbuf, jk, layer);
    h_cur = hbuf;
  }

  pool_kernel<<<dim3(N_GRAPHS, 8), 64, 0, stream>>>(jk, batch, g);
  fc1_kernel<<<N_GRAPHS, 512, 0, stream>>>(g, fc1_W, fc1_b, g2lin);
  bn4_kernel<<<2, 256, 0, stream>>>(g2lin, bn4_g, bn4_b, g2);
  fc2_kernel<<<N_GRAPHS, 64, 0, stream>>>(g2, fc2_W, fc2_b, out);
}

// Round 5
// 324.058 us; speedup vs baseline: 9.1753x; 1.1281x over previous
//
#include <hip/hip_runtime.h>
#include <hip/hip_bf16.h>
#include <math.h>

#define N_NODES 10000
#define N_GRAPHS 64
#define N_EDGES 160000
#define D_INPUT 128
#define D_H 512
#define EPS 1e-7f
#define MAXV 10.0f
#define BN_EPS 1e-5f
#define M_PAD 10112  // 79 * 128

typedef __attribute__((ext_vector_type(4))) float f32x4;
typedef __attribute__((ext_vector_type(8))) __bf16 bf16x8;

// ================= CSR build =================
__global__ __launch_bounds__(256) void hist_kernel(const int* __restrict__ dst,
                                                   int* __restrict__ cnt) {
  int i = blockIdx.x * blockDim.x + threadIdx.x;
  if (i < N_EDGES) atomicAdd(&cnt[dst[i]], 1);
}

__global__ __launch_bounds__(256) void scan_kernel(const int* __restrict__ cnt,
                                                   int* __restrict__ rowptr) {
  __shared__ int ps[256];
  int tid = threadIdx.x;
  const int CH = (N_NODES + 255) / 256;
  int b0 = tid * CH;
  int b1 = min(N_NODES, b0 + CH);
  int s = 0;
  for (int i = b0; i < b1; i++) s += cnt[i];
  ps[tid] = s;
  __syncthreads();
  for (int off = 1; off < 256; off <<= 1) {
    int v = (tid >= off) ? ps[tid - off] : 0;
    __syncthreads();
    ps[tid] += v;
    __syncthreads();
  }
  int run = (tid == 0) ? 0 : ps[tid - 1];
  for (int i = b0; i < b1; i++) {
    rowptr[i] = run;
    run += cnt[i];
  }
  if (tid == 255) rowptr[N_NODES] = run;
}

__global__ __launch_bounds__(256) void scatter_kernel(
    const int* __restrict__ src, const int* __restrict__ dst,
    const int* __restrict__ rowptr, int* __restrict__ cursor,
    int* __restrict__ csr_src) {
  int i = blockIdx.x * blockDim.x + threadIdx.x;
  if (i < N_EDGES) {
    int t = dst[i];
    int pos = rowptr[t] + atomicAdd(&cursor[t], 1);
    csr_src[pos] = src[i];
  }
}

// ============ BN affine params from stats: aff[c]=scale, aff[512+c]=shift ============
__global__ __launch_bounds__(512) void bn_affine(const float* __restrict__ stats,
                                                 const float* __restrict__ gamma,
                                                 const float* __restrict__ beta,
                                                 float* __restrict__ aff) {
  int c = threadIdx.x;
  const float invN = 1.0f / (float)N_NODES;
  float mean = stats[c] * invN;
  float var = stats[D_H + c] * invN - mean * mean;
  float sc = rsqrtf(var + BN_EPS) * gamma[c];
  aff[c] = sc;
  aff[D_H + c] = beta[c] - mean * sc;
}

// ============ fused: [BN+ReLU of prev layer] + CSR aggregation + power-mean
//              + MessageNorm + residual (bf16 out) ============
// h is pre-BN (hlin) when BN=true; aff supplies per-column scale/shift.
template <int D, bool BN>
__global__ __launch_bounds__(256) void agg_msgnorm_kernel(
    const float* __restrict__ h, const float* __restrict__ aff,
    const int* __restrict__ rowptr, const int* __restrict__ csr_src,
    const float* __restrict__ p_ptr, const float* __restrict__ scale_ptr,
    __hip_bfloat16* __restrict__ out) {
  constexpr int C = D / 2;        // float2 columns (64 or 256)
  constexpr int SL = 256 / C;     // edge slices (4 or 1)
  int n = blockIdx.x;
  int tid = threadIdx.x;
  int col = tid % C;
  int slice = tid / C;
  int lo = rowptr[n], hi = rowptr[n + 1];
  float p = *p_ptr;
  float scale = *scale_ptr;
  bool p1 = (p == 1.0f);
  float invp = 1.0f / p;
  float inv_dg = 1.0f / fmaxf((float)(hi - lo), 1.0f);
  const float2* h2 = (const float2*)h;

  float scx = 1.f, shx = 0.f, scy = 1.f, shy = 0.f;
  if constexpr (BN) {
    float2 s2 = ((const float2*)aff)[col];
    float2 b2 = ((const float2*)(aff + D_H))[col];
    scx = s2.x; shx = b2.x; scy = s2.y; shy = b2.y;
  }

  __shared__ int s_src[256];
  float accx = 0.f, accy = 0.f;
  for (int base = lo; base < hi; base += 256) {
    int m = min(256, hi - base);
    __syncthreads();
    if (tid < m) s_src[tid] = csr_src[base + tid];
    __syncthreads();
    int j = slice;
    for (; j + 3 * SL < m; j += 4 * SL) {
      int s0 = s_src[j], s1 = s_src[j + SL], s2 = s_src[j + 2 * SL], s3 = s_src[j + 3 * SL];
      float2 x0 = h2[(size_t)s0 * C + col];
      float2 x1 = h2[(size_t)s1 * C + col];
      float2 x2 = h2[(size_t)s2 * C + col];
      float2 x3 = h2[(size_t)s3 * C + col];
      if constexpr (BN) {
        x0.x = x0.x * scx + shx; x0.y = x0.y * scy + shy;
        x1.x = x1.x * scx + shx; x1.y = x1.y * scy + shy;
        x2.x = x2.x * scx + shx; x2.y = x2.y * scy + shy;
        x3.x = x3.x * scx + shx; x3.y = x3.y * scy + shy;
      }
      float m0x = fminf(fmaxf(x0.x, 0.f) + EPS, MAXV), m0y = fminf(fmaxf(x0.y, 0.f) + EPS, MAXV);
      float m1x = fminf(fmaxf(x1.x, 0.f) + EPS, MAXV), m1y = fminf(fmaxf(x1.y, 0.f) + EPS, MAXV);
      float m2x = fminf(fmaxf(x2.x, 0.f) + EPS, MAXV), m2y = fminf(fmaxf(x2.y, 0.f) + EPS, MAXV);
      float m3x = fminf(fmaxf(x3.x, 0.f) + EPS, MAXV), m3y = fminf(fmaxf(x3.y, 0.f) + EPS, MAXV);
      if (!p1) {
        m0x = powf(m0x, p); m0y = powf(m0y, p);
        m1x = powf(m1x, p); m1y = powf(m1y, p);
        m2x = powf(m2x, p); m2y = powf(m2y, p);
        m3x = powf(m3x, p); m3y = powf(m3y, p);
      }
      accx += (m0x + m1x) + (m2x + m3x);
      accy += (m0y + m1y) + (m2y + m3y);
    }
    for (; j < m; j += SL) {
      float2 x = h2[(size_t)s_src[j] * C + col];
      if constexpr (BN) {
        x.x = x.x * scx + shx;
        x.y = x.y * scy + shy;
      }
      float mx = fminf(fmaxf(x.x, 0.f) + EPS, MAXV);
      float my = fminf(fmaxf(x.y, 0.f) + EPS, MAXV);
      if (!p1) { mx = powf(mx, p); my = powf(my, p); }
      accx += mx;
      accy += my;
    }
  }

  if constexpr (SL > 1) {
    __shared__ float sacc[2][256];
    sacc[0][tid] = accx;
    sacc[1][tid] = accy;
    __syncthreads();
    if (tid < C) {
#pragma unroll
      for (int s = 1; s < SL; s++) {
        accx += sacc[0][s * C + tid];
        accy += sacc[1][s * C + tid];
      }
    }
  }

  float a0 = 0.f, a1 = 0.f, hv0 = 0.f, hv1 = 0.f, sa = 0.f, sh = 0.f;
  if (tid < C) {
    a0 = fminf(fmaxf(accx * inv_dg, EPS), MAXV);
    a1 = fminf(fmaxf(accy * inv_dg, EPS), MAXV);
    if (!p1) { a0 = powf(a0, invp); a1 = powf(a1, invp); }
    float2 hx = h2[(size_t)n * C + tid];
    if constexpr (BN) {
      hx.x = fmaxf(hx.x * scx + shx, 0.f);
      hx.y = fmaxf(hx.y * scy + shy, 0.f);
    }
    hv0 = hx.x;
    hv1 = hx.y;
    sa = a0 * a0 + a1 * a1;
    sh = hv0 * hv0 + hv1 * hv1;
  }
  for (int off = 32; off; off >>= 1) {
    sa += __shfl_down(sa, off);
    sh += __shfl_down(sh, off);
  }
  __shared__ float red[2][4];
  __shared__ float tot[2];
  int wid = tid >> 6;
  if ((tid & 63) == 0) { red[0][wid] = sa; red[1][wid] = sh; }
  __syncthreads();
  if (tid == 0) {
    tot[0] = red[0][0] + red[0][1] + red[0][2] + red[0][3];
    tot[1] = red[1][0] + red[1][1] + red[1][2] + red[1][3];
  }
  __syncthreads();
  float k = sqrtf(tot[1]) * scale / fmaxf(sqrtf(tot[0]), 1e-12f);
  if (tid < C) {
    __hip_bfloat162 o2;
    o2.x = __float2bfloat16(hv0 + a0 * k);
    o2.y = __float2bfloat16(hv1 + a1 * k);
    ((__hip_bfloat162*)out)[(size_t)n * C + tid] = o2;
  }
}

// ============ LDS-tiled convert + transpose: W[K][N] f32 -> Wt[N][K] bf16 ============
__global__ __launch_bounds__(256) void convert_wt(const float* __restrict__ W,
                                                  __hip_bfloat16* __restrict__ Wt,
                                                  int K, int N) {
  __shared__ float tile[32][33];
  int k0 = blockIdx.x * 32, n0 = blockIdx.y * 32;
  int tx = threadIdx.x & 31, ty = threadIdx.x >> 5;
  for (int i = ty; i < 32; i += 8)
    tile[i][tx] = W[(size_t)(k0 + i) * N + n0 + tx];
  __syncthreads();
  for (int i = ty; i < 32; i += 8)
    Wt[(size_t)(n0 + i) * K + k0 + tx] = __float2bfloat16(tile[tx][i]);
}

// ============ MFMA bf16 GEMM + fused column stats ============
__global__ __launch_bounds__(256) void mfma_gemm(
    const __hip_bfloat16* __restrict__ A, const __hip_bfloat16* __restrict__ Bt,
    const float* __restrict__ bias, float* __restrict__ C, float* __restrict__ stats,
    int M, int K) {
  __shared__ ushort As[128 * 64];
  __shared__ ushort Bs[128 * 64];
  __shared__ float sred[128][2];
  int tid = threadIdx.x;
  int l = tid & 63;
  int w = tid >> 6;
  int wm = w >> 1, wn = w & 1;
  int row0 = blockIdx.x * 128;
  int col0 = blockIdx.y * 128;

  f32x4 acc[4][4];
#pragma unroll
  for (int m = 0; m < 4; m++)
#pragma unroll
    for (int n = 0; n < 4; n++) acc[m][n] = (f32x4){0.f, 0.f, 0.f, 0.f};

  const ushort* Ag = (const ushort*)A;
  const ushort* Bg = (const ushort*)Bt;
  char* AsB = (char*)As;
  char* BsB = (char*)Bs;

  if (tid < 128) { sred[tid][0] = 0.f; sred[tid][1] = 0.f; }

  int srow = tid >> 3;
  int scb = (tid & 7) * 16;
  int wbyte = scb ^ ((srow & 7) << 4);
  int scol = scb >> 1;

  int lswz = (l & 7) << 4;
  int kb = (l >> 4) * 16;
  int arow = wm * 64 + (l & 15);
  int brow = wn * 64 + (l & 15);

  for (int k0 = 0; k0 < K; k0 += 64) {
    uint4 ra[4], rb[4];
#pragma unroll
    for (int j = 0; j < 4; j++) {
      int row = j * 32 + srow;
      ra[j] = *(const uint4*)(Ag + (size_t)(row0 + row) * K + k0 + scol);
      rb[j] = *(const uint4*)(Bg + (size_t)(col0 + row) * K + k0 + scol);
    }
#pragma unroll
    for (int j = 0; j < 4; j++) {
      int row = j * 32 + srow;
      *(uint4*)(AsB + row * 128 + wbyte) = ra[j];
      *(uint4*)(BsB + row * 128 + wbyte) = rb[j];
    }
    __syncthreads();
#pragma unroll
    for (int kk = 0; kk < 2; kk++) {
      bf16x8 af[4], bfr[4];
#pragma unroll
      for (int m = 0; m < 4; m++)
        af[m] = *(const bf16x8*)(AsB + (arow + m * 16) * 128 + ((kk * 64 + kb) ^ lswz));
#pragma unroll
      for (int n = 0; n < 4; n++)
        bfr[n] = *(const bf16x8*)(BsB + (brow + n * 16) * 128 + ((kk * 64 + kb) ^ lswz));
#pragma unroll
      for (int m = 0; m < 4; m++)
#pragma unroll
        for (int n = 0; n < 4; n++)
          acc[m][n] = __builtin_amdgcn_mfma_f32_16x16x32_bf16(af[m], bfr[n], acc[m][n], 0, 0, 0);
    }
    __syncthreads();
  }

  int crow0 = row0 + wm * 64 + (l >> 4) * 4;
  int ccol0 = col0 + wn * 64 + (l & 15);
#pragma unroll
  for (int n = 0; n < 4; n++) {
    int col = ccol0 + n * 16;
    float bv = bias[col];
    float ps = 0.f, pq = 0.f;
#pragma unroll
    for (int m = 0; m < 4; m++) {
#pragma unroll
      for (int r = 0; r < 4; r++) {
        int rr = crow0 + m * 16 + r;
        if (rr < M) {
          float v = acc[m][n][r] + bv;
          C[(size_t)rr * D_H + col] = v;
          ps += v;
          pq += v * v;
        }
      }
    }
    ps += __shfl_down(ps, 16); pq += __shfl_down(pq, 16);
    ps += __shfl_down(ps, 32); pq += __shfl_down(pq, 32);
    if ((l >> 4) == 0) {
      atomicAdd(&sred[wn * 64 + n * 16 + (l & 15)][0], ps);
      atomicAdd(&sred[wn * 64 + n * 16 + (l & 15)][1], pq);
    }
  }
  __syncthreads();
  if (tid < 128) {
    atomicAdd(&stats[col0 + tid], sred[tid][0]);
    atomicAdd(&stats[D_H + col0 + tid], sred[tid][1]);
  }
}

// ---------------- JK-max update: jk = max(jk, relu(affine(hlin))) ----------------
__global__ __launch_bounds__(256) void jk_update(const float* __restrict__ hlin,
                                                 const float* __restrict__ aff,
                                                 float* __restrict__ jk, int layer) {
  const int total = N_NODES * D_H / 4;
  for (int idx = blockIdx.x * blockDim.x + threadIdx.x; idx < total;
       idx += gridDim.x * blockDim.x) {
    int c4 = idx & 127;  // float4 col index
    float4 x = ((const float4*)hlin)[idx];
    float4 sc = ((const float4*)aff)[c4];
    float4 sh = ((const float4*)(aff + D_H))[c4];
    float4 v;
    v.x = fmaxf(x.x * sc.x + sh.x, 0.f);
    v.y = fmaxf(x.y * sc.y + sh.y, 0.f);
    v.z = fmaxf(x.z * sc.z + sh.z, 0.f);
    v.w = fmaxf(x.w * sc.w + sh.w, 0.f);
    if (layer != 0) {
      float4 j = ((const float4*)jk)[idx];
      v.x = fmaxf(v.x, j.x);
      v.y = fmaxf(v.y, j.y);
      v.z = fmaxf(v.z, j.z);
      v.w = fmaxf(v.w, j.w);
    }
    ((float4*)jk)[idx] = v;
  }
}

// ---------------- per-graph max+mean pooling ----------------
// grid (graph, 8 col-chunks) x 256 threads = 64 cols x 4 row-slices, unroll x4
__device__ __forceinline__ int lower_bound_i(const int* a, int n, int v) {
  int lo = 0, hi = n;
  while (lo < hi) {
    int mid = (lo + hi) >> 1;
    if (a[mid] < v) lo = mid + 1; else hi = mid;
  }
  return lo;
}

__global__ __launch_bounds__(256) void pool_kernel(const float* __restrict__ jk,
                                                   const int* __restrict__ batch,
                                                   float* __restrict__ g) {
  int gid = blockIdx.x;
  int col = blockIdx.y * 64 + (threadIdx.x & 63);
  int slice = threadIdx.x >> 6;
  int lo = lower_bound_i(batch, N_NODES, gid);
  int hi = lower_bound_i(batch, N_NODES, gid + 1);
  float mx = 0.f, sm = 0.f;
  int r = lo + slice;
  for (; r + 12 < hi; r += 16) {
    float v0 = jk[(size_t)r * D_H + col];
    float v1 = jk[(size_t)(r + 4) * D_H + col];
    float v2 = jk[(size_t)(r + 8) * D_H + col];
    float v3 = jk[(size_t)(r + 12) * D_H + col];
    mx = fmaxf(fmaxf(fmaxf(mx, v0), fmaxf(v1, v2)), v3);
    sm += (v0 + v1) + (v2 + v3);
  }
  for (; r < hi; r += 4) {
    float v = jk[(size_t)r * D_H + col];
    mx = fmaxf(mx, v);
    sm += v;
  }
  __shared__ float smax[4][64];
  __shared__ float ssum[4][64];
  smax[slice][threadIdx.x & 63] = mx;
  ssum[slice][threadIdx.x & 63] = sm;
  __syncthreads();
  if (slice == 0) {
    int c = threadIdx.x & 63;
    mx = fmaxf(fmaxf(smax[0][c], smax[1][c]), fmaxf(smax[2][c], smax[3][c]));
    sm = ssum[0][c] + ssum[1][c] + ssum[2][c] + ssum[3][c];
    float inv_cnt = 1.0f / fmaxf((float)(hi - lo), 1.0f);
    g[(size_t)gid * 1024 + col] = (hi > lo) ? mx : 0.f;
    g[(size_t)gid * 1024 + D_H + col] = sm * inv_cnt;
  }
}

// ---------------- fc1: [64,1024] @ [1024,512] + b ----------------
__global__ __launch_bounds__(512) void fc1_kernel(const float* __restrict__ g,
                                                  const float* __restrict__ W,
                                                  const float* __restrict__ b,
                                                  float* __restrict__ out) {
  __shared__ float sg[1024];
  int gid = blockIdx.x;
  for (int i = threadIdx.x; i < 1024; i += 512) sg[i] = g[(size_t)gid * 1024 + i];
  __syncthreads();
  int c = threadIdx.x;
  float acc = b[c];
  for (int k = 0; k < 1024; k++) acc += sg[k] * W[(size_t)k * D_H + c];
  out[(size_t)gid * D_H + c] = acc;
}

// ---------------- BN over 64 graphs + ReLU ----------------
__global__ __launch_bounds__(256) void bn4_kernel(const float* __restrict__ x,
                                                  const float* __restrict__ gmm,
                                                  const float* __restrict__ bb,
                                                  float* __restrict__ y) {
  int c = blockIdx.x * blockDim.x + threadIdx.x;
  if (c >= D_H) return;
  float s = 0.f, q = 0.f;
  for (int r = 0; r < N_GRAPHS; r++) {
    float v = x[(size_t)r * D_H + c];
    s += v; q += v * v;
  }
  float mean = s / (float)N_GRAPHS;
  float var = q / (float)N_GRAPHS - mean * mean;
  float rs = rsqrtf(var + BN_EPS) * gmm[c];
  for (int r = 0; r < N_GRAPHS; r++) {
    float v = (x[(size_t)r * D_H + c] - mean) * rs + bb[c];
    y[(size_t)r * D_H + c] = fmaxf(v, 0.f);
  }
}

// ---------------- fc2: [64,512] @ [512,2] + b ----------------
__global__ __launch_bounds__(64) void fc2_kernel(const float* __restrict__ y,
                                                 const float* __restrict__ W,
                                                 const float* __restrict__ b,
                                                 float* __restrict__ out) {
  int gid = blockIdx.x;
  int lane = threadIdx.x;
  float a0 = 0.f, a1 = 0.f;
  for (int k = lane; k < D_H; k += 64) {
    float v = y[(size_t)gid * D_H + k];
    a0 += v * W[k * 2 + 0];
    a1 += v * W[k * 2 + 1];
  }
  for (int off = 32; off; off >>= 1) {
    a0 += __shfl_down(a0, off);
    a1 += __shfl_down(a1, off);
  }
  if (lane == 0) {
    out[gid * 2 + 0] = a0 + b[0];
    out[gid * 2 + 1] = a1 + b[1];
  }
}

extern "C" void kernel_launch(void* const* d_in, const int* in_sizes, int n_in,
                              void* d_out, int out_size, void* d_ws, size_t ws_size,
                              hipStream_t stream) {
  const float* x       = (const float*)d_in[0];
  const float* W0      = (const float*)d_in[1];
  const float* Wrest   = (const float*)d_in[2];
  const float* bconv   = (const float*)d_in[3];
  const float* p       = (const float*)d_in[4];
  const float* mscale  = (const float*)d_in[5];
  const float* bn_g    = (const float*)d_in[6];
  const float* bn_b    = (const float*)d_in[7];
  const float* fc1_W   = (const float*)d_in[8];
  const float* fc1_b   = (const float*)d_in[9];
  const float* bn4_g   = (const float*)d_in[10];
  const float* bn4_b   = (const float*)d_in[11];
  const float* fc2_W   = (const float*)d_in[12];
  const float* fc2_b   = (const float*)d_in[13];
  const int*   eidx    = (const int*)d_in[14];
  const int*   batch   = (const int*)d_in[15];
  float* out = (float*)d_out;

  const int* src = eidx;
  const int* dst = eidx + N_EDGES;

  float* ws = (float*)d_ws;
  const size_t NH = (size_t)N_NODES * D_H;
  float* hlin  = ws;
  float* jk    = hlin + NH;
  float* stats = jk + NH;                          // 1024
  float* aff   = stats + 1024;                     // 1024
  __hip_bfloat16* residb = (__hip_bfloat16*)(aff + 1024);    // [M_PAD][512] bf16
  __hip_bfloat16* w0t = residb + (size_t)M_PAD * D_H;
  __hip_bfloat16* w1t = w0t + 512 * 128;
  __hip_bfloat16* w2t = w1t + 512 * 512;
  int* cnt     = (int*)(w2t + 512 * 512);
  int* rowptr  = cnt + N_NODES;
  int* csr_src = rowptr + N_NODES + 1;
  float* g     = (float*)(csr_src + N_EDGES);
  float* g2lin = g + 64 * 1024;
  float* g2    = g2lin + 64 * D_H;

  // ---- weight convert+transpose (bf16, LDS-tiled) ----
  convert_wt<<<dim3(D_INPUT / 32, D_H / 32), 256, 0, stream>>>(W0, w0t, D_INPUT, D_H);
  convert_wt<<<dim3(D_H / 32, D_H / 32), 256, 0, stream>>>(Wrest, w1t, D_H, D_H);
  convert_wt<<<dim3(D_H / 32, D_H / 32), 256, 0, stream>>>(Wrest + (size_t)D_H * D_H, w2t, D_H, D_H);

  // ---- build CSR ----
  hipMemsetAsync(cnt, 0, N_NODES * sizeof(int), stream);
  hist_kernel<<<(N_EDGES + 255) / 256, 256, 0, stream>>>(dst, cnt);
  scan_kernel<<<1, 256, 0, stream>>>(cnt, rowptr);
  hipMemsetAsync(cnt, 0, N_NODES * sizeof(int), stream);
  scatter_kernel<<<(N_EDGES + 255) / 256, 256, 0, stream>>>(src, dst, rowptr, cnt, csr_src);

  for (int layer = 0; layer < 3; layer++) {
    if (layer == 0)
      agg_msgnorm_kernel<D_INPUT, false><<<N_NODES, 256, 0, stream>>>(
          x, nullptr, rowptr, csr_src, p + layer, mscale + layer, residb);
    else
      agg_msgnorm_kernel<D_H, true><<<N_NODES, 256, 0, stream>>>(
          hlin, aff, rowptr, csr_src, p + layer, mscale + layer, residb);
    const __hip_bfloat16* Wt = (layer == 0) ? w0t : (layer == 1 ? w1t : w2t);
    int K = (layer == 0) ? D_INPUT : D_H;
    hipMemsetAsync(stats, 0, 1024 * sizeof(float), stream);
    mfma_gemm<<<dim3(M_PAD / 128, D_H / 128), 256, 0, stream>>>(
        residb, Wt, bconv + (size_t)layer * D_H, hlin, stats, N_NODES, K);
    bn_affine<<<1, 512, 0, stream>>>(stats, bn_g + (size_t)layer * D_H,
                                     bn_b + (size_t)layer * D_H, aff);
    jk_update<<<2048, 256, 0, stream>>>(hlin, aff, jk, layer);
  }

  pool_kernel<<<dim3(N_GRAPHS, 8), 256, 0, stream>>>(jk, batch, g);
  fc1_kernel<<<N_GRAPHS, 512, 0, stream>>>(g, fc1_W, fc1_b, g2lin);
  bn4_kernel<<<2, 256, 0, stream>>>(g2lin, bn4_g, bn4_b, g2);
  fc2_kernel<<<N_GRAPHS, 64, 0, stream>>>(g2, fc2_W, fc2_b, out);
}

// Round 6
// 297.078 us; speedup vs baseline: 10.0086x; 1.0908x over previous
//
#include <hip/hip_runtime.h>
#include <hip/hip_bf16.h>
#include <math.h>

#define N_NODES 10000
#define N_GRAPHS 64
#define N_EDGES 160000
#define D_INPUT 128
#define D_H 512
#define EPS 1e-7f
#define MAXV 10.0f
#define BN_EPS 1e-5f
#define M_PAD 10112  // 79 * 128

typedef __attribute__((ext_vector_type(4))) float f32x4;
typedef __attribute__((ext_vector_type(8))) __bf16 bf16x8;

// ================= CSR build =================
__global__ __launch_bounds__(256) void hist_kernel(const int* __restrict__ dst,
                                                   int* __restrict__ cnt) {
  int i = blockIdx.x * blockDim.x + threadIdx.x;
  if (i < N_EDGES) atomicAdd(&cnt[dst[i]], 1);
}

__global__ __launch_bounds__(256) void scan_kernel(const int* __restrict__ cnt,
                                                   int* __restrict__ rowptr) {
  __shared__ int ps[256];
  int tid = threadIdx.x;
  const int CH = (N_NODES + 255) / 256;
  int b0 = tid * CH;
  int b1 = min(N_NODES, b0 + CH);
  int s = 0;
  for (int i = b0; i < b1; i++) s += cnt[i];
  ps[tid] = s;
  __syncthreads();
  for (int off = 1; off < 256; off <<= 1) {
    int v = (tid >= off) ? ps[tid - off] : 0;
    __syncthreads();
    ps[tid] += v;
    __syncthreads();
  }
  int run = (tid == 0) ? 0 : ps[tid - 1];
  for (int i = b0; i < b1; i++) {
    rowptr[i] = run;
    run += cnt[i];
  }
  if (tid == 255) rowptr[N_NODES] = run;
}

__global__ __launch_bounds__(256) void scatter_kernel(
    const int* __restrict__ src, const int* __restrict__ dst,
    const int* __restrict__ rowptr, int* __restrict__ cursor,
    int* __restrict__ csr_src) {
  int i = blockIdx.x * blockDim.x + threadIdx.x;
  if (i < N_EDGES) {
    int t = dst[i];
    int pos = rowptr[t] + atomicAdd(&cursor[t], 1);
    csr_src[pos] = src[i];
  }
}

// ============ BN affine params from stats: aff[c]=scale, aff[512+c]=shift ============
__global__ __launch_bounds__(512) void bn_affine(const float* __restrict__ stats,
                                                 const float* __restrict__ gamma,
                                                 const float* __restrict__ beta,
                                                 float* __restrict__ aff) {
  int c = threadIdx.x;
  const float invN = 1.0f / (float)N_NODES;
  float mean = stats[c] * invN;
  float var = stats[D_H + c] * invN - mean * mean;
  float sc = rsqrtf(var + BN_EPS) * gamma[c];
  aff[c] = sc;
  aff[D_H + c] = beta[c] - mean * sc;
}

// ============ layer-0 message table: msgb = bf16(min(relu(x)+eps,MAXV)^p) ============
__global__ __launch_bounds__(256) void msg0_kernel(const float* __restrict__ x,
                                                   const float* __restrict__ p_ptr,
                                                   __hip_bfloat16* __restrict__ msgb) {
  float p = *p_ptr;
  bool p1 = (p == 1.0f);
  const int total = N_NODES * D_INPUT / 2;
  for (int i = blockIdx.x * 256 + threadIdx.x; i < total; i += gridDim.x * 256) {
    float2 v = ((const float2*)x)[i];
    float m0 = fminf(fmaxf(v.x, 0.f) + EPS, MAXV);
    float m1 = fminf(fmaxf(v.y, 0.f) + EPS, MAXV);
    if (!p1) { m0 = powf(m0, p); m1 = powf(m1, p); }
    __hip_bfloat162 o;
    o.x = __float2bfloat16(m0);
    o.y = __float2bfloat16(m1);
    ((__hip_bfloat162*)msgb)[i] = o;
  }
}

// ============ fused: CSR aggregation (bf16 msg table) + power-mean
//              + MessageNorm + residual (bf16 out) ============
// Gather reads precomputed bf16 messages; residual reads f32 h (affine when BN).
template <int D, bool BN>
__global__ __launch_bounds__(256) void agg_msgnorm_kernel(
    const float* __restrict__ h, const float* __restrict__ aff,
    const __hip_bfloat16* __restrict__ msgb,
    const int* __restrict__ rowptr, const int* __restrict__ csr_src,
    const float* __restrict__ p_ptr, const float* __restrict__ scale_ptr,
    __hip_bfloat16* __restrict__ out) {
  constexpr int C = D / 2;        // bf16-pair columns (64 or 256)
  constexpr int SL = 256 / C;     // edge slices (4 or 1)
  int n = blockIdx.x;
  int tid = threadIdx.x;
  int col = tid % C;
  int slice = tid / C;
  int lo = rowptr[n], hi = rowptr[n + 1];
  float p = *p_ptr;
  float scale = *scale_ptr;
  bool p1 = (p == 1.0f);
  float invp = 1.0f / p;
  float inv_dg = 1.0f / fmaxf((float)(hi - lo), 1.0f);
  const float2* h2 = (const float2*)h;
  const uint* mg = (const uint*)msgb;

  __shared__ int s_src[256];
  float accx = 0.f, accy = 0.f;
  for (int base = lo; base < hi; base += 256) {
    int m = min(256, hi - base);
    __syncthreads();
    if (tid < m) s_src[tid] = csr_src[base + tid];
    __syncthreads();
    int j = slice;
    for (; j + 3 * SL < m; j += 4 * SL) {
      int s0 = s_src[j], s1 = s_src[j + SL], s2 = s_src[j + 2 * SL], s3 = s_src[j + 3 * SL];
      uint u0 = mg[(size_t)s0 * C + col];
      uint u1 = mg[(size_t)s1 * C + col];
      uint u2 = mg[(size_t)s2 * C + col];
      uint u3 = mg[(size_t)s3 * C + col];
      accx += (__uint_as_float(u0 << 16) + __uint_as_float(u1 << 16)) +
              (__uint_as_float(u2 << 16) + __uint_as_float(u3 << 16));
      accy += (__uint_as_float(u0 & 0xFFFF0000u) + __uint_as_float(u1 & 0xFFFF0000u)) +
              (__uint_as_float(u2 & 0xFFFF0000u) + __uint_as_float(u3 & 0xFFFF0000u));
    }
    for (; j < m; j += SL) {
      uint u = mg[(size_t)s_src[j] * C + col];
      accx += __uint_as_float(u << 16);
      accy += __uint_as_float(u & 0xFFFF0000u);
    }
  }

  if constexpr (SL > 1) {
    __shared__ float sacc[2][256];
    sacc[0][tid] = accx;
    sacc[1][tid] = accy;
    __syncthreads();
    if (tid < C) {
#pragma unroll
      for (int s = 1; s < SL; s++) {
        accx += sacc[0][s * C + tid];
        accy += sacc[1][s * C + tid];
      }
    }
  }

  float a0 = 0.f, a1 = 0.f, hv0 = 0.f, hv1 = 0.f, sa = 0.f, sh = 0.f;
  if (tid < C) {
    a0 = fminf(fmaxf(accx * inv_dg, EPS), MAXV);
    a1 = fminf(fmaxf(accy * inv_dg, EPS), MAXV);
    if (!p1) { a0 = powf(a0, invp); a1 = powf(a1, invp); }
    float2 hx = h2[(size_t)n * C + tid];
    if constexpr (BN) {
      float2 s2 = ((const float2*)aff)[tid];
      float2 b2 = ((const float2*)(aff + D_H))[tid];
      hx.x = fmaxf(hx.x * s2.x + b2.x, 0.f);
      hx.y = fmaxf(hx.y * s2.y + b2.y, 0.f);
    }
    hv0 = hx.x;
    hv1 = hx.y;
    sa = a0 * a0 + a1 * a1;
    sh = hv0 * hv0 + hv1 * hv1;
  }
  for (int off = 32; off; off >>= 1) {
    sa += __shfl_down(sa, off);
    sh += __shfl_down(sh, off);
  }
  __shared__ float red[2][4];
  __shared__ float tot[2];
  int wid = tid >> 6;
  if ((tid & 63) == 0) { red[0][wid] = sa; red[1][wid] = sh; }
  __syncthreads();
  if (tid == 0) {
    tot[0] = red[0][0] + red[0][1] + red[0][2] + red[0][3];
    tot[1] = red[1][0] + red[1][1] + red[1][2] + red[1][3];
  }
  __syncthreads();
  float k = sqrtf(tot[1]) * scale / fmaxf(sqrtf(tot[0]), 1e-12f);
  if (tid < C) {
    __hip_bfloat162 o2;
    o2.x = __float2bfloat16(hv0 + a0 * k);
    o2.y = __float2bfloat16(hv1 + a1 * k);
    ((__hip_bfloat162*)out)[(size_t)n * C + tid] = o2;
  }
}

// ============ LDS-tiled convert + transpose: W[K][N] f32 -> Wt[N][K] bf16 ============
__global__ __launch_bounds__(256) void convert_wt(const float* __restrict__ W,
                                                  __hip_bfloat16* __restrict__ Wt,
                                                  int K, int N) {
  __shared__ float tile[32][33];
  int k0 = blockIdx.x * 32, n0 = blockIdx.y * 32;
  int tx = threadIdx.x & 31, ty = threadIdx.x >> 5;
  for (int i = ty; i < 32; i += 8)
    tile[i][tx] = W[(size_t)(k0 + i) * N + n0 + tx];
  __syncthreads();
  for (int i = ty; i < 32; i += 8)
    Wt[(size_t)(n0 + i) * K + k0 + tx] = __float2bfloat16(tile[tx][i]);
}

// ============ MFMA bf16 GEMM + fused column stats ============
__global__ __launch_bounds__(256) void mfma_gemm(
    const __hip_bfloat16* __restrict__ A, const __hip_bfloat16* __restrict__ Bt,
    const float* __restrict__ bias, float* __restrict__ C, float* __restrict__ stats,
    int M, int K) {
  __shared__ ushort As[128 * 64];
  __shared__ ushort Bs[128 * 64];
  __shared__ float sred[128][2];
  int tid = threadIdx.x;
  int l = tid & 63;
  int w = tid >> 6;
  int wm = w >> 1, wn = w & 1;
  int row0 = blockIdx.x * 128;
  int col0 = blockIdx.y * 128;

  f32x4 acc[4][4];
#pragma unroll
  for (int m = 0; m < 4; m++)
#pragma unroll
    for (int n = 0; n < 4; n++) acc[m][n] = (f32x4){0.f, 0.f, 0.f, 0.f};

  const ushort* Ag = (const ushort*)A;
  const ushort* Bg = (const ushort*)Bt;
  char* AsB = (char*)As;
  char* BsB = (char*)Bs;

  if (tid < 128) { sred[tid][0] = 0.f; sred[tid][1] = 0.f; }

  int srow = tid >> 3;
  int scb = (tid & 7) * 16;
  int wbyte = scb ^ ((srow & 7) << 4);
  int scol = scb >> 1;

  int lswz = (l & 7) << 4;
  int kb = (l >> 4) * 16;
  int arow = wm * 64 + (l & 15);
  int brow = wn * 64 + (l & 15);

  for (int k0 = 0; k0 < K; k0 += 64) {
    uint4 ra[4], rb[4];
#pragma unroll
    for (int j = 0; j < 4; j++) {
      int row = j * 32 + srow;
      ra[j] = *(const uint4*)(Ag + (size_t)(row0 + row) * K + k0 + scol);
      rb[j] = *(const uint4*)(Bg + (size_t)(col0 + row) * K + k0 + scol);
    }
#pragma unroll
    for (int j = 0; j < 4; j++) {
      int row = j * 32 + srow;
      *(uint4*)(AsB + row * 128 + wbyte) = ra[j];
      *(uint4*)(BsB + row * 128 + wbyte) = rb[j];
    }
    __syncthreads();
#pragma unroll
    for (int kk = 0; kk < 2; kk++) {
      bf16x8 af[4], bfr[4];
#pragma unroll
      for (int m = 0; m < 4; m++)
        af[m] = *(const bf16x8*)(AsB + (arow + m * 16) * 128 + ((kk * 64 + kb) ^ lswz));
#pragma unroll
      for (int n = 0; n < 4; n++)
        bfr[n] = *(const bf16x8*)(BsB + (brow + n * 16) * 128 + ((kk * 64 + kb) ^ lswz));
#pragma unroll
      for (int m = 0; m < 4; m++)
#pragma unroll
        for (int n = 0; n < 4; n++)
          acc[m][n] = __builtin_amdgcn_mfma_f32_16x16x32_bf16(af[m], bfr[n], acc[m][n], 0, 0, 0);
    }
    __syncthreads();
  }

  int crow0 = row0 + wm * 64 + (l >> 4) * 4;
  int ccol0 = col0 + wn * 64 + (l & 15);
#pragma unroll
  for (int n = 0; n < 4; n++) {
    int col = ccol0 + n * 16;
    float bv = bias[col];
    float ps = 0.f, pq = 0.f;
#pragma unroll
    for (int m = 0; m < 4; m++) {
#pragma unroll
      for (int r = 0; r < 4; r++) {
        int rr = crow0 + m * 16 + r;
        if (rr < M) {
          float v = acc[m][n][r] + bv;
          C[(size_t)rr * D_H + col] = v;
          ps += v;
          pq += v * v;
        }
      }
    }
    ps += __shfl_down(ps, 16); pq += __shfl_down(pq, 16);
    ps += __shfl_down(ps, 32); pq += __shfl_down(pq, 32);
    if ((l >> 4) == 0) {
      atomicAdd(&sred[wn * 64 + n * 16 + (l & 15)][0], ps);
      atomicAdd(&sred[wn * 64 + n * 16 + (l & 15)][1], pq);
    }
  }
  __syncthreads();
  if (tid < 128) {
    atomicAdd(&stats[col0 + tid], sred[tid][0]);
    atomicAdd(&stats[D_H + col0 + tid], sred[tid][1]);
  }
}

// ---------------- JK-max update + next-layer msg table ----------------
// v = relu(affine(hlin)); jk = max(jk, v); msgb = bf16(min(v+eps,MAXV)^p_next)
template <bool WRITE_MSG>
__global__ __launch_bounds__(256) void jk_msg_update(
    const float* __restrict__ hlin, const float* __restrict__ aff,
    float* __restrict__ jk, const float* __restrict__ p_ptr,
    __hip_bfloat16* __restrict__ msgb, int layer) {
  float p = 1.f;
  bool p1 = true;
  if constexpr (WRITE_MSG) {
    p = *p_ptr;
    p1 = (p == 1.0f);
  }
  const int total = N_NODES * D_H / 4;
  for (int idx = blockIdx.x * blockDim.x + threadIdx.x; idx < total;
       idx += gridDim.x * blockDim.x) {
    int c4 = idx & 127;  // float4 col index
    float4 x = ((const float4*)hlin)[idx];
    float4 sc = ((const float4*)aff)[c4];
    float4 sh = ((const float4*)(aff + D_H))[c4];
    float4 v;
    v.x = fmaxf(x.x * sc.x + sh.x, 0.f);
    v.y = fmaxf(x.y * sc.y + sh.y, 0.f);
    v.z = fmaxf(x.z * sc.z + sh.z, 0.f);
    v.w = fmaxf(x.w * sc.w + sh.w, 0.f);
    if constexpr (WRITE_MSG) {
      float m0 = fminf(v.x + EPS, MAXV);
      float m1 = fminf(v.y + EPS, MAXV);
      float m2 = fminf(v.z + EPS, MAXV);
      float m3 = fminf(v.w + EPS, MAXV);
      if (!p1) { m0 = powf(m0, p); m1 = powf(m1, p); m2 = powf(m2, p); m3 = powf(m3, p); }
      __hip_bfloat162 o01, o23;
      o01.x = __float2bfloat16(m0); o01.y = __float2bfloat16(m1);
      o23.x = __float2bfloat16(m2); o23.y = __float2bfloat16(m3);
      ((__hip_bfloat162*)msgb)[2 * idx] = o01;
      ((__hip_bfloat162*)msgb)[2 * idx + 1] = o23;
    }
    if (layer != 0) {
      float4 j = ((const float4*)jk)[idx];
      v.x = fmaxf(v.x, j.x);
      v.y = fmaxf(v.y, j.y);
      v.z = fmaxf(v.z, j.z);
      v.w = fmaxf(v.w, j.w);
    }
    ((float4*)jk)[idx] = v;
  }
}

// ---------------- per-graph max+mean pooling ----------------
__device__ __forceinline__ int lower_bound_i(const int* a, int n, int v) {
  int lo = 0, hi = n;
  while (lo < hi) {
    int mid = (lo + hi) >> 1;
    if (a[mid] < v) lo = mid + 1; else hi = mid;
  }
  return lo;
}

__global__ __launch_bounds__(256) void pool_kernel(const float* __restrict__ jk,
                                                   const int* __restrict__ batch,
                                                   float* __restrict__ g) {
  int gid = blockIdx.x;
  int col = blockIdx.y * 64 + (threadIdx.x & 63);
  int slice = threadIdx.x >> 6;
  int lo = lower_bound_i(batch, N_NODES, gid);
  int hi = lower_bound_i(batch, N_NODES, gid + 1);
  float mx = 0.f, sm = 0.f;
  int r = lo + slice;
  for (; r + 12 < hi; r += 16) {
    float v0 = jk[(size_t)r * D_H + col];
    float v1 = jk[(size_t)(r + 4) * D_H + col];
    float v2 = jk[(size_t)(r + 8) * D_H + col];
    float v3 = jk[(size_t)(r + 12) * D_H + col];
    mx = fmaxf(fmaxf(fmaxf(mx, v0), fmaxf(v1, v2)), v3);
    sm += (v0 + v1) + (v2 + v3);
  }
  for (; r < hi; r += 4) {
    float v = jk[(size_t)r * D_H + col];
    mx = fmaxf(mx, v);
    sm += v;
  }
  __shared__ float smax[4][64];
  __shared__ float ssum[4][64];
  smax[slice][threadIdx.x & 63] = mx;
  ssum[slice][threadIdx.x & 63] = sm;
  __syncthreads();
  if (slice == 0) {
    int c = threadIdx.x & 63;
    mx = fmaxf(fmaxf(smax[0][c], smax[1][c]), fmaxf(smax[2][c], smax[3][c]));
    sm = ssum[0][c] + ssum[1][c] + ssum[2][c] + ssum[3][c];
    float inv_cnt = 1.0f / fmaxf((float)(hi - lo), 1.0f);
    g[(size_t)gid * 1024 + col] = (hi > lo) ? mx : 0.f;
    g[(size_t)gid * 1024 + D_H + col] = sm * inv_cnt;
  }
}

// ---------------- fc1: [64,1024] @ [1024,512] + b ----------------
__global__ __launch_bounds__(512) void fc1_kernel(const float* __restrict__ g,
                                                  const float* __restrict__ W,
                                                  const float* __restrict__ b,
                                                  float* __restrict__ out) {
  __shared__ float sg[1024];
  int gid = blockIdx.x;
  for (int i = threadIdx.x; i < 1024; i += 512) sg[i] = g[(size_t)gid * 1024 + i];
  __syncthreads();
  int c = threadIdx.x;
  float acc = b[c];
  for (int k = 0; k < 1024; k++) acc += sg[k] * W[(size_t)k * D_H + c];
  out[(size_t)gid * D_H + c] = acc;
}

// ---------------- BN over 64 graphs + ReLU ----------------
__global__ __launch_bounds__(256) void bn4_kernel(const float* __restrict__ x,
                                                  const float* __restrict__ gmm,
                                                  const float* __restrict__ bb,
                                                  float* __restrict__ y) {
  int c = blockIdx.x * blockDim.x + threadIdx.x;
  if (c >= D_H) return;
  float s = 0.f, q = 0.f;
  for (int r = 0; r < N_GRAPHS; r++) {
    float v = x[(size_t)r * D_H + c];
    s += v; q += v * v;
  }
  float mean = s / (float)N_GRAPHS;
  float var = q / (float)N_GRAPHS - mean * mean;
  float rs = rsqrtf(var + BN_EPS) * gmm[c];
  for (int r = 0; r < N_GRAPHS; r++) {
    float v = (x[(size_t)r * D_H + c] - mean) * rs + bb[c];
    y[(size_t)r * D_H + c] = fmaxf(v, 0.f);
  }
}

// ---------------- fc2: [64,512] @ [512,2] + b ----------------
__global__ __launch_bounds__(64) void fc2_kernel(const float* __restrict__ y,
                                                 const float* __restrict__ W,
                                                 const float* __restrict__ b,
                                                 float* __restrict__ out) {
  int gid = blockIdx.x;
  int lane = threadIdx.x;
  float a0 = 0.f, a1 = 0.f;
  for (int k = lane; k < D_H; k += 64) {
    float v = y[(size_t)gid * D_H + k];
    a0 += v * W[k * 2 + 0];
    a1 += v * W[k * 2 + 1];
  }
  for (int off = 32; off; off >>= 1) {
    a0 += __shfl_down(a0, off);
    a1 += __shfl_down(a1, off);
  }
  if (lane == 0) {
    out[gid * 2 + 0] = a0 + b[0];
    out[gid * 2 + 1] = a1 + b[1];
  }
}

extern "C" void kernel_launch(void* const* d_in, const int* in_sizes, int n_in,
                              void* d_out, int out_size, void* d_ws, size_t ws_size,
                              hipStream_t stream) {
  const float* x       = (const float*)d_in[0];
  const float* W0      = (const float*)d_in[1];
  const float* Wrest   = (const float*)d_in[2];
  const float* bconv   = (const float*)d_in[3];
  const float* p       = (const float*)d_in[4];
  const float* mscale  = (const float*)d_in[5];
  const float* bn_g    = (const float*)d_in[6];
  const float* bn_b    = (const float*)d_in[7];
  const float* fc1_W   = (const float*)d_in[8];
  const float* fc1_b   = (const float*)d_in[9];
  const float* bn4_g   = (const float*)d_in[10];
  const float* bn4_b   = (const float*)d_in[11];
  const float* fc2_W   = (const float*)d_in[12];
  const float* fc2_b   = (const float*)d_in[13];
  const int*   eidx    = (const int*)d_in[14];
  const int*   batch   = (const int*)d_in[15];
  float* out = (float*)d_out;

  const int* src = eidx;
  const int* dst = eidx + N_EDGES;

  float* ws = (float*)d_ws;
  const size_t NH = (size_t)N_NODES * D_H;
  float* hlin  = ws;
  float* jk    = hlin + NH;
  float* stats = jk + NH;                          // 1024
  float* aff   = stats + 1024;                     // 1024
  __hip_bfloat16* residb = (__hip_bfloat16*)(aff + 1024);    // [M_PAD][512] bf16
  __hip_bfloat16* msgb = residb + (size_t)M_PAD * D_H;       // [N_NODES][512] bf16
  __hip_bfloat16* w0t = msgb + NH;
  __hip_bfloat16* w1t = w0t + 512 * 128;
  __hip_bfloat16* w2t = w1t + 512 * 512;
  int* cnt     = (int*)(w2t + 512 * 512);
  int* rowptr  = cnt + N_NODES;
  int* csr_src = rowptr + N_NODES + 1;
  float* g     = (float*)(csr_src + N_EDGES);
  float* g2lin = g + 64 * 1024;
  float* g2    = g2lin + 64 * D_H;

  // ---- weight convert+transpose (bf16, LDS-tiled) ----
  convert_wt<<<dim3(D_INPUT / 32, D_H / 32), 256, 0, stream>>>(W0, w0t, D_INPUT, D_H);
  convert_wt<<<dim3(D_H / 32, D_H / 32), 256, 0, stream>>>(Wrest, w1t, D_H, D_H);
  convert_wt<<<dim3(D_H / 32, D_H / 32), 256, 0, stream>>>(Wrest + (size_t)D_H * D_H, w2t, D_H, D_H);

  // ---- build CSR ----
  hipMemsetAsync(cnt, 0, N_NODES * sizeof(int), stream);
  hist_kernel<<<(N_EDGES + 255) / 256, 256, 0, stream>>>(dst, cnt);
  scan_kernel<<<1, 256, 0, stream>>>(cnt, rowptr);
  hipMemsetAsync(cnt, 0, N_NODES * sizeof(int), stream);
  scatter_kernel<<<(N_EDGES + 255) / 256, 256, 0, stream>>>(src, dst, rowptr, cnt, csr_src);

  // ---- layer-0 message table ----
  msg0_kernel<<<1280, 256, 0, stream>>>(x, p, msgb);

  for (int layer = 0; layer < 3; layer++) {
    if (layer == 0)
      agg_msgnorm_kernel<D_INPUT, false><<<N_NODES, 256, 0, stream>>>(
          x, nullptr, msgb, rowptr, csr_src, p + layer, mscale + layer, residb);
    else
      agg_msgnorm_kernel<D_H, true><<<N_NODES, 256, 0, stream>>>(
          hlin, aff, msgb, rowptr, csr_src, p + layer, mscale + layer, residb);
    const __hip_bfloat16* Wt = (layer == 0) ? w0t : (layer == 1 ? w1t : w2t);
    int K = (layer == 0) ? D_INPUT : D_H;
    hipMemsetAsync(stats, 0, 1024 * sizeof(float), stream);
    mfma_gemm<<<dim3(M_PAD / 128, D_H / 128), 256, 0, stream>>>(
        residb, Wt, bconv + (size_t)layer * D_H, hlin, stats, N_NODES, K);
    bn_affine<<<1, 512, 0, stream>>>(stats, bn_g + (size_t)layer * D_H,
                                     bn_b + (size_t)layer * D_H, aff);
    if (layer < 2)
      jk_msg_update<true><<<2048, 256, 0, stream>>>(hlin, aff, jk, p + layer + 1, msgb, layer);
    else
      jk_msg_update<false><<<2048, 256, 0, stream>>>(hlin, aff, jk, nullptr, nullptr, layer);
  }

  pool_kernel<<<dim3(N_GRAPHS, 8), 256, 0, stream>>>(jk, batch, g);
  fc1_kernel<<<N_GRAPHS, 512, 0, stream>>>(g, fc1_W, fc1_b, g2lin);
  bn4_kernel<<<2, 256, 0, stream>>>(g2lin, bn4_g, bn4_b, g2);
  fc2_kernel<<<N_GRAPHS, 64, 0, stream>>>(g2, fc2_W, fc2_b, out);
}

// Round 7
// 286.603 us; speedup vs baseline: 10.3744x; 1.0365x over previous
//
#include <hip/hip_runtime.h>
#include <hip/hip_bf16.h>
#include <math.h>

#define N_NODES 10000
#define N_GRAPHS 64
#define N_EDGES 160000
#define D_INPUT 128
#define D_H 512
#define EPS 1e-7f
#define MAXV 10.0f
#define BN_EPS 1e-5f
#define M_PAD 10112  // 79 * 128

typedef __attribute__((ext_vector_type(4))) float f32x4;
typedef __attribute__((ext_vector_type(8))) __bf16 bf16x8;

// ================= CSR build =================
__global__ __launch_bounds__(256) void hist_kernel(const int* __restrict__ dst,
                                                   int* __restrict__ cnt) {
  int i = blockIdx.x * blockDim.x + threadIdx.x;
  if (i < N_EDGES) atomicAdd(&cnt[dst[i]], 1);
}

// scan also zeroes cnt after final read so scatter's cursor starts at 0
__global__ __launch_bounds__(256) void scan_kernel(int* __restrict__ cnt,
                                                   int* __restrict__ rowptr) {
  __shared__ int ps[256];
  int tid = threadIdx.x;
  const int CH = (N_NODES + 255) / 256;
  int b0 = tid * CH;
  int b1 = min(N_NODES, b0 + CH);
  int s = 0;
  for (int i = b0; i < b1; i++) s += cnt[i];
  ps[tid] = s;
  __syncthreads();
  for (int off = 1; off < 256; off <<= 1) {
    int v = (tid >= off) ? ps[tid - off] : 0;
    __syncthreads();
    ps[tid] += v;
    __syncthreads();
  }
  int run = (tid == 0) ? 0 : ps[tid - 1];
  for (int i = b0; i < b1; i++) {
    rowptr[i] = run;
    run += cnt[i];
    cnt[i] = 0;
  }
  if (tid == 255) rowptr[N_NODES] = run;
}

__global__ __launch_bounds__(256) void scatter_kernel(
    const int* __restrict__ src, const int* __restrict__ dst,
    const int* __restrict__ rowptr, int* __restrict__ cursor,
    int* __restrict__ csr_src) {
  int i = blockIdx.x * blockDim.x + threadIdx.x;
  if (i < N_EDGES) {
    int t = dst[i];
    int pos = rowptr[t] + atomicAdd(&cursor[t], 1);
    csr_src[pos] = src[i];
  }
}

// ============ BN affine params; zeroes stats for the next layer ============
__global__ __launch_bounds__(512) void bn_affine(float* __restrict__ stats,
                                                 const float* __restrict__ gamma,
                                                 const float* __restrict__ beta,
                                                 float* __restrict__ aff) {
  int c = threadIdx.x;
  const float invN = 1.0f / (float)N_NODES;
  float mean = stats[c] * invN;
  float var = stats[D_H + c] * invN - mean * mean;
  float sc = rsqrtf(var + BN_EPS) * gamma[c];
  aff[c] = sc;
  aff[D_H + c] = beta[c] - mean * sc;
  stats[c] = 0.f;
  stats[D_H + c] = 0.f;
}

// ============ layer-0 message table: msgb = bf16(min(relu(x)+eps,MAXV)^p) ============
__global__ __launch_bounds__(256) void msg0_kernel(const float* __restrict__ x,
                                                   const float* __restrict__ p_ptr,
                                                   __hip_bfloat16* __restrict__ msgb) {
  float p = *p_ptr;
  bool p1 = (p == 1.0f);
  const int total = N_NODES * D_INPUT / 2;
  for (int i = blockIdx.x * 256 + threadIdx.x; i < total; i += gridDim.x * 256) {
    float2 v = ((const float2*)x)[i];
    float m0 = fminf(fmaxf(v.x, 0.f) + EPS, MAXV);
    float m1 = fminf(fmaxf(v.y, 0.f) + EPS, MAXV);
    if (!p1) { m0 = powf(m0, p); m1 = powf(m1, p); }
    __hip_bfloat162 o;
    o.x = __float2bfloat16(m0);
    o.y = __float2bfloat16(m1);
    ((__hip_bfloat162*)msgb)[i] = o;
  }
}

// ============ fused: CSR aggregation (bf16 msg table) + power-mean
//              + MessageNorm + residual (bf16 out) ============
template <int D, bool BN>
__global__ __launch_bounds__(256) void agg_msgnorm_kernel(
    const float* __restrict__ h, const float* __restrict__ aff,
    const __hip_bfloat16* __restrict__ msgb,
    const int* __restrict__ rowptr, const int* __restrict__ csr_src,
    const float* __restrict__ p_ptr, const float* __restrict__ scale_ptr,
    __hip_bfloat16* __restrict__ out) {
  constexpr int C = D / 2;        // bf16-pair columns (64 or 256)
  constexpr int SL = 256 / C;     // edge slices (4 or 1)
  int n = blockIdx.x;
  int tid = threadIdx.x;
  int col = tid % C;
  int slice = tid / C;
  int lo = rowptr[n], hi = rowptr[n + 1];
  float p = *p_ptr;
  float scale = *scale_ptr;
  bool p1 = (p == 1.0f);
  float invp = 1.0f / p;
  float inv_dg = 1.0f / fmaxf((float)(hi - lo), 1.0f);
  const float2* h2 = (const float2*)h;
  const uint* mg = (const uint*)msgb;

  __shared__ int s_src[256];
  float accx = 0.f, accy = 0.f;
  for (int base = lo; base < hi; base += 256) {
    int m = min(256, hi - base);
    __syncthreads();
    if (tid < m) s_src[tid] = csr_src[base + tid];
    __syncthreads();
    int j = slice;
    for (; j + 3 * SL < m; j += 4 * SL) {
      int s0 = s_src[j], s1 = s_src[j + SL], s2 = s_src[j + 2 * SL], s3 = s_src[j + 3 * SL];
      uint u0 = mg[(size_t)s0 * C + col];
      uint u1 = mg[(size_t)s1 * C + col];
      uint u2 = mg[(size_t)s2 * C + col];
      uint u3 = mg[(size_t)s3 * C + col];
      accx += (__uint_as_float(u0 << 16) + __uint_as_float(u1 << 16)) +
              (__uint_as_float(u2 << 16) + __uint_as_float(u3 << 16));
      accy += (__uint_as_float(u0 & 0xFFFF0000u) + __uint_as_float(u1 & 0xFFFF0000u)) +
              (__uint_as_float(u2 & 0xFFFF0000u) + __uint_as_float(u3 & 0xFFFF0000u));
    }
    for (; j < m; j += SL) {
      uint u = mg[(size_t)s_src[j] * C + col];
      accx += __uint_as_float(u << 16);
      accy += __uint_as_float(u & 0xFFFF0000u);
    }
  }

  if constexpr (SL > 1) {
    __shared__ float sacc[2][256];
    sacc[0][tid] = accx;
    sacc[1][tid] = accy;
    __syncthreads();
    if (tid < C) {
#pragma unroll
      for (int s = 1; s < SL; s++) {
        accx += sacc[0][s * C + tid];
        accy += sacc[1][s * C + tid];
      }
    }
  }

  float a0 = 0.f, a1 = 0.f, hv0 = 0.f, hv1 = 0.f, sa = 0.f, sh = 0.f;
  if (tid < C) {
    a0 = fminf(fmaxf(accx * inv_dg, EPS), MAXV);
    a1 = fminf(fmaxf(accy * inv_dg, EPS), MAXV);
    if (!p1) { a0 = powf(a0, invp); a1 = powf(a1, invp); }
    float2 hx = h2[(size_t)n * C + tid];
    if constexpr (BN) {
      float2 s2 = ((const float2*)aff)[tid];
      float2 b2 = ((const float2*)(aff + D_H))[tid];
      hx.x = fmaxf(hx.x * s2.x + b2.x, 0.f);
      hx.y = fmaxf(hx.y * s2.y + b2.y, 0.f);
    }
    hv0 = hx.x;
    hv1 = hx.y;
    sa = a0 * a0 + a1 * a1;
    sh = hv0 * hv0 + hv1 * hv1;
  }
  for (int off = 32; off; off >>= 1) {
    sa += __shfl_down(sa, off);
    sh += __shfl_down(sh, off);
  }
  __shared__ float red[2][4];
  __shared__ float tot[2];
  int wid = tid >> 6;
  if ((tid & 63) == 0) { red[0][wid] = sa; red[1][wid] = sh; }
  __syncthreads();
  if (tid == 0) {
    tot[0] = red[0][0] + red[0][1] + red[0][2] + red[0][3];
    tot[1] = red[1][0] + red[1][1] + red[1][2] + red[1][3];
  }
  __syncthreads();
  float k = sqrtf(tot[1]) * scale / fmaxf(sqrtf(tot[0]), 1e-12f);
  if (tid < C) {
    __hip_bfloat162 o2;
    o2.x = __float2bfloat16(hv0 + a0 * k);
    o2.y = __float2bfloat16(hv1 + a1 * k);
    ((__hip_bfloat162*)out)[(size_t)n * C + tid] = o2;
  }
}

// ============ LDS-tiled convert + transpose: W[K][N] f32 -> Wt[N][K] bf16 ============
__global__ __launch_bounds__(256) void convert_wt(const float* __restrict__ W,
                                                  __hip_bfloat16* __restrict__ Wt,
                                                  int K, int N) {
  __shared__ float tile[32][33];
  int k0 = blockIdx.x * 32, n0 = blockIdx.y * 32;
  int tx = threadIdx.x & 31, ty = threadIdx.x >> 5;
  for (int i = ty; i < 32; i += 8)
    tile[i][tx] = W[(size_t)(k0 + i) * N + n0 + tx];
  __syncthreads();
  for (int i = ty; i < 32; i += 8)
    Wt[(size_t)(n0 + i) * K + k0 + tx] = __float2bfloat16(tile[tx][i]);
}

// ============ MFMA bf16 GEMM + fused column stats ============
__global__ __launch_bounds__(256) void mfma_gemm(
    const __hip_bfloat16* __restrict__ A, const __hip_bfloat16* __restrict__ Bt,
    const float* __restrict__ bias, float* __restrict__ C, float* __restrict__ stats,
    int M, int K) {
  __shared__ ushort As[128 * 64];
  __shared__ ushort Bs[128 * 64];
  __shared__ float sred[128][2];
  int tid = threadIdx.x;
  int l = tid & 63;
  int w = tid >> 6;
  int wm = w >> 1, wn = w & 1;
  int row0 = blockIdx.x * 128;
  int col0 = blockIdx.y * 128;

  f32x4 acc[4][4];
#pragma unroll
  for (int m = 0; m < 4; m++)
#pragma unroll
    for (int n = 0; n < 4; n++) acc[m][n] = (f32x4){0.f, 0.f, 0.f, 0.f};

  const ushort* Ag = (const ushort*)A;
  const ushort* Bg = (const ushort*)Bt;
  char* AsB = (char*)As;
  char* BsB = (char*)Bs;

  if (tid < 128) { sred[tid][0] = 0.f; sred[tid][1] = 0.f; }

  int srow = tid >> 3;
  int scb = (tid & 7) * 16;
  int wbyte = scb ^ ((srow & 7) << 4);
  int scol = scb >> 1;

  int lswz = (l & 7) << 4;
  int kb = (l >> 4) * 16;
  int arow = wm * 64 + (l & 15);
  int brow = wn * 64 + (l & 15);

  for (int k0 = 0; k0 < K; k0 += 64) {
    uint4 ra[4], rb[4];
#pragma unroll
    for (int j = 0; j < 4; j++) {
      int row = j * 32 + srow;
      ra[j] = *(const uint4*)(Ag + (size_t)(row0 + row) * K + k0 + scol);
      rb[j] = *(const uint4*)(Bg + (size_t)(col0 + row) * K + k0 + scol);
    }
#pragma unroll
    for (int j = 0; j < 4; j++) {
      int row = j * 32 + srow;
      *(uint4*)(AsB + row * 128 + wbyte) = ra[j];
      *(uint4*)(BsB + row * 128 + wbyte) = rb[j];
    }
    __syncthreads();
#pragma unroll
    for (int kk = 0; kk < 2; kk++) {
      bf16x8 af[4], bfr[4];
#pragma unroll
      for (int m = 0; m < 4; m++)
        af[m] = *(const bf16x8*)(AsB + (arow + m * 16) * 128 + ((kk * 64 + kb) ^ lswz));
#pragma unroll
      for (int n = 0; n < 4; n++)
        bfr[n] = *(const bf16x8*)(BsB + (brow + n * 16) * 128 + ((kk * 64 + kb) ^ lswz));
#pragma unroll
      for (int m = 0; m < 4; m++)
#pragma unroll
        for (int n = 0; n < 4; n++)
          acc[m][n] = __builtin_amdgcn_mfma_f32_16x16x32_bf16(af[m], bfr[n], acc[m][n], 0, 0, 0);
    }
    __syncthreads();
  }

  int crow0 = row0 + wm * 64 + (l >> 4) * 4;
  int ccol0 = col0 + wn * 64 + (l & 15);
#pragma unroll
  for (int n = 0; n < 4; n++) {
    int col = ccol0 + n * 16;
    float bv = bias[col];
    float ps = 0.f, pq = 0.f;
#pragma unroll
    for (int m = 0; m < 4; m++) {
#pragma unroll
      for (int r = 0; r < 4; r++) {
        int rr = crow0 + m * 16 + r;
        if (rr < M) {
          float v = acc[m][n][r] + bv;
          C[(size_t)rr * D_H + col] = v;
          ps += v;
          pq += v * v;
        }
      }
    }
    ps += __shfl_down(ps, 16); pq += __shfl_down(pq, 16);
    ps += __shfl_down(ps, 32); pq += __shfl_down(pq, 32);
    if ((l >> 4) == 0) {
      atomicAdd(&sred[wn * 64 + n * 16 + (l & 15)][0], ps);
      atomicAdd(&sred[wn * 64 + n * 16 + (l & 15)][1], pq);
    }
  }
  __syncthreads();
  if (tid < 128) {
    atomicAdd(&stats[col0 + tid], sred[tid][0]);
    atomicAdd(&stats[D_H + col0 + tid], sred[tid][1]);
  }
}

// ---------------- JK-max update + next-layer msg table ----------------
template <bool WRITE_MSG>
__global__ __launch_bounds__(256) void jk_msg_update(
    const float* __restrict__ hlin, const float* __restrict__ aff,
    float* __restrict__ jk, const float* __restrict__ p_ptr,
    __hip_bfloat16* __restrict__ msgb, int layer) {
  float p = 1.f;
  bool p1 = true;
  if constexpr (WRITE_MSG) {
    p = *p_ptr;
    p1 = (p == 1.0f);
  }
  const int total = N_NODES * D_H / 4;
  for (int idx = blockIdx.x * blockDim.x + threadIdx.x; idx < total;
       idx += gridDim.x * blockDim.x) {
    int c4 = idx & 127;
    float4 x = ((const float4*)hlin)[idx];
    float4 sc = ((const float4*)aff)[c4];
    float4 sh = ((const float4*)(aff + D_H))[c4];
    float4 v;
    v.x = fmaxf(x.x * sc.x + sh.x, 0.f);
    v.y = fmaxf(x.y * sc.y + sh.y, 0.f);
    v.z = fmaxf(x.z * sc.z + sh.z, 0.f);
    v.w = fmaxf(x.w * sc.w + sh.w, 0.f);
    if constexpr (WRITE_MSG) {
      float m0 = fminf(v.x + EPS, MAXV);
      float m1 = fminf(v.y + EPS, MAXV);
      float m2 = fminf(v.z + EPS, MAXV);
      float m3 = fminf(v.w + EPS, MAXV);
      if (!p1) { m0 = powf(m0, p); m1 = powf(m1, p); m2 = powf(m2, p); m3 = powf(m3, p); }
      __hip_bfloat162 o01, o23;
      o01.x = __float2bfloat16(m0); o01.y = __float2bfloat16(m1);
      o23.x = __float2bfloat16(m2); o23.y = __float2bfloat16(m3);
      ((__hip_bfloat162*)msgb)[2 * idx] = o01;
      ((__hip_bfloat162*)msgb)[2 * idx + 1] = o23;
    }
    if (layer != 0) {
      float4 j = ((const float4*)jk)[idx];
      v.x = fmaxf(v.x, j.x);
      v.y = fmaxf(v.y, j.y);
      v.z = fmaxf(v.z, j.z);
      v.w = fmaxf(v.w, j.w);
    }
    ((float4*)jk)[idx] = v;
  }
}

// ---------------- per-graph max+mean pooling ----------------
__device__ __forceinline__ int lower_bound_i(const int* a, int n, int v) {
  int lo = 0, hi = n;
  while (lo < hi) {
    int mid = (lo + hi) >> 1;
    if (a[mid] < v) lo = mid + 1; else hi = mid;
  }
  return lo;
}

__global__ __launch_bounds__(256) void pool_kernel(const float* __restrict__ jk,
                                                   const int* __restrict__ batch,
                                                   float* __restrict__ g) {
  int gid = blockIdx.x;
  int col = blockIdx.y * 64 + (threadIdx.x & 63);
  int slice = threadIdx.x >> 6;
  int lo = lower_bound_i(batch, N_NODES, gid);
  int hi = lower_bound_i(batch, N_NODES, gid + 1);
  float mx = 0.f, sm = 0.f;
  int r = lo + slice;
  for (; r + 12 < hi; r += 16) {
    float v0 = jk[(size_t)r * D_H + col];
    float v1 = jk[(size_t)(r + 4) * D_H + col];
    float v2 = jk[(size_t)(r + 8) * D_H + col];
    float v3 = jk[(size_t)(r + 12) * D_H + col];
    mx = fmaxf(fmaxf(fmaxf(mx, v0), fmaxf(v1, v2)), v3);
    sm += (v0 + v1) + (v2 + v3);
  }
  for (; r < hi; r += 4) {
    float v = jk[(size_t)r * D_H + col];
    mx = fmaxf(mx, v);
    sm += v;
  }
  __shared__ float smax[4][64];
  __shared__ float ssum[4][64];
  smax[slice][threadIdx.x & 63] = mx;
  ssum[slice][threadIdx.x & 63] = sm;
  __syncthreads();
  if (slice == 0) {
    int c = threadIdx.x & 63;
    mx = fmaxf(fmaxf(smax[0][c], smax[1][c]), fmaxf(smax[2][c], smax[3][c]));
    sm = ssum[0][c] + ssum[1][c] + ssum[2][c] + ssum[3][c];
    float inv_cnt = 1.0f / fmaxf((float)(hi - lo), 1.0f);
    g[(size_t)gid * 1024 + col] = (hi > lo) ? mx : 0.f;
    g[(size_t)gid * 1024 + D_H + col] = sm * inv_cnt;
  }
}

// ---------------- fc1: [64,1024] @ [1024,512] + b ----------------
// grid (graph, 8 col-chunks) x 256 = 64 cols x 4 K-slices of 256
__global__ __launch_bounds__(256) void fc1_kernel(const float* __restrict__ g,
                                                  const float* __restrict__ W,
                                                  const float* __restrict__ b,
                                                  float* __restrict__ out) {
  __shared__ float sg[1024];
  __shared__ float sred[4][64];
  int gid = blockIdx.x;
  int tid = threadIdx.x;
  ((float4*)sg)[tid] = ((const float4*)(g + (size_t)gid * 1024))[tid];
  __syncthreads();
  int cl = tid & 63;
  int slice = tid >> 6;
  int col = blockIdx.y * 64 + cl;
  int k0 = slice * 256;
  float acc = 0.f;
#pragma unroll 4
  for (int k = k0; k < k0 + 256; k++) acc += sg[k] * W[(size_t)k * D_H + col];
  sred[slice][cl] = acc;
  __syncthreads();
  if (slice == 0)
    out[(size_t)gid * D_H + col] =
        sred[0][cl] + sred[1][cl] + sred[2][cl] + sred[3][cl] + b[col];
}

// ---------------- BN over 64 graphs + ReLU: 8 blocks x (64 cols x 4 row-slices) ----------------
__global__ __launch_bounds__(256) void bn4_kernel(const float* __restrict__ x,
                                                  const float* __restrict__ gmm,
                                                  const float* __restrict__ bb,
                                                  float* __restrict__ y) {
  int cl = threadIdx.x & 63;
  int slice = threadIdx.x >> 6;
  int c = blockIdx.x * 64 + cl;
  float s = 0.f, q = 0.f;
#pragma unroll
  for (int r = slice * 16; r < slice * 16 + 16; r++) {
    float v = x[(size_t)r * D_H + c];
    s += v; q += v * v;
  }
  __shared__ float ss[4][64], sq[4][64];
  ss[slice][cl] = s;
  sq[slice][cl] = q;
  __syncthreads();
  float S = ss[0][cl] + ss[1][cl] + ss[2][cl] + ss[3][cl];
  float Q = sq[0][cl] + sq[1][cl] + sq[2][cl] + sq[3][cl];
  float mean = S * (1.0f / N_GRAPHS);
  float var = Q * (1.0f / N_GRAPHS) - mean * mean;
  float rs = rsqrtf(var + BN_EPS) * gmm[c];
  float sh = bb[c] - mean * rs;
#pragma unroll
  for (int r = slice * 16; r < slice * 16 + 16; r++)
    y[(size_t)r * D_H + c] = fmaxf(x[(size_t)r * D_H + c] * rs + sh, 0.f);
}

// ---------------- fc2: [64,512] @ [512,2] + b ----------------
__global__ __launch_bounds__(64) void fc2_kernel(const float* __restrict__ y,
                                                 const float* __restrict__ W,
                                                 const float* __restrict__ b,
                                                 float* __restrict__ out) {
  int gid = blockIdx.x;
  int lane = threadIdx.x;
  float a0 = 0.f, a1 = 0.f;
  for (int k = lane; k < D_H; k += 64) {
    float v = y[(size_t)gid * D_H + k];
    a0 += v * W[k * 2 + 0];
    a1 += v * W[k * 2 + 1];
  }
  for (int off = 32; off; off >>= 1) {
    a0 += __shfl_down(a0, off);
    a1 += __shfl_down(a1, off);
  }
  if (lane == 0) {
    out[gid * 2 + 0] = a0 + b[0];
    out[gid * 2 + 1] = a1 + b[1];
  }
}

extern "C" void kernel_launch(void* const* d_in, const int* in_sizes, int n_in,
                              void* d_out, int out_size, void* d_ws, size_t ws_size,
                              hipStream_t stream) {
  const float* x       = (const float*)d_in[0];
  const float* W0      = (const float*)d_in[1];
  const float* Wrest   = (const float*)d_in[2];
  const float* bconv   = (const float*)d_in[3];
  const float* p       = (const float*)d_in[4];
  const float* mscale  = (const float*)d_in[5];
  const float* bn_g    = (const float*)d_in[6];
  const float* bn_b    = (const float*)d_in[7];
  const float* fc1_W   = (const float*)d_in[8];
  const float* fc1_b   = (const float*)d_in[9];
  const float* bn4_g   = (const float*)d_in[10];
  const float* bn4_b   = (const float*)d_in[11];
  const float* fc2_W   = (const float*)d_in[12];
  const float* fc2_b   = (const float*)d_in[13];
  const int*   eidx    = (const int*)d_in[14];
  const int*   batch   = (const int*)d_in[15];
  float* out = (float*)d_out;

  const int* src = eidx;
  const int* dst = eidx + N_EDGES;

  float* ws = (float*)d_ws;
  const size_t NH = (size_t)N_NODES * D_H;
  float* hlin  = ws;
  float* jk    = hlin + NH;
  float* stats = jk + NH;                          // 1024
  float* aff   = stats + 1024;                     // 1024
  __hip_bfloat16* residb = (__hip_bfloat16*)(aff + 1024);    // [M_PAD][512] bf16
  __hip_bfloat16* msgb = residb + (size_t)M_PAD * D_H;       // [N_NODES][512] bf16
  __hip_bfloat16* w0t = msgb + NH;
  __hip_bfloat16* w1t = w0t + 512 * 128;
  __hip_bfloat16* w2t = w1t + 512 * 512;
  int* cnt     = (int*)(w2t + 512 * 512);
  int* rowptr  = cnt + N_NODES;
  int* csr_src = rowptr + N_NODES + 1;
  float* g     = (float*)(csr_src + N_EDGES);
  float* g2lin = g + 64 * 1024;
  float* g2    = g2lin + 64 * D_H;

  // ---- weight convert+transpose (bf16, LDS-tiled) ----
  convert_wt<<<dim3(D_INPUT / 32, D_H / 32), 256, 0, stream>>>(W0, w0t, D_INPUT, D_H);
  convert_wt<<<dim3(D_H / 32, D_H / 32), 256, 0, stream>>>(Wrest, w1t, D_H, D_H);
  convert_wt<<<dim3(D_H / 32, D_H / 32), 256, 0, stream>>>(Wrest + (size_t)D_H * D_H, w2t, D_H, D_H);

  // ---- build CSR (scan zeroes cnt for scatter's cursor) ----
  hipMemsetAsync(cnt, 0, N_NODES * sizeof(int), stream);
  hist_kernel<<<(N_EDGES + 255) / 256, 256, 0, stream>>>(dst, cnt);
  scan_kernel<<<1, 256, 0, stream>>>(cnt, rowptr);
  scatter_kernel<<<(N_EDGES + 255) / 256, 256, 0, stream>>>(src, dst, rowptr, cnt, csr_src);

  // ---- layer-0 message table; zero stats once (bn_affine re-zeroes per layer) ----
  hipMemsetAsync(stats, 0, 1024 * sizeof(float), stream);
  msg0_kernel<<<1280, 256, 0, stream>>>(x, p, msgb);

  for (int layer = 0; layer < 3; layer++) {
    if (layer == 0)
      agg_msgnorm_kernel<D_INPUT, false><<<N_NODES, 256, 0, stream>>>(
          x, nullptr, msgb, rowptr, csr_src, p + layer, mscale + layer, residb);
    else
      agg_msgnorm_kernel<D_H, true><<<N_NODES, 256, 0, stream>>>(
          hlin, aff, msgb, rowptr, csr_src, p + layer, mscale + layer, residb);
    const __hip_bfloat16* Wt = (layer == 0) ? w0t : (layer == 1 ? w1t : w2t);
    int K = (layer == 0) ? D_INPUT : D_H;
    mfma_gemm<<<dim3(M_PAD / 128, D_H / 128), 256, 0, stream>>>(
        residb, Wt, bconv + (size_t)layer * D_H, hlin, stats, N_NODES, K);
    bn_affine<<<1, 512, 0, stream>>>(stats, bn_g + (size_t)layer * D_H,
                                     bn_b + (size_t)layer * D_H, aff);
    if (layer < 2)
      jk_msg_update<true><<<2048, 256, 0, stream>>>(hlin, aff, jk, p + layer + 1, msgb, layer);
    else
      jk_msg_update<false><<<2048, 256, 0, stream>>>(hlin, aff, jk, nullptr, nullptr, layer);
  }

  pool_kernel<<<dim3(N_GRAPHS, 8), 256, 0, stream>>>(jk, batch, g);
  fc1_kernel<<<dim3(N_GRAPHS, 8), 256, 0, stream>>>(g, fc1_W, fc1_b, g2lin);
  bn4_kernel<<<8, 256, 0, stream>>>(g2lin, bn4_g, bn4_b, g2);
  fc2_kernel<<<N_GRAPHS, 64, 0, stream>>>(g2, fc2_W, fc2_b, out);
}

// Round 8
// 279.142 us; speedup vs baseline: 10.6516x; 1.0267x over previous
//
#include <hip/hip_runtime.h>
#include <hip/hip_bf16.h>
#include <math.h>

#define N_NODES 10000
#define N_GRAPHS 64
#define N_EDGES 160000
#define D_INPUT 128
#define D_H 512
#define EPS 1e-7f
#define MAXV 10.0f
#define BN_EPS 1e-5f
#define M_PAD 10112  // 79 * 128

typedef __attribute__((ext_vector_type(4))) float f32x4;
typedef __attribute__((ext_vector_type(8))) __bf16 bf16x8;

__device__ __forceinline__ float bf_lo(uint u) { return __uint_as_float(u << 16); }
__device__ __forceinline__ float bf_hi(uint u) { return __uint_as_float(u & 0xFFFF0000u); }

// ================= CSR build =================
__global__ __launch_bounds__(256) void hist_kernel(const int* __restrict__ dst,
                                                   int* __restrict__ cnt) {
  int i = blockIdx.x * blockDim.x + threadIdx.x;
  if (i < N_EDGES) atomicAdd(&cnt[dst[i]], 1);
}

// single-block scan; reads cnt via int4, writes rowptr via int4, zeroes cnt
__global__ __launch_bounds__(256) void scan_kernel(int* __restrict__ cnt,
                                                   int* __restrict__ rowptr) {
  __shared__ int ps[256];
  int tid = threadIdx.x;
  const int CH = 40;  // 250 threads x 40 = 10000
  int b0 = tid * CH;
  bool active = (b0 < N_NODES);
  int v[CH];
  int s = 0;
  if (active) {
    const int4* c4p = (const int4*)(cnt + b0);
#pragma unroll
    for (int i = 0; i < CH / 4; i++) {
      int4 q = c4p[i];
      v[4 * i] = q.x; v[4 * i + 1] = q.y; v[4 * i + 2] = q.z; v[4 * i + 3] = q.w;
      s += q.x + q.y + q.z + q.w;
    }
  }
  ps[tid] = s;
  __syncthreads();
  for (int off = 1; off < 256; off <<= 1) {
    int t = (tid >= off) ? ps[tid - off] : 0;
    __syncthreads();
    ps[tid] += t;
    __syncthreads();
  }
  int run = (tid == 0) ? 0 : ps[tid - 1];
  if (active) {
    int r[CH];
#pragma unroll
    for (int i = 0; i < CH; i++) { r[i] = run; run += v[i]; }
    int4* rp = (int4*)(rowptr + b0);
    int4* cz = (int4*)(cnt + b0);
#pragma unroll
    for (int i = 0; i < CH / 4; i++) {
      rp[i] = make_int4(r[4 * i], r[4 * i + 1], r[4 * i + 2], r[4 * i + 3]);
      cz[i] = make_int4(0, 0, 0, 0);
    }
  }
  if (tid == 255) rowptr[N_NODES] = ps[255];
}

__global__ __launch_bounds__(256) void scatter_kernel(
    const int* __restrict__ src, const int* __restrict__ dst,
    const int* __restrict__ rowptr, int* __restrict__ cursor,
    int* __restrict__ csr_src) {
  int i = blockIdx.x * blockDim.x + threadIdx.x;
  if (i < N_EDGES) {
    int t = dst[i];
    int pos = rowptr[t] + atomicAdd(&cursor[t], 1);
    csr_src[pos] = src[i];
  }
}

// ============ BN affine params; zeroes stats for the next layer ============
__global__ __launch_bounds__(512) void bn_affine(float* __restrict__ stats,
                                                 const float* __restrict__ gamma,
                                                 const float* __restrict__ beta,
                                                 float* __restrict__ aff) {
  int c = threadIdx.x;
  const float invN = 1.0f / (float)N_NODES;
  float mean = stats[c] * invN;
  float var = stats[D_H + c] * invN - mean * mean;
  float sc = rsqrtf(var + BN_EPS) * gamma[c];
  aff[c] = sc;
  aff[D_H + c] = beta[c] - mean * sc;
  stats[c] = 0.f;
  stats[D_H + c] = 0.f;
}

// ============ layer-0 message table ============
__global__ __launch_bounds__(256) void msg0_kernel(const float* __restrict__ x,
                                                   const float* __restrict__ p_ptr,
                                                   __hip_bfloat16* __restrict__ msgb) {
  float p = *p_ptr;
  bool p1 = (p == 1.0f);
  const int total = N_NODES * D_INPUT / 2;
  for (int i = blockIdx.x * 256 + threadIdx.x; i < total; i += gridDim.x * 256) {
    float2 v = ((const float2*)x)[i];
    float m0 = fminf(fmaxf(v.x, 0.f) + EPS, MAXV);
    float m1 = fminf(fmaxf(v.y, 0.f) + EPS, MAXV);
    if (!p1) { m0 = powf(m0, p); m1 = powf(m1, p); }
    __hip_bfloat162 o;
    o.x = __float2bfloat16(m0);
    o.y = __float2bfloat16(m1);
    ((__hip_bfloat162*)msgb)[i] = o;
  }
}

// ============ fused: CSR aggregation (uint4 over bf16 msg table) + power-mean
//              + MessageNorm + residual (bf16 out) ============
template <int D, bool BN>
__global__ __launch_bounds__(256) void agg_msgnorm_kernel(
    const float* __restrict__ h, const float* __restrict__ aff,
    const __hip_bfloat16* __restrict__ msgb,
    const int* __restrict__ rowptr, const int* __restrict__ csr_src,
    const float* __restrict__ p_ptr, const float* __restrict__ scale_ptr,
    __hip_bfloat16* __restrict__ out) {
  constexpr int C4 = D / 8;      // uint4 columns (64 or 16)
  constexpr int SL = 256 / C4;   // edge slices (4 or 16)
  int n = blockIdx.x;
  int tid = threadIdx.x;
  int col = tid & (C4 - 1);
  int slice = tid / C4;
  int lo = rowptr[n], hi = rowptr[n + 1];
  float p = *p_ptr;
  float scale = *scale_ptr;
  bool p1 = (p == 1.0f);
  float invp = 1.0f / p;
  float inv_dg = 1.0f / fmaxf((float)(hi - lo), 1.0f);
  const uint4* mg = (const uint4*)msgb;  // row stride = C4 uint4s

  __shared__ int s_src[256];
  float acc[8] = {0.f, 0.f, 0.f, 0.f, 0.f, 0.f, 0.f, 0.f};

#define ACCU(U)                                   \
  do {                                            \
    acc[0] += bf_lo((U).x); acc[1] += bf_hi((U).x); \
    acc[2] += bf_lo((U).y); acc[3] += bf_hi((U).y); \
    acc[4] += bf_lo((U).z); acc[5] += bf_hi((U).z); \
    acc[6] += bf_lo((U).w); acc[7] += bf_hi((U).w); \
  } while (0)

  for (int base = lo; base < hi; base += 256) {
    int m = min(256, hi - base);
    __syncthreads();
    if (tid < m) s_src[tid] = csr_src[base + tid];
    __syncthreads();
    int j = slice;
    for (; j + 3 * SL < m; j += 4 * SL) {
      uint4 u0 = mg[(size_t)s_src[j] * C4 + col];
      uint4 u1 = mg[(size_t)s_src[j + SL] * C4 + col];
      uint4 u2 = mg[(size_t)s_src[j + 2 * SL] * C4 + col];
      uint4 u3 = mg[(size_t)s_src[j + 3 * SL] * C4 + col];
      ACCU(u0); ACCU(u1); ACCU(u2); ACCU(u3);
    }
    for (; j < m; j += SL) {
      uint4 u = mg[(size_t)s_src[j] * C4 + col];
      ACCU(u);
    }
  }
#undef ACCU

  // cross-slice combine (padded LDS: stride 9 -> conflict-free)
  __shared__ float sacc[256][9];
#pragma unroll
  for (int i = 0; i < 8; i++) sacc[tid][i] = acc[i];
  __syncthreads();

  float a[8], hv[8];
  float sa = 0.f, sh = 0.f;
  if (tid < C4) {
#pragma unroll
    for (int s = 1; s < SL; s++)
#pragma unroll
      for (int i = 0; i < 8; i++) acc[i] += sacc[s * C4 + tid][i];
#pragma unroll
    for (int i = 0; i < 8; i++) {
      float v = fminf(fmaxf(acc[i] * inv_dg, EPS), MAXV);
      if (!p1) v = powf(v, invp);
      a[i] = v;
      sa += v * v;
    }
    const float4* hrow = (const float4*)(h + (size_t)n * D) + tid * 2;
    float4 h0 = hrow[0], h1 = hrow[1];
    hv[0] = h0.x; hv[1] = h0.y; hv[2] = h0.z; hv[3] = h0.w;
    hv[4] = h1.x; hv[5] = h1.y; hv[6] = h1.z; hv[7] = h1.w;
    if constexpr (BN) {
      const float4* sc4 = (const float4*)aff + tid * 2;
      const float4* sh4 = (const float4*)(aff + D_H) + tid * 2;
      float4 s0 = sc4[0], s1 = sc4[1], b0 = sh4[0], b1 = sh4[1];
      hv[0] = fmaxf(hv[0] * s0.x + b0.x, 0.f);
      hv[1] = fmaxf(hv[1] * s0.y + b0.y, 0.f);
      hv[2] = fmaxf(hv[2] * s0.z + b0.z, 0.f);
      hv[3] = fmaxf(hv[3] * s0.w + b0.w, 0.f);
      hv[4] = fmaxf(hv[4] * s1.x + b1.x, 0.f);
      hv[5] = fmaxf(hv[5] * s1.y + b1.y, 0.f);
      hv[6] = fmaxf(hv[6] * s1.z + b1.z, 0.f);
      hv[7] = fmaxf(hv[7] * s1.w + b1.w, 0.f);
    }
#pragma unroll
    for (int i = 0; i < 8; i++) sh += hv[i] * hv[i];
  }
  for (int off = 32; off; off >>= 1) {
    sa += __shfl_down(sa, off);
    sh += __shfl_down(sh, off);
  }
  __shared__ float red[2][4];
  __shared__ float tot[2];
  int wid = tid >> 6;
  if ((tid & 63) == 0) { red[0][wid] = sa; red[1][wid] = sh; }
  __syncthreads();
  if (tid == 0) {
    tot[0] = red[0][0] + red[0][1] + red[0][2] + red[0][3];
    tot[1] = red[1][0] + red[1][1] + red[1][2] + red[1][3];
  }
  __syncthreads();
  float k = sqrtf(tot[1]) * scale / fmaxf(sqrtf(tot[0]), 1e-12f);
  if (tid < C4) {
    alignas(16) __hip_bfloat162 o[4];
#pragma unroll
    for (int i = 0; i < 4; i++) {
      o[i].x = __float2bfloat16(hv[2 * i] + a[2 * i] * k);
      o[i].y = __float2bfloat16(hv[2 * i + 1] + a[2 * i + 1] * k);
    }
    ((uint4*)(out + (size_t)n * D))[tid] = *(const uint4*)o;
  }
}

// ============ fused weight convert+transpose (3 mats) + cnt/stats zero ============
__global__ __launch_bounds__(256) void convert_all(
    const float* __restrict__ W0, const float* __restrict__ Wrest,
    __hip_bfloat16* __restrict__ w0t, __hip_bfloat16* __restrict__ w1t,
    __hip_bfloat16* __restrict__ w2t, int* __restrict__ cnt,
    float* __restrict__ stats) {
  int z = blockIdx.z;
  const float* W;
  __hip_bfloat16* Wt;
  int K;
  if (z == 0) { W = W0; Wt = w0t; K = D_INPUT; }
  else if (z == 1) { W = Wrest; Wt = w1t; K = D_H; }
  else { W = Wrest + (size_t)D_H * D_H; Wt = w2t; K = D_H; }

  if (z == 0 && blockIdx.x >= 4) {
    // spare blocks: zero cnt[10000] + stats[1024]
    int bid = (blockIdx.x - 4) * 16 + blockIdx.y;  // 0..191
    int idx = bid * 256 + threadIdx.x;
    if (idx < N_NODES) cnt[idx] = 0;
    int sidx = idx - N_NODES;
    if (sidx >= 0 && sidx < 1024) stats[sidx] = 0.f;
    return;
  }

  __shared__ float tile[32][33];
  int k0 = blockIdx.x * 32, n0 = blockIdx.y * 32;
  int tx = threadIdx.x & 31, ty = threadIdx.x >> 5;
  for (int i = ty; i < 32; i += 8)
    tile[i][tx] = W[(size_t)(k0 + i) * D_H + n0 + tx];
  __syncthreads();
  for (int i = ty; i < 32; i += 8)
    Wt[(size_t)(n0 + i) * K + k0 + tx] = __float2bfloat16(tile[tx][i]);
}

// ============ MFMA bf16 GEMM + fused column stats ============
__global__ __launch_bounds__(256) void mfma_gemm(
    const __hip_bfloat16* __restrict__ A, const __hip_bfloat16* __restrict__ Bt,
    const float* __restrict__ bias, float* __restrict__ C, float* __restrict__ stats,
    int M, int K) {
  __shared__ ushort As[128 * 64];
  __shared__ ushort Bs[128 * 64];
  __shared__ float sred[128][2];
  int tid = threadIdx.x;
  int l = tid & 63;
  int w = tid >> 6;
  int wm = w >> 1, wn = w & 1;
  int row0 = blockIdx.x * 128;
  int col0 = blockIdx.y * 128;

  f32x4 acc[4][4];
#pragma unroll
  for (int m = 0; m < 4; m++)
#pragma unroll
    for (int n = 0; n < 4; n++) acc[m][n] = (f32x4){0.f, 0.f, 0.f, 0.f};

  const ushort* Ag = (const ushort*)A;
  const ushort* Bg = (const ushort*)Bt;
  char* AsB = (char*)As;
  char* BsB = (char*)Bs;

  if (tid < 128) { sred[tid][0] = 0.f; sred[tid][1] = 0.f; }

  int srow = tid >> 3;
  int scb = (tid & 7) * 16;
  int wbyte = scb ^ ((srow & 7) << 4);
  int scol = scb >> 1;

  int lswz = (l & 7) << 4;
  int kb = (l >> 4) * 16;
  int arow = wm * 64 + (l & 15);
  int brow = wn * 64 + (l & 15);

  for (int k0 = 0; k0 < K; k0 += 64) {
    uint4 ra[4], rb[4];
#pragma unroll
    for (int j = 0; j < 4; j++) {
      int row = j * 32 + srow;
      ra[j] = *(const uint4*)(Ag + (size_t)(row0 + row) * K + k0 + scol);
      rb[j] = *(const uint4*)(Bg + (size_t)(col0 + row) * K + k0 + scol);
    }
#pragma unroll
    for (int j = 0; j < 4; j++) {
      int row = j * 32 + srow;
      *(uint4*)(AsB + row * 128 + wbyte) = ra[j];
      *(uint4*)(BsB + row * 128 + wbyte) = rb[j];
    }
    __syncthreads();
#pragma unroll
    for (int kk = 0; kk < 2; kk++) {
      bf16x8 af[4], bfr[4];
#pragma unroll
      for (int m = 0; m < 4; m++)
        af[m] = *(const bf16x8*)(AsB + (arow + m * 16) * 128 + ((kk * 64 + kb) ^ lswz));
#pragma unroll
      for (int n = 0; n < 4; n++)
        bfr[n] = *(const bf16x8*)(BsB + (brow + n * 16) * 128 + ((kk * 64 + kb) ^ lswz));
#pragma unroll
      for (int m = 0; m < 4; m++)
#pragma unroll
        for (int n = 0; n < 4; n++)
          acc[m][n] = __builtin_amdgcn_mfma_f32_16x16x32_bf16(af[m], bfr[n], acc[m][n], 0, 0, 0);
    }
    __syncthreads();
  }

  int crow0 = row0 + wm * 64 + (l >> 4) * 4;
  int ccol0 = col0 + wn * 64 + (l & 15);
#pragma unroll
  for (int n = 0; n < 4; n++) {
    int col = ccol0 + n * 16;
    float bv = bias[col];
    float ps = 0.f, pq = 0.f;
#pragma unroll
    for (int m = 0; m < 4; m++) {
#pragma unroll
      for (int r = 0; r < 4; r++) {
        int rr = crow0 + m * 16 + r;
        if (rr < M) {
          float v = acc[m][n][r] + bv;
          C[(size_t)rr * D_H + col] = v;
          ps += v;
          pq += v * v;
        }
      }
    }
    ps += __shfl_down(ps, 16); pq += __shfl_down(pq, 16);
    ps += __shfl_down(ps, 32); pq += __shfl_down(pq, 32);
    if ((l >> 4) == 0) {
      atomicAdd(&sred[wn * 64 + n * 16 + (l & 15)][0], ps);
      atomicAdd(&sred[wn * 64 + n * 16 + (l & 15)][1], pq);
    }
  }
  __syncthreads();
  if (tid < 128) {
    atomicAdd(&stats[col0 + tid], sred[tid][0]);
    atomicAdd(&stats[D_H + col0 + tid], sred[tid][1]);
  }
}

// ---------------- JK-max update + next-layer msg table ----------------
template <bool WRITE_MSG>
__global__ __launch_bounds__(256) void jk_msg_update(
    const float* __restrict__ hlin, const float* __restrict__ aff,
    float* __restrict__ jk, const float* __restrict__ p_ptr,
    __hip_bfloat16* __restrict__ msgb, int layer) {
  float p = 1.f;
  bool p1 = true;
  if constexpr (WRITE_MSG) {
    p = *p_ptr;
    p1 = (p == 1.0f);
  }
  const int total = N_NODES * D_H / 4;
  for (int idx = blockIdx.x * blockDim.x + threadIdx.x; idx < total;
       idx += gridDim.x * blockDim.x) {
    int c4 = idx & 127;
    float4 x = ((const float4*)hlin)[idx];
    float4 sc = ((const float4*)aff)[c4];
    float4 sh = ((const float4*)(aff + D_H))[c4];
    float4 v;
    v.x = fmaxf(x.x * sc.x + sh.x, 0.f);
    v.y = fmaxf(x.y * sc.y + sh.y, 0.f);
    v.z = fmaxf(x.z * sc.z + sh.z, 0.f);
    v.w = fmaxf(x.w * sc.w + sh.w, 0.f);
    if constexpr (WRITE_MSG) {
      float m0 = fminf(v.x + EPS, MAXV);
      float m1 = fminf(v.y + EPS, MAXV);
      float m2 = fminf(v.z + EPS, MAXV);
      float m3 = fminf(v.w + EPS, MAXV);
      if (!p1) { m0 = powf(m0, p); m1 = powf(m1, p); m2 = powf(m2, p); m3 = powf(m3, p); }
      __hip_bfloat162 o01, o23;
      o01.x = __float2bfloat16(m0); o01.y = __float2bfloat16(m1);
      o23.x = __float2bfloat16(m2); o23.y = __float2bfloat16(m3);
      ((__hip_bfloat162*)msgb)[2 * idx] = o01;
      ((__hip_bfloat162*)msgb)[2 * idx + 1] = o23;
    }
    if (layer != 0) {
      float4 j = ((const float4*)jk)[idx];
      v.x = fmaxf(v.x, j.x);
      v.y = fmaxf(v.y, j.y);
      v.z = fmaxf(v.z, j.z);
      v.w = fmaxf(v.w, j.w);
    }
    ((float4*)jk)[idx] = v;
  }
}

// ---------------- per-graph max+mean pooling (float4) ----------------
// grid (graph, 8 chunks): 256 thr = 16 f4-cols x 16 row-slices
__device__ __forceinline__ int lower_bound_i(const int* a, int n, int v) {
  int lo = 0, hi = n;
  while (lo < hi) {
    int mid = (lo + hi) >> 1;
    if (a[mid] < v) lo = mid + 1; else hi = mid;
  }
  return lo;
}

__global__ __launch_bounds__(256) void pool_kernel(const float* __restrict__ jk,
                                                   const int* __restrict__ batch,
                                                   float* __restrict__ g) {
  int gid = blockIdx.x;
  int cl = threadIdx.x & 15;
  int slice = threadIdx.x >> 4;
  int f4c = blockIdx.y * 16 + cl;  // 0..127
  int lo = lower_bound_i(batch, N_NODES, gid);
  int hi = lower_bound_i(batch, N_NODES, gid + 1);
  const float4* J = (const float4*)jk;
  float4 mx = make_float4(0.f, 0.f, 0.f, 0.f);
  float4 sm = make_float4(0.f, 0.f, 0.f, 0.f);
  int r = lo + slice;
  for (; r + 16 < hi; r += 32) {
    float4 v0 = J[(size_t)r * 128 + f4c];
    float4 v1 = J[(size_t)(r + 16) * 128 + f4c];
    mx.x = fmaxf(fmaxf(mx.x, v0.x), v1.x);
    mx.y = fmaxf(fmaxf(mx.y, v0.y), v1.y);
    mx.z = fmaxf(fmaxf(mx.z, v0.z), v1.z);
    mx.w = fmaxf(fmaxf(mx.w, v0.w), v1.w);
    sm.x += v0.x + v1.x; sm.y += v0.y + v1.y;
    sm.z += v0.z + v1.z; sm.w += v0.w + v1.w;
  }
  for (; r < hi; r += 16) {
    float4 v = J[(size_t)r * 128 + f4c];
    mx.x = fmaxf(mx.x, v.x); mx.y = fmaxf(mx.y, v.y);
    mx.z = fmaxf(mx.z, v.z); mx.w = fmaxf(mx.w, v.w);
    sm.x += v.x; sm.y += v.y; sm.z += v.z; sm.w += v.w;
  }
  __shared__ float4 smax[16][16];
  __shared__ float4 ssum[16][16];
  smax[slice][cl] = mx;
  ssum[slice][cl] = sm;
  __syncthreads();
  if (slice == 0) {
#pragma unroll
    for (int s = 1; s < 16; s++) {
      float4 m2 = smax[s][cl], s2 = ssum[s][cl];
      mx.x = fmaxf(mx.x, m2.x); mx.y = fmaxf(mx.y, m2.y);
      mx.z = fmaxf(mx.z, m2.z); mx.w = fmaxf(mx.w, m2.w);
      sm.x += s2.x; sm.y += s2.y; sm.z += s2.z; sm.w += s2.w;
    }
    float ic = 1.0f / fmaxf((float)(hi - lo), 1.0f);
    if (hi <= lo) mx = make_float4(0.f, 0.f, 0.f, 0.f);
    sm.x *= ic; sm.y *= ic; sm.z *= ic; sm.w *= ic;
    ((float4*)(g + (size_t)gid * 1024))[f4c] = mx;
    ((float4*)(g + (size_t)gid * 1024 + D_H))[f4c] = sm;
  }
}

// ---------------- fc1: [64,1024] @ [1024,512] + b ----------------
__global__ __launch_bounds__(256) void fc1_kernel(const float* __restrict__ g,
                                                  const float* __restrict__ W,
                                                  const float* __restrict__ b,
                                                  float* __restrict__ out) {
  __shared__ float sg[1024];
  __shared__ float sred[4][64];
  int gid = blockIdx.x;
  int tid = threadIdx.x;
  ((float4*)sg)[tid] = ((const float4*)(g + (size_t)gid * 1024))[tid];
  __syncthreads();
  int cl = tid & 63;
  int slice = tid >> 6;
  int col = blockIdx.y * 64 + cl;
  int k0 = slice * 256;
  float acc = 0.f;
#pragma unroll 4
  for (int k = k0; k < k0 + 256; k++) acc += sg[k] * W[(size_t)k * D_H + col];
  sred[slice][cl] = acc;
  __syncthreads();
  if (slice == 0)
    out[(size_t)gid * D_H + col] =
        sred[0][cl] + sred[1][cl] + sred[2][cl] + sred[3][cl] + b[col];
}

// ---------------- BN over 64 graphs + ReLU ----------------
__global__ __launch_bounds__(256) void bn4_kernel(const float* __restrict__ x,
                                                  const float* __restrict__ gmm,
                                                  const float* __restrict__ bb,
                                                  float* __restrict__ y) {
  int cl = threadIdx.x & 63;
  int slice = threadIdx.x >> 6;
  int c = blockIdx.x * 64 + cl;
  float s = 0.f, q = 0.f;
#pragma unroll
  for (int r = slice * 16; r < slice * 16 + 16; r++) {
    float v = x[(size_t)r * D_H + c];
    s += v; q += v * v;
  }
  __shared__ float ss[4][64], sq[4][64];
  ss[slice][cl] = s;
  sq[slice][cl] = q;
  __syncthreads();
  float S = ss[0][cl] + ss[1][cl] + ss[2][cl] + ss[3][cl];
  float Q = sq[0][cl] + sq[1][cl] + sq[2][cl] + sq[3][cl];
  float mean = S * (1.0f / N_GRAPHS);
  float var = Q * (1.0f / N_GRAPHS) - mean * mean;
  float rs = rsqrtf(var + BN_EPS) * gmm[c];
  float sh = bb[c] - mean * rs;
#pragma unroll
  for (int r = slice * 16; r < slice * 16 + 16; r++)
    y[(size_t)r * D_H + c] = fmaxf(x[(size_t)r * D_H + c] * rs + sh, 0.f);
}

// ---------------- fc2: [64,512] @ [512,2] + b ----------------
__global__ __launch_bounds__(64) void fc2_kernel(const float* __restrict__ y,
                                                 const float* __restrict__ W,
                                                 const float* __restrict__ b,
                                                 float* __restrict__ out) {
  int gid = blockIdx.x;
  int lane = threadIdx.x;
  float a0 = 0.f, a1 = 0.f;
  for (int k = lane; k < D_H; k += 64) {
    float v = y[(size_t)gid * D_H + k];
    a0 += v * W[k * 2 + 0];
    a1 += v * W[k * 2 + 1];
  }
  for (int off = 32; off; off >>= 1) {
    a0 += __shfl_down(a0, off);
    a1 += __shfl_down(a1, off);
  }
  if (lane == 0) {
    out[gid * 2 + 0] = a0 + b[0];
    out[gid * 2 + 1] = a1 + b[1];
  }
}

extern "C" void kernel_launch(void* const* d_in, const int* in_sizes, int n_in,
                              void* d_out, int out_size, void* d_ws, size_t ws_size,
                              hipStream_t stream) {
  const float* x       = (const float*)d_in[0];
  const float* W0      = (const float*)d_in[1];
  const float* Wrest   = (const float*)d_in[2];
  const float* bconv   = (const float*)d_in[3];
  const float* p       = (const float*)d_in[4];
  const float* mscale  = (const float*)d_in[5];
  const float* bn_g    = (const float*)d_in[6];
  const float* bn_b    = (const float*)d_in[7];
  const float* fc1_W   = (const float*)d_in[8];
  const float* fc1_b   = (const float*)d_in[9];
  const float* bn4_g   = (const float*)d_in[10];
  const float* bn4_b   = (const float*)d_in[11];
  const float* fc2_W   = (const float*)d_in[12];
  const float* fc2_b   = (const float*)d_in[13];
  const int*   eidx    = (const int*)d_in[14];
  const int*   batch   = (const int*)d_in[15];
  float* out = (float*)d_out;

  const int* src = eidx;
  const int* dst = eidx + N_EDGES;

  float* ws = (float*)d_ws;
  const size_t NH = (size_t)N_NODES * D_H;
  float* hlin  = ws;
  float* jk    = hlin + NH;
  float* stats = jk + NH;                          // 1024
  float* aff   = stats + 1024;                     // 1024
  __hip_bfloat16* residb = (__hip_bfloat16*)(aff + 1024);    // [M_PAD][512] bf16
  __hip_bfloat16* msgb = residb + (size_t)M_PAD * D_H;       // [N_NODES][512] bf16
  __hip_bfloat16* w0t = msgb + NH;
  __hip_bfloat16* w1t = w0t + 512 * 128;
  __hip_bfloat16* w2t = w1t + 512 * 512;
  int* cnt     = (int*)(w2t + 512 * 512);
  int* rowptr  = cnt + N_NODES;
  int* csr_src = rowptr + N_NODES + 1;
  float* g     = (float*)(csr_src + N_EDGES);
  float* g2lin = g + 64 * 1024;
  float* g2    = g2lin + 64 * D_H;

  // ---- weights (bf16, transposed) + cnt/stats zero, one dispatch ----
  convert_all<<<dim3(16, 16, 3), 256, 0, stream>>>(W0, Wrest, w0t, w1t, w2t, cnt, stats);

  // ---- build CSR (scan zeroes cnt for scatter's cursor) ----
  hist_kernel<<<(N_EDGES + 255) / 256, 256, 0, stream>>>(dst, cnt);
  scan_kernel<<<1, 256, 0, stream>>>(cnt, rowptr);
  scatter_kernel<<<(N_EDGES + 255) / 256, 256, 0, stream>>>(src, dst, rowptr, cnt, csr_src);

  // ---- layer-0 message table ----
  msg0_kernel<<<1280, 256, 0, stream>>>(x, p, msgb);

  for (int layer = 0; layer < 3; layer++) {
    if (layer == 0)
      agg_msgnorm_kernel<D_INPUT, false><<<N_NODES, 256, 0, stream>>>(
          x, nullptr, msgb, rowptr, csr_src, p + layer, mscale + layer, residb);
    else
      agg_msgnorm_kernel<D_H, true><<<N_NODES, 256, 0, stream>>>(
          hlin, aff, msgb, rowptr, csr_src, p + layer, mscale + layer, residb);
    const __hip_bfloat16* Wt = (layer == 0) ? w0t : (layer == 1 ? w1t : w2t);
    int K = (layer == 0) ? D_INPUT : D_H;
    mfma_gemm<<<dim3(M_PAD / 128, D_H / 128), 256, 0, stream>>>(
        residb, Wt, bconv + (size_t)layer * D_H, hlin, stats, N_NODES, K);
    bn_affine<<<1, 512, 0, stream>>>(stats, bn_g + (size_t)layer * D_H,
                                     bn_b + (size_t)layer * D_H, aff);
    if (layer < 2)
      jk_msg_update<true><<<2048, 256, 0, stream>>>(hlin, aff, jk, p + layer + 1, msgb, layer);
    else
      jk_msg_update<false><<<2048, 256, 0, stream>>>(hlin, aff, jk, nullptr, nullptr, layer);
  }

  pool_kernel<<<dim3(N_GRAPHS, 8), 256, 0, stream>>>(jk, batch, g);
  fc1_kernel<<<dim3(N_GRAPHS, 8), 256, 0, stream>>>(g, fc1_W, fc1_b, g2lin);
  bn4_kernel<<<8, 256, 0, stream>>>(g2lin, bn4_g, bn4_b, g2);
  fc2_kernel<<<N_GRAPHS, 64, 0, stream>>>(g2, fc2_W, fc2_b, out);
}

// Round 9
// 255.893 us; speedup vs baseline: 11.6194x; 1.0909x over previous
//
#include <hip/hip_runtime.h>
#include <hip/hip_bf16.h>
#include <math.h>

#define N_NODES 10000
#define N_GRAPHS 64
#define N_EDGES 160000
#define D_INPUT 128
#define D_H 512
#define EPS 1e-7f
#define MAXV 10.0f
#define BN_EPS 1e-5f
#define M_PAD 10112  // 79 * 128

typedef __attribute__((ext_vector_type(4))) float f32x4;
typedef __attribute__((ext_vector_type(8))) __bf16 bf16x8;

// ================= CSR build =================
__global__ __launch_bounds__(256) void hist_kernel(const int* __restrict__ dst,
                                                   int* __restrict__ cnt) {
  int i = blockIdx.x * blockDim.x + threadIdx.x;
  if (i < N_EDGES) atomicAdd(&cnt[dst[i]], 1);
}

// single-block scan; reads cnt via int4, writes rowptr via int4, zeroes cnt
__global__ __launch_bounds__(256) void scan_kernel(int* __restrict__ cnt,
                                                   int* __restrict__ rowptr) {
  __shared__ int ps[256];
  int tid = threadIdx.x;
  const int CH = 40;  // 250 threads x 40 = 10000
  int b0 = tid * CH;
  bool active = (b0 < N_NODES);
  int v[CH];
  int s = 0;
  if (active) {
    const int4* c4p = (const int4*)(cnt + b0);
#pragma unroll
    for (int i = 0; i < CH / 4; i++) {
      int4 q = c4p[i];
      v[4 * i] = q.x; v[4 * i + 1] = q.y; v[4 * i + 2] = q.z; v[4 * i + 3] = q.w;
      s += q.x + q.y + q.z + q.w;
    }
  }
  ps[tid] = s;
  __syncthreads();
  for (int off = 1; off < 256; off <<= 1) {
    int t = (tid >= off) ? ps[tid - off] : 0;
    __syncthreads();
    ps[tid] += t;
    __syncthreads();
  }
  int run = (tid == 0) ? 0 : ps[tid - 1];
  if (active) {
    int r[CH];
#pragma unroll
    for (int i = 0; i < CH; i++) { r[i] = run; run += v[i]; }
    int4* rp = (int4*)(rowptr + b0);
    int4* cz = (int4*)(cnt + b0);
#pragma unroll
    for (int i = 0; i < CH / 4; i++) {
      rp[i] = make_int4(r[4 * i], r[4 * i + 1], r[4 * i + 2], r[4 * i + 3]);
      cz[i] = make_int4(0, 0, 0, 0);
    }
  }
  if (tid == 255) rowptr[N_NODES] = ps[255];
}

__global__ __launch_bounds__(256) void scatter_kernel(
    const int* __restrict__ src, const int* __restrict__ dst,
    const int* __restrict__ rowptr, int* __restrict__ cursor,
    int* __restrict__ csr_src) {
  int i = blockIdx.x * blockDim.x + threadIdx.x;
  if (i < N_EDGES) {
    int t = dst[i];
    int pos = rowptr[t] + atomicAdd(&cursor[t], 1);
    csr_src[pos] = src[i];
  }
}

// ============ BN affine params; zeroes stats for the next layer ============
__global__ __launch_bounds__(512) void bn_affine(float* __restrict__ stats,
                                                 const float* __restrict__ gamma,
                                                 const float* __restrict__ beta,
                                                 float* __restrict__ aff) {
  int c = threadIdx.x;
  const float invN = 1.0f / (float)N_NODES;
  float mean = stats[c] * invN;
  float var = stats[D_H + c] * invN - mean * mean;
  float sc = rsqrtf(var + BN_EPS) * gamma[c];
  aff[c] = sc;
  aff[D_H + c] = beta[c] - mean * sc;
  stats[c] = 0.f;
  stats[D_H + c] = 0.f;
}

// ============ layer-0 message table ============
__global__ __launch_bounds__(256) void msg0_kernel(const float* __restrict__ x,
                                                   const float* __restrict__ p_ptr,
                                                   __hip_bfloat16* __restrict__ msgb) {
  float p = *p_ptr;
  bool p1 = (p == 1.0f);
  const int total = N_NODES * D_INPUT / 2;
  for (int i = blockIdx.x * 256 + threadIdx.x; i < total; i += gridDim.x * 256) {
    float2 v = ((const float2*)x)[i];
    float m0 = fminf(fmaxf(v.x, 0.f) + EPS, MAXV);
    float m1 = fminf(fmaxf(v.y, 0.f) + EPS, MAXV);
    if (!p1) { m0 = powf(m0, p); m1 = powf(m1, p); }
    __hip_bfloat162 o;
    o.x = __float2bfloat16(m0);
    o.y = __float2bfloat16(m1);
    ((__hip_bfloat162*)msgb)[i] = o;
  }
}

// ============ fused: CSR aggregation (bf16 msg table, 4B gather) + power-mean
//              + MessageNorm + residual (bf16 out) ============
// Proven R7 structure: low VGPR, full occupancy; gather is latency-bound.
template <int D, bool BN>
__global__ __launch_bounds__(256) void agg_msgnorm_kernel(
    const float* __restrict__ h, const float* __restrict__ aff,
    const __hip_bfloat16* __restrict__ msgb,
    const int* __restrict__ rowptr, const int* __restrict__ csr_src,
    const float* __restrict__ p_ptr, const float* __restrict__ scale_ptr,
    __hip_bfloat16* __restrict__ out) {
  constexpr int C = D / 2;        // bf16-pair columns (64 or 256)
  constexpr int SL = 256 / C;     // edge slices (4 or 1)
  int n = blockIdx.x;
  int tid = threadIdx.x;
  int col = tid % C;
  int slice = tid / C;
  int lo = rowptr[n], hi = rowptr[n + 1];
  float p = *p_ptr;
  float scale = *scale_ptr;
  bool p1 = (p == 1.0f);
  float invp = 1.0f / p;
  float inv_dg = 1.0f / fmaxf((float)(hi - lo), 1.0f);
  const float2* h2 = (const float2*)h;
  const uint* mg = (const uint*)msgb;

  __shared__ int s_src[256];
  float accx = 0.f, accy = 0.f;
  for (int base = lo; base < hi; base += 256) {
    int m = min(256, hi - base);
    __syncthreads();
    if (tid < m) s_src[tid] = csr_src[base + tid];
    __syncthreads();
    int j = slice;
    for (; j + 3 * SL < m; j += 4 * SL) {
      uint u0 = mg[(size_t)s_src[j] * C + col];
      uint u1 = mg[(size_t)s_src[j + SL] * C + col];
      uint u2 = mg[(size_t)s_src[j + 2 * SL] * C + col];
      uint u3 = mg[(size_t)s_src[j + 3 * SL] * C + col];
      accx += (__uint_as_float(u0 << 16) + __uint_as_float(u1 << 16)) +
              (__uint_as_float(u2 << 16) + __uint_as_float(u3 << 16));
      accy += (__uint_as_float(u0 & 0xFFFF0000u) + __uint_as_float(u1 & 0xFFFF0000u)) +
              (__uint_as_float(u2 & 0xFFFF0000u) + __uint_as_float(u3 & 0xFFFF0000u));
    }
    for (; j < m; j += SL) {
      uint u = mg[(size_t)s_src[j] * C + col];
      accx += __uint_as_float(u << 16);
      accy += __uint_as_float(u & 0xFFFF0000u);
    }
  }

  if constexpr (SL > 1) {
    __shared__ float sacc[2][256];
    sacc[0][tid] = accx;
    sacc[1][tid] = accy;
    __syncthreads();
    if (tid < C) {
#pragma unroll
      for (int s = 1; s < SL; s++) {
        accx += sacc[0][s * C + tid];
        accy += sacc[1][s * C + tid];
      }
    }
  }

  float a0 = 0.f, a1 = 0.f, hv0 = 0.f, hv1 = 0.f, sa = 0.f, sh = 0.f;
  if (tid < C) {
    a0 = fminf(fmaxf(accx * inv_dg, EPS), MAXV);
    a1 = fminf(fmaxf(accy * inv_dg, EPS), MAXV);
    if (!p1) { a0 = powf(a0, invp); a1 = powf(a1, invp); }
    float2 hx = h2[(size_t)n * C + tid];
    if constexpr (BN) {
      float2 s2 = ((const float2*)aff)[tid];
      float2 b2 = ((const float2*)(aff + D_H))[tid];
      hx.x = fmaxf(hx.x * s2.x + b2.x, 0.f);
      hx.y = fmaxf(hx.y * s2.y + b2.y, 0.f);
    }
    hv0 = hx.x;
    hv1 = hx.y;
    sa = a0 * a0 + a1 * a1;
    sh = hv0 * hv0 + hv1 * hv1;
  }
  for (int off = 32; off; off >>= 1) {
    sa += __shfl_down(sa, off);
    sh += __shfl_down(sh, off);
  }
  __shared__ float red[2][4];
  __shared__ float tot[2];
  int wid = tid >> 6;
  if ((tid & 63) == 0) { red[0][wid] = sa; red[1][wid] = sh; }
  __syncthreads();
  if (tid == 0) {
    tot[0] = red[0][0] + red[0][1] + red[0][2] + red[0][3];
    tot[1] = red[1][0] + red[1][1] + red[1][2] + red[1][3];
  }
  __syncthreads();
  float k = sqrtf(tot[1]) * scale / fmaxf(sqrtf(tot[0]), 1e-12f);
  if (tid < C) {
    __hip_bfloat162 o2;
    o2.x = __float2bfloat16(hv0 + a0 * k);
    o2.y = __float2bfloat16(hv1 + a1 * k);
    ((__hip_bfloat162*)out)[(size_t)n * C + tid] = o2;
  }
}

// ============ fused weight convert+transpose (3 mats) + cnt/stats zero ============
__global__ __launch_bounds__(256) void convert_all(
    const float* __restrict__ W0, const float* __restrict__ Wrest,
    __hip_bfloat16* __restrict__ w0t, __hip_bfloat16* __restrict__ w1t,
    __hip_bfloat16* __restrict__ w2t, int* __restrict__ cnt,
    float* __restrict__ stats) {
  int z = blockIdx.z;
  const float* W;
  __hip_bfloat16* Wt;
  int K;
  if (z == 0) { W = W0; Wt = w0t; K = D_INPUT; }
  else if (z == 1) { W = Wrest; Wt = w1t; K = D_H; }
  else { W = Wrest + (size_t)D_H * D_H; Wt = w2t; K = D_H; }

  if (z == 0 && blockIdx.x >= 4) {
    int bid = (blockIdx.x - 4) * 16 + blockIdx.y;  // 0..191
    int idx = bid * 256 + threadIdx.x;
    if (idx < N_NODES) cnt[idx] = 0;
    int sidx = idx - N_NODES;
    if (sidx >= 0 && sidx < 1024) stats[sidx] = 0.f;
    return;
  }

  __shared__ float tile[32][33];
  int k0 = blockIdx.x * 32, n0 = blockIdx.y * 32;
  int tx = threadIdx.x & 31, ty = threadIdx.x >> 5;
  for (int i = ty; i < 32; i += 8)
    tile[i][tx] = W[(size_t)(k0 + i) * D_H + n0 + tx];
  __syncthreads();
  for (int i = ty; i < 32; i += 8)
    Wt[(size_t)(n0 + i) * K + k0 + tx] = __float2bfloat16(tile[tx][i]);
}

// ============ MFMA bf16 GEMM + fused column stats ============
__global__ __launch_bounds__(256) void mfma_gemm(
    const __hip_bfloat16* __restrict__ A, const __hip_bfloat16* __restrict__ Bt,
    const float* __restrict__ bias, float* __restrict__ C, float* __restrict__ stats,
    int M, int K) {
  __shared__ ushort As[128 * 64];
  __shared__ ushort Bs[128 * 64];
  __shared__ float sred[128][2];
  int tid = threadIdx.x;
  int l = tid & 63;
  int w = tid >> 6;
  int wm = w >> 1, wn = w & 1;
  int row0 = blockIdx.x * 128;
  int col0 = blockIdx.y * 128;

  f32x4 acc[4][4];
#pragma unroll
  for (int m = 0; m < 4; m++)
#pragma unroll
    for (int n = 0; n < 4; n++) acc[m][n] = (f32x4){0.f, 0.f, 0.f, 0.f};

  const ushort* Ag = (const ushort*)A;
  const ushort* Bg = (const ushort*)Bt;
  char* AsB = (char*)As;
  char* BsB = (char*)Bs;

  if (tid < 128) { sred[tid][0] = 0.f; sred[tid][1] = 0.f; }

  int srow = tid >> 3;
  int scb = (tid & 7) * 16;
  int wbyte = scb ^ ((srow & 7) << 4);
  int scol = scb >> 1;

  int lswz = (l & 7) << 4;
  int kb = (l >> 4) * 16;
  int arow = wm * 64 + (l & 15);
  int brow = wn * 64 + (l & 15);

  for (int k0 = 0; k0 < K; k0 += 64) {
    uint4 ra[4], rb[4];
#pragma unroll
    for (int j = 0; j < 4; j++) {
      int row = j * 32 + srow;
      ra[j] = *(const uint4*)(Ag + (size_t)(row0 + row) * K + k0 + scol);
      rb[j] = *(const uint4*)(Bg + (size_t)(col0 + row) * K + k0 + scol);
    }
#pragma unroll
    for (int j = 0; j < 4; j++) {
      int row = j * 32 + srow;
      *(uint4*)(AsB + row * 128 + wbyte) = ra[j];
      *(uint4*)(BsB + row * 128 + wbyte) = rb[j];
    }
    __syncthreads();
#pragma unroll
    for (int kk = 0; kk < 2; kk++) {
      bf16x8 af[4], bfr[4];
#pragma unroll
      for (int m = 0; m < 4; m++)
        af[m] = *(const bf16x8*)(AsB + (arow + m * 16) * 128 + ((kk * 64 + kb) ^ lswz));
#pragma unroll
      for (int n = 0; n < 4; n++)
        bfr[n] = *(const bf16x8*)(BsB + (brow + n * 16) * 128 + ((kk * 64 + kb) ^ lswz));
#pragma unroll
      for (int m = 0; m < 4; m++)
#pragma unroll
        for (int n = 0; n < 4; n++)
          acc[m][n] = __builtin_amdgcn_mfma_f32_16x16x32_bf16(af[m], bfr[n], acc[m][n], 0, 0, 0);
    }
    __syncthreads();
  }

  int crow0 = row0 + wm * 64 + (l >> 4) * 4;
  int ccol0 = col0 + wn * 64 + (l & 15);
#pragma unroll
  for (int n = 0; n < 4; n++) {
    int col = ccol0 + n * 16;
    float bv = bias[col];
    float ps = 0.f, pq = 0.f;
#pragma unroll
    for (int m = 0; m < 4; m++) {
#pragma unroll
      for (int r = 0; r < 4; r++) {
        int rr = crow0 + m * 16 + r;
        if (rr < M) {
          float v = acc[m][n][r] + bv;
          C[(size_t)rr * D_H + col] = v;
          ps += v;
          pq += v * v;
        }
      }
    }
    ps += __shfl_down(ps, 16); pq += __shfl_down(pq, 16);
    ps += __shfl_down(ps, 32); pq += __shfl_down(pq, 32);
    if ((l >> 4) == 0) {
      atomicAdd(&sred[wn * 64 + n * 16 + (l & 15)][0], ps);
      atomicAdd(&sred[wn * 64 + n * 16 + (l & 15)][1], pq);
    }
  }
  __syncthreads();
  if (tid < 128) {
    atomicAdd(&stats[col0 + tid], sred[tid][0]);
    atomicAdd(&stats[D_H + col0 + tid], sred[tid][1]);
  }
}

// ---------------- JK-max update + next-layer msg table ----------------
template <bool WRITE_MSG>
__global__ __launch_bounds__(256) void jk_msg_update(
    const float* __restrict__ hlin, const float* __restrict__ aff,
    float* __restrict__ jk, const float* __restrict__ p_ptr,
    __hip_bfloat16* __restrict__ msgb, int layer) {
  float p = 1.f;
  bool p1 = true;
  if constexpr (WRITE_MSG) {
    p = *p_ptr;
    p1 = (p == 1.0f);
  }
  const int total = N_NODES * D_H / 4;
  for (int idx = blockIdx.x * blockDim.x + threadIdx.x; idx < total;
       idx += gridDim.x * blockDim.x) {
    int c4 = idx & 127;
    float4 x = ((const float4*)hlin)[idx];
    float4 sc = ((const float4*)aff)[c4];
    float4 sh = ((const float4*)(aff + D_H))[c4];
    float4 v;
    v.x = fmaxf(x.x * sc.x + sh.x, 0.f);
    v.y = fmaxf(x.y * sc.y + sh.y, 0.f);
    v.z = fmaxf(x.z * sc.z + sh.z, 0.f);
    v.w = fmaxf(x.w * sc.w + sh.w, 0.f);
    if constexpr (WRITE_MSG) {
      float m0 = fminf(v.x + EPS, MAXV);
      float m1 = fminf(v.y + EPS, MAXV);
      float m2 = fminf(v.z + EPS, MAXV);
      float m3 = fminf(v.w + EPS, MAXV);
      if (!p1) { m0 = powf(m0, p); m1 = powf(m1, p); m2 = powf(m2, p); m3 = powf(m3, p); }
      __hip_bfloat162 o01, o23;
      o01.x = __float2bfloat16(m0); o01.y = __float2bfloat16(m1);
      o23.x = __float2bfloat16(m2); o23.y = __float2bfloat16(m3);
      ((__hip_bfloat162*)msgb)[2 * idx] = o01;
      ((__hip_bfloat162*)msgb)[2 * idx + 1] = o23;
    }
    if (layer != 0) {
      float4 j = ((const float4*)jk)[idx];
      v.x = fmaxf(v.x, j.x);
      v.y = fmaxf(v.y, j.y);
      v.z = fmaxf(v.z, j.z);
      v.w = fmaxf(v.w, j.w);
    }
    ((float4*)jk)[idx] = v;
  }
}

// ---------------- per-graph max+mean pooling (float4) ----------------
__device__ __forceinline__ int lower_bound_i(const int* a, int n, int v) {
  int lo = 0, hi = n;
  while (lo < hi) {
    int mid = (lo + hi) >> 1;
    if (a[mid] < v) lo = mid + 1; else hi = mid;
  }
  return lo;
}

__global__ __launch_bounds__(256) void pool_kernel(const float* __restrict__ jk,
                                                   const int* __restrict__ batch,
                                                   float* __restrict__ g) {
  int gid = blockIdx.x;
  int cl = threadIdx.x & 15;
  int slice = threadIdx.x >> 4;
  int f4c = blockIdx.y * 16 + cl;  // 0..127
  int lo = lower_bound_i(batch, N_NODES, gid);
  int hi = lower_bound_i(batch, N_NODES, gid + 1);
  const float4* J = (const float4*)jk;
  float4 mx = make_float4(0.f, 0.f, 0.f, 0.f);
  float4 sm = make_float4(0.f, 0.f, 0.f, 0.f);
  int r = lo + slice;
  for (; r + 16 < hi; r += 32) {
    float4 v0 = J[(size_t)r * 128 + f4c];
    float4 v1 = J[(size_t)(r + 16) * 128 + f4c];
    mx.x = fmaxf(fmaxf(mx.x, v0.x), v1.x);
    mx.y = fmaxf(fmaxf(mx.y, v0.y), v1.y);
    mx.z = fmaxf(fmaxf(mx.z, v0.z), v1.z);
    mx.w = fmaxf(fmaxf(mx.w, v0.w), v1.w);
    sm.x += v0.x + v1.x; sm.y += v0.y + v1.y;
    sm.z += v0.z + v1.z; sm.w += v0.w + v1.w;
  }
  for (; r < hi; r += 16) {
    float4 v = J[(size_t)r * 128 + f4c];
    mx.x = fmaxf(mx.x, v.x); mx.y = fmaxf(mx.y, v.y);
    mx.z = fmaxf(mx.z, v.z); mx.w = fmaxf(mx.w, v.w);
    sm.x += v.x; sm.y += v.y; sm.z += v.z; sm.w += v.w;
  }
  __shared__ float4 smax[16][16];
  __shared__ float4 ssum[16][16];
  smax[slice][cl] = mx;
  ssum[slice][cl] = sm;
  __syncthreads();
  if (slice == 0) {
#pragma unroll
    for (int s = 1; s < 16; s++) {
      float4 m2 = smax[s][cl], s2 = ssum[s][cl];
      mx.x = fmaxf(mx.x, m2.x); mx.y = fmaxf(mx.y, m2.y);
      mx.z = fmaxf(mx.z, m2.z); mx.w = fmaxf(mx.w, m2.w);
      sm.x += s2.x; sm.y += s2.y; sm.z += s2.z; sm.w += s2.w;
    }
    float ic = 1.0f / fmaxf((float)(hi - lo), 1.0f);
    if (hi <= lo) mx = make_float4(0.f, 0.f, 0.f, 0.f);
    sm.x *= ic; sm.y *= ic; sm.z *= ic; sm.w *= ic;
    ((float4*)(g + (size_t)gid * 1024))[f4c] = mx;
    ((float4*)(g + (size_t)gid * 1024 + D_H))[f4c] = sm;
  }
}

// ---------------- fc1: [64,1024] @ [1024,512] + b ----------------
__global__ __launch_bounds__(256) void fc1_kernel(const float* __restrict__ g,
                                                  const float* __restrict__ W,
                                                  const float* __restrict__ b,
                                                  float* __restrict__ out) {
  __shared__ float sg[1024];
  __shared__ float sred[4][64];
  int gid = blockIdx.x;
  int tid = threadIdx.x;
  ((float4*)sg)[tid] = ((const float4*)(g + (size_t)gid * 1024))[tid];
  __syncthreads();
  int cl = tid & 63;
  int slice = tid >> 6;
  int col = blockIdx.y * 64 + cl;
  int k0 = slice * 256;
  float acc = 0.f;
#pragma unroll 4
  for (int k = k0; k < k0 + 256; k++) acc += sg[k] * W[(size_t)k * D_H + col];
  sred[slice][cl] = acc;
  __syncthreads();
  if (slice == 0)
    out[(size_t)gid * D_H + col] =
        sred[0][cl] + sred[1][cl] + sred[2][cl] + sred[3][cl] + b[col];
}

// ---------------- BN over 64 graphs + ReLU ----------------
__global__ __launch_bounds__(256) void bn4_kernel(const float* __restrict__ x,
                                                  const float* __restrict__ gmm,
                                                  const float* __restrict__ bb,
                                                  float* __restrict__ y) {
  int cl = threadIdx.x & 63;
  int slice = threadIdx.x >> 6;
  int c = blockIdx.x * 64 + cl;
  float s = 0.f, q = 0.f;
#pragma unroll
  for (int r = slice * 16; r < slice * 16 + 16; r++) {
    float v = x[(size_t)r * D_H + c];
    s += v; q += v * v;
  }
  __shared__ float ss[4][64], sq[4][64];
  ss[slice][cl] = s;
  sq[slice][cl] = q;
  __syncthreads();
  float S = ss[0][cl] + ss[1][cl] + ss[2][cl] + ss[3][cl];
  float Q = sq[0][cl] + sq[1][cl] + sq[2][cl] + sq[3][cl];
  float mean = S * (1.0f / N_GRAPHS);
  float var = Q * (1.0f / N_GRAPHS) - mean * mean;
  float rs = rsqrtf(var + BN_EPS) * gmm[c];
  float sh = bb[c] - mean * rs;
#pragma unroll
  for (int r = slice * 16; r < slice * 16 + 16; r++)
    y[(size_t)r * D_H + c] = fmaxf(x[(size_t)r * D_H + c] * rs + sh, 0.f);
}

// ---------------- fc2: [64,512] @ [512,2] + b ----------------
__global__ __launch_bounds__(64) void fc2_kernel(const float* __restrict__ y,
                                                 const float* __restrict__ W,
                                                 const float* __restrict__ b,
                                                 float* __restrict__ out) {
  int gid = blockIdx.x;
  int lane = threadIdx.x;
  float a0 = 0.f, a1 = 0.f;
  for (int k = lane; k < D_H; k += 64) {
    float v = y[(size_t)gid * D_H + k];
    a0 += v * W[k * 2 + 0];
    a1 += v * W[k * 2 + 1];
  }
  for (int off = 32; off; off >>= 1) {
    a0 += __shfl_down(a0, off);
    a1 += __shfl_down(a1, off);
  }
  if (lane == 0) {
    out[gid * 2 + 0] = a0 + b[0];
    out[gid * 2 + 1] = a1 + b[1];
  }
}

extern "C" void kernel_launch(void* const* d_in, const int* in_sizes, int n_in,
                              void* d_out, int out_size, void* d_ws, size_t ws_size,
                              hipStream_t stream) {
  const float* x       = (const float*)d_in[0];
  const float* W0      = (const float*)d_in[1];
  const float* Wrest   = (const float*)d_in[2];
  const float* bconv   = (const float*)d_in[3];
  const float* p       = (const float*)d_in[4];
  const float* mscale  = (const float*)d_in[5];
  const float* bn_g    = (const float*)d_in[6];
  const float* bn_b    = (const float*)d_in[7];
  const float* fc1_W   = (const float*)d_in[8];
  const float* fc1_b   = (const float*)d_in[9];
  const float* bn4_g   = (const float*)d_in[10];
  const float* bn4_b   = (const float*)d_in[11];
  const float* fc2_W   = (const float*)d_in[12];
  const float* fc2_b   = (const float*)d_in[13];
  const int*   eidx    = (const int*)d_in[14];
  const int*   batch   = (const int*)d_in[15];
  float* out = (float*)d_out;

  const int* src = eidx;
  const int* dst = eidx + N_EDGES;

  float* ws = (float*)d_ws;
  const size_t NH = (size_t)N_NODES * D_H;
  float* hlin  = ws;
  float* jk    = hlin + NH;
  float* stats = jk + NH;                          // 1024
  float* aff   = stats + 1024;                     // 1024
  __hip_bfloat16* residb = (__hip_bfloat16*)(aff + 1024);    // [M_PAD][512] bf16
  __hip_bfloat16* msgb = residb + (size_t)M_PAD * D_H;       // [N_NODES][512] bf16
  __hip_bfloat16* w0t = msgb + NH;
  __hip_bfloat16* w1t = w0t + 512 * 128;
  __hip_bfloat16* w2t = w1t + 512 * 512;
  int* cnt     = (int*)(w2t + 512 * 512);
  int* rowptr  = cnt + N_NODES;
  int* csr_src = rowptr + N_NODES + 1;
  float* g     = (float*)(csr_src + N_EDGES);
  float* g2lin = g + 64 * 1024;
  float* g2    = g2lin + 64 * D_H;

  // ---- weights (bf16, transposed) + cnt/stats zero, one dispatch ----
  convert_all<<<dim3(16, 16, 3), 256, 0, stream>>>(W0, Wrest, w0t, w1t, w2t, cnt, stats);

  // ---- build CSR (scan zeroes cnt for scatter's cursor) ----
  hist_kernel<<<(N_EDGES + 255) / 256, 256, 0, stream>>>(dst, cnt);
  scan_kernel<<<1, 256, 0, stream>>>(cnt, rowptr);
  scatter_kernel<<<(N_EDGES + 255) / 256, 256, 0, stream>>>(src, dst, rowptr, cnt, csr_src);

  // ---- layer-0 message table ----
  msg0_kernel<<<1280, 256, 0, stream>>>(x, p, msgb);

  for (int layer = 0; layer < 3; layer++) {
    if (layer == 0)
      agg_msgnorm_kernel<D_INPUT, false><<<N_NODES, 256, 0, stream>>>(
          x, nullptr, msgb, rowptr, csr_src, p + layer, mscale + layer, residb);
    else
      agg_msgnorm_kernel<D_H, true><<<N_NODES, 256, 0, stream>>>(
          hlin, aff, msgb, rowptr, csr_src, p + layer, mscale + layer, residb);
    const __hip_bfloat16* Wt = (layer == 0) ? w0t : (layer == 1 ? w1t : w2t);
    int K = (layer == 0) ? D_INPUT : D_H;
    mfma_gemm<<<dim3(M_PAD / 128, D_H / 128), 256, 0, stream>>>(
        residb, Wt, bconv + (size_t)layer * D_H, hlin, stats, N_NODES, K);
    bn_affine<<<1, 512, 0, stream>>>(stats, bn_g + (size_t)layer * D_H,
                                     bn_b + (size_t)layer * D_H, aff);
    if (layer < 2)
      jk_msg_update<true><<<2048, 256, 0, stream>>>(hlin, aff, jk, p + layer + 1, msgb, layer);
    else
      jk_msg_update<false><<<2048, 256, 0, stream>>>(hlin, aff, jk, nullptr, nullptr, layer);
  }

  pool_kernel<<<dim3(N_GRAPHS, 8), 256, 0, stream>>>(jk, batch, g);
  fc1_kernel<<<dim3(N_GRAPHS, 8), 256, 0, stream>>>(g, fc1_W, fc1_b, g2lin);
  bn4_kernel<<<8, 256, 0, stream>>>(g2lin, bn4_g, bn4_b, g2);
  fc2_kernel<<<N_GRAPHS, 64, 0, stream>>>(g2, fc2_W, fc2_b, out);
}

// Round 10
// 243.917 us; speedup vs baseline: 12.1899x; 1.0491x over previous
//
#include <hip/hip_runtime.h>
#include <hip/hip_bf16.h>
#include <math.h>

#define N_NODES 10000
#define N_GRAPHS 64
#define N_EDGES 160000
#define D_INPUT 128
#define D_H 512
#define EPS 1e-7f
#define MAXV 10.0f
#define BN_EPS 1e-5f
#define M_PAD 10112  // 79 * 128

typedef __attribute__((ext_vector_type(4))) float f32x4;
typedef __attribute__((ext_vector_type(8))) __bf16 bf16x8;

// ================= fused hist + layer-0 msg table =================
__global__ __launch_bounds__(256) void hist_msg0(const int* __restrict__ dst,
                                                 int* __restrict__ cnt,
                                                 const float* __restrict__ x,
                                                 const float* __restrict__ p_ptr,
                                                 __hip_bfloat16* __restrict__ msgb) {
  int bid = blockIdx.x;
  int tid = threadIdx.x;
  if (bid < 625) {  // 625*256 == N_EDGES
    atomicAdd(&cnt[dst[bid * 256 + tid]], 1);
    return;
  }
  float p = *p_ptr;
  bool p1 = (p == 1.0f);
  const int total = N_NODES * D_INPUT / 2;  // 640000 float2
  for (int i = (bid - 625) * 256 + tid; i < total; i += 320000) {
    float2 v = ((const float2*)x)[i];
    float m0 = fminf(fmaxf(v.x, 0.f) + EPS, MAXV);
    float m1 = fminf(fmaxf(v.y, 0.f) + EPS, MAXV);
    if (!p1) { m0 = powf(m0, p); m1 = powf(m1, p); }
    __hip_bfloat162 o;
    o.x = __float2bfloat16(m0);
    o.y = __float2bfloat16(m1);
    ((__hip_bfloat162*)msgb)[i] = o;
  }
}

// single-block scan; reads cnt via int4, writes rowptr via int4, zeroes cnt
__global__ __launch_bounds__(256) void scan_kernel(int* __restrict__ cnt,
                                                   int* __restrict__ rowptr) {
  __shared__ int ps[256];
  int tid = threadIdx.x;
  const int CH = 40;
  int b0 = tid * CH;
  bool active = (b0 < N_NODES);
  int v[CH];
  int s = 0;
  if (active) {
    const int4* c4p = (const int4*)(cnt + b0);
#pragma unroll
    for (int i = 0; i < CH / 4; i++) {
      int4 q = c4p[i];
      v[4 * i] = q.x; v[4 * i + 1] = q.y; v[4 * i + 2] = q.z; v[4 * i + 3] = q.w;
      s += q.x + q.y + q.z + q.w;
    }
  }
  ps[tid] = s;
  __syncthreads();
  for (int off = 1; off < 256; off <<= 1) {
    int t = (tid >= off) ? ps[tid - off] : 0;
    __syncthreads();
    ps[tid] += t;
    __syncthreads();
  }
  int run = (tid == 0) ? 0 : ps[tid - 1];
  if (active) {
    int r[CH];
#pragma unroll
    for (int i = 0; i < CH; i++) { r[i] = run; run += v[i]; }
    int4* rp = (int4*)(rowptr + b0);
    int4* cz = (int4*)(cnt + b0);
#pragma unroll
    for (int i = 0; i < CH / 4; i++) {
      rp[i] = make_int4(r[4 * i], r[4 * i + 1], r[4 * i + 2], r[4 * i + 3]);
      cz[i] = make_int4(0, 0, 0, 0);
    }
  }
  if (tid == 255) rowptr[N_NODES] = ps[255];
}

__global__ __launch_bounds__(256) void scatter_kernel(
    const int* __restrict__ src, const int* __restrict__ dst,
    const int* __restrict__ rowptr, int* __restrict__ cursor,
    int* __restrict__ csr_src) {
  int i = blockIdx.x * blockDim.x + threadIdx.x;
  if (i < N_EDGES) {
    int t = dst[i];
    int pos = rowptr[t] + atomicAdd(&cursor[t], 1);
    csr_src[pos] = src[i];
  }
}

// ============ fused: CSR aggregation (bf16 msg table, 4B gather) + power-mean
//              + MessageNorm + residual (bf16 out) ============
template <int D, bool BN>
__global__ __launch_bounds__(256) void agg_msgnorm_kernel(
    const float* __restrict__ h, const float* __restrict__ aff,
    const __hip_bfloat16* __restrict__ msgb,
    const int* __restrict__ rowptr, const int* __restrict__ csr_src,
    const float* __restrict__ p_ptr, const float* __restrict__ scale_ptr,
    __hip_bfloat16* __restrict__ out) {
  constexpr int C = D / 2;
  constexpr int SL = 256 / C;
  int n = blockIdx.x;
  int tid = threadIdx.x;
  int col = tid % C;
  int slice = tid / C;
  int lo = rowptr[n], hi = rowptr[n + 1];
  float p = *p_ptr;
  float scale = *scale_ptr;
  bool p1 = (p == 1.0f);
  float invp = 1.0f / p;
  float inv_dg = 1.0f / fmaxf((float)(hi - lo), 1.0f);
  const float2* h2 = (const float2*)h;
  const uint* mg = (const uint*)msgb;

  __shared__ int s_src[256];
  float accx = 0.f, accy = 0.f;
  for (int base = lo; base < hi; base += 256) {
    int m = min(256, hi - base);
    __syncthreads();
    if (tid < m) s_src[tid] = csr_src[base + tid];
    __syncthreads();
    int j = slice;
    for (; j + 3 * SL < m; j += 4 * SL) {
      uint u0 = mg[(size_t)s_src[j] * C + col];
      uint u1 = mg[(size_t)s_src[j + SL] * C + col];
      uint u2 = mg[(size_t)s_src[j + 2 * SL] * C + col];
      uint u3 = mg[(size_t)s_src[j + 3 * SL] * C + col];
      accx += (__uint_as_float(u0 << 16) + __uint_as_float(u1 << 16)) +
              (__uint_as_float(u2 << 16) + __uint_as_float(u3 << 16));
      accy += (__uint_as_float(u0 & 0xFFFF0000u) + __uint_as_float(u1 & 0xFFFF0000u)) +
              (__uint_as_float(u2 & 0xFFFF0000u) + __uint_as_float(u3 & 0xFFFF0000u));
    }
    for (; j < m; j += SL) {
      uint u = mg[(size_t)s_src[j] * C + col];
      accx += __uint_as_float(u << 16);
      accy += __uint_as_float(u & 0xFFFF0000u);
    }
  }

  if constexpr (SL > 1) {
    __shared__ float sacc[2][256];
    sacc[0][tid] = accx;
    sacc[1][tid] = accy;
    __syncthreads();
    if (tid < C) {
#pragma unroll
      for (int s = 1; s < SL; s++) {
        accx += sacc[0][s * C + tid];
        accy += sacc[1][s * C + tid];
      }
    }
  }

  float a0 = 0.f, a1 = 0.f, hv0 = 0.f, hv1 = 0.f, sa = 0.f, sh = 0.f;
  if (tid < C) {
    a0 = fminf(fmaxf(accx * inv_dg, EPS), MAXV);
    a1 = fminf(fmaxf(accy * inv_dg, EPS), MAXV);
    if (!p1) { a0 = powf(a0, invp); a1 = powf(a1, invp); }
    float2 hx = h2[(size_t)n * C + tid];
    if constexpr (BN) {
      float2 s2 = ((const float2*)aff)[tid];
      float2 b2 = ((const float2*)(aff + D_H))[tid];
      hx.x = fmaxf(hx.x * s2.x + b2.x, 0.f);
      hx.y = fmaxf(hx.y * s2.y + b2.y, 0.f);
    }
    hv0 = hx.x;
    hv1 = hx.y;
    sa = a0 * a0 + a1 * a1;
    sh = hv0 * hv0 + hv1 * hv1;
  }
  for (int off = 32; off; off >>= 1) {
    sa += __shfl_down(sa, off);
    sh += __shfl_down(sh, off);
  }
  __shared__ float red[2][4];
  __shared__ float tot[2];
  int wid = tid >> 6;
  if ((tid & 63) == 0) { red[0][wid] = sa; red[1][wid] = sh; }
  __syncthreads();
  if (tid == 0) {
    tot[0] = red[0][0] + red[0][1] + red[0][2] + red[0][3];
    tot[1] = red[1][0] + red[1][1] + red[1][2] + red[1][3];
  }
  __syncthreads();
  float k = sqrtf(tot[1]) * scale / fmaxf(sqrtf(tot[0]), 1e-12f);
  if (tid < C) {
    __hip_bfloat162 o2;
    o2.x = __float2bfloat16(hv0 + a0 * k);
    o2.y = __float2bfloat16(hv1 + a1 * k);
    ((__hip_bfloat162*)out)[(size_t)n * C + tid] = o2;
  }
}

// ============ weight convert+transpose (3 mats) + zero {cnt, stats x3, stats4, g} ============
__global__ __launch_bounds__(256) void convert_all(
    const float* __restrict__ W0, const float* __restrict__ Wrest,
    __hip_bfloat16* __restrict__ w0t, __hip_bfloat16* __restrict__ w1t,
    __hip_bfloat16* __restrict__ w2t, int* __restrict__ cnt,
    float* __restrict__ stats, float* __restrict__ stats4,
    float* __restrict__ g) {
  int z = blockIdx.z;
  const float* W;
  __hip_bfloat16* Wt;
  int K;
  if (z == 0) { W = W0; Wt = w0t; K = D_INPUT; }
  else if (z == 1) { W = Wrest; Wt = w1t; K = D_H; }
  else { W = Wrest + (size_t)D_H * D_H; Wt = w2t; K = D_H; }

  if (z == 0 && blockIdx.x >= 4) {
    // spare: zero cnt[10000] + stats[3072] + stats4[1024] + g[65536]
    int base = ((blockIdx.x - 4) * 16 + blockIdx.y) * 256 + threadIdx.x;  // 0..49151
    const int TOT = 10000 + 3072 + 1024 + 65536;                          // 79632
    for (int e = base; e < TOT; e += 49152) {
      if (e < 10000) cnt[e] = 0;
      else {
        int f = e - 10000;
        if (f < 3072) stats[f] = 0.f;
        else if (f < 4096) stats4[f - 3072] = 0.f;
        else g[f - 4096] = 0.f;
      }
    }
    return;
  }

  __shared__ float tile[32][33];
  int k0 = blockIdx.x * 32, n0 = blockIdx.y * 32;
  int tx = threadIdx.x & 31, ty = threadIdx.x >> 5;
  for (int i = ty; i < 32; i += 8)
    tile[i][tx] = W[(size_t)(k0 + i) * D_H + n0 + tx];
  __syncthreads();
  for (int i = ty; i < 32; i += 8)
    Wt[(size_t)(n0 + i) * K + k0 + tx] = __float2bfloat16(tile[tx][i]);
}

// ============ MFMA bf16 GEMM + fused column stats ============
__global__ __launch_bounds__(256) void mfma_gemm(
    const __hip_bfloat16* __restrict__ A, const __hip_bfloat16* __restrict__ Bt,
    const float* __restrict__ bias, float* __restrict__ C, float* __restrict__ stats,
    int M, int K) {
  __shared__ ushort As[128 * 64];
  __shared__ ushort Bs[128 * 64];
  __shared__ float sred[128][2];
  int tid = threadIdx.x;
  int l = tid & 63;
  int w = tid >> 6;
  int wm = w >> 1, wn = w & 1;
  int row0 = blockIdx.x * 128;
  int col0 = blockIdx.y * 128;

  f32x4 acc[4][4];
#pragma unroll
  for (int m = 0; m < 4; m++)
#pragma unroll
    for (int n = 0; n < 4; n++) acc[m][n] = (f32x4){0.f, 0.f, 0.f, 0.f};

  const ushort* Ag = (const ushort*)A;
  const ushort* Bg = (const ushort*)Bt;
  char* AsB = (char*)As;
  char* BsB = (char*)Bs;

  if (tid < 128) { sred[tid][0] = 0.f; sred[tid][1] = 0.f; }

  int srow = tid >> 3;
  int scb = (tid & 7) * 16;
  int wbyte = scb ^ ((srow & 7) << 4);
  int scol = scb >> 1;

  int lswz = (l & 7) << 4;
  int kb = (l >> 4) * 16;
  int arow = wm * 64 + (l & 15);
  int brow = wn * 64 + (l & 15);

  for (int k0 = 0; k0 < K; k0 += 64) {
    uint4 ra[4], rb[4];
#pragma unroll
    for (int j = 0; j < 4; j++) {
      int row = j * 32 + srow;
      ra[j] = *(const uint4*)(Ag + (size_t)(row0 + row) * K + k0 + scol);
      rb[j] = *(const uint4*)(Bg + (size_t)(col0 + row) * K + k0 + scol);
    }
#pragma unroll
    for (int j = 0; j < 4; j++) {
      int row = j * 32 + srow;
      *(uint4*)(AsB + row * 128 + wbyte) = ra[j];
      *(uint4*)(BsB + row * 128 + wbyte) = rb[j];
    }
    __syncthreads();
#pragma unroll
    for (int kk = 0; kk < 2; kk++) {
      bf16x8 af[4], bfr[4];
#pragma unroll
      for (int m = 0; m < 4; m++)
        af[m] = *(const bf16x8*)(AsB + (arow + m * 16) * 128 + ((kk * 64 + kb) ^ lswz));
#pragma unroll
      for (int n = 0; n < 4; n++)
        bfr[n] = *(const bf16x8*)(BsB + (brow + n * 16) * 128 + ((kk * 64 + kb) ^ lswz));
#pragma unroll
      for (int m = 0; m < 4; m++)
#pragma unroll
        for (int n = 0; n < 4; n++)
          acc[m][n] = __builtin_amdgcn_mfma_f32_16x16x32_bf16(af[m], bfr[n], acc[m][n], 0, 0, 0);
    }
    __syncthreads();
  }

  int crow0 = row0 + wm * 64 + (l >> 4) * 4;
  int ccol0 = col0 + wn * 64 + (l & 15);
#pragma unroll
  for (int n = 0; n < 4; n++) {
    int col = ccol0 + n * 16;
    float bv = bias[col];
    float ps = 0.f, pq = 0.f;
#pragma unroll
    for (int m = 0; m < 4; m++) {
#pragma unroll
      for (int r = 0; r < 4; r++) {
        int rr = crow0 + m * 16 + r;
        if (rr < M) {
          float v = acc[m][n][r] + bv;
          C[(size_t)rr * D_H + col] = v;
          ps += v;
          pq += v * v;
        }
      }
    }
    ps += __shfl_down(ps, 16); pq += __shfl_down(pq, 16);
    ps += __shfl_down(ps, 32); pq += __shfl_down(pq, 32);
    if ((l >> 4) == 0) {
      atomicAdd(&sred[wn * 64 + n * 16 + (l & 15)][0], ps);
      atomicAdd(&sred[wn * 64 + n * 16 + (l & 15)][1], pq);
    }
  }
  __syncthreads();
  if (tid < 128) {
    atomicAdd(&stats[col0 + tid], sred[tid][0]);
    atomicAdd(&stats[D_H + col0 + tid], sred[tid][1]);
  }
}

// ---------------- JK update + next-layer msg table; BN-affine computed inline
//                  from stats; block 0 publishes aff for the next agg ----------------
__global__ __launch_bounds__(256) void jk_msg_update(
    const float* __restrict__ hlin, const float* __restrict__ stats,
    const float* __restrict__ gamma, const float* __restrict__ beta,
    float* __restrict__ jk, const float* __restrict__ p_ptr,
    __hip_bfloat16* __restrict__ msgb, float* __restrict__ aff, int layer) {
  float p = *p_ptr;
  bool p1 = (p == 1.0f);
  const float invN = 1.0f / (float)N_NODES;
  const int total = N_NODES * D_H / 4;
  for (int idx = blockIdx.x * blockDim.x + threadIdx.x; idx < total;
       idx += gridDim.x * blockDim.x) {
    int c4 = idx & 127;
    float4 s4 = ((const float4*)stats)[c4];
    float4 q4 = ((const float4*)(stats + D_H))[c4];
    float4 g4 = ((const float4*)gamma)[c4];
    float4 b4 = ((const float4*)beta)[c4];
    float4 sc, sh;
    {
      float m0 = s4.x * invN, m1 = s4.y * invN, m2 = s4.z * invN, m3 = s4.w * invN;
      sc.x = rsqrtf(q4.x * invN - m0 * m0 + BN_EPS) * g4.x;
      sc.y = rsqrtf(q4.y * invN - m1 * m1 + BN_EPS) * g4.y;
      sc.z = rsqrtf(q4.z * invN - m2 * m2 + BN_EPS) * g4.z;
      sc.w = rsqrtf(q4.w * invN - m3 * m3 + BN_EPS) * g4.w;
      sh.x = b4.x - m0 * sc.x;
      sh.y = b4.y - m1 * sc.y;
      sh.z = b4.z - m2 * sc.z;
      sh.w = b4.w - m3 * sc.w;
    }
    if (idx < 128) {  // block 0, first pass: publish aff
      ((float4*)aff)[idx] = sc;
      ((float4*)(aff + D_H))[idx] = sh;
    }
    float4 x = ((const float4*)hlin)[idx];
    float4 v;
    v.x = fmaxf(x.x * sc.x + sh.x, 0.f);
    v.y = fmaxf(x.y * sc.y + sh.y, 0.f);
    v.z = fmaxf(x.z * sc.z + sh.z, 0.f);
    v.w = fmaxf(x.w * sc.w + sh.w, 0.f);
    {
      float m0 = fminf(v.x + EPS, MAXV);
      float m1 = fminf(v.y + EPS, MAXV);
      float m2 = fminf(v.z + EPS, MAXV);
      float m3 = fminf(v.w + EPS, MAXV);
      if (!p1) { m0 = powf(m0, p); m1 = powf(m1, p); m2 = powf(m2, p); m3 = powf(m3, p); }
      __hip_bfloat162 o01, o23;
      o01.x = __float2bfloat16(m0); o01.y = __float2bfloat16(m1);
      o23.x = __float2bfloat16(m2); o23.y = __float2bfloat16(m3);
      ((__hip_bfloat162*)msgb)[2 * idx] = o01;
      ((__hip_bfloat162*)msgb)[2 * idx + 1] = o23;
    }
    if (layer != 0) {
      float4 j = ((const float4*)jk)[idx];
      v.x = fmaxf(v.x, j.x);
      v.y = fmaxf(v.y, j.y);
      v.z = fmaxf(v.z, j.z);
      v.w = fmaxf(v.w, j.w);
    }
    ((float4*)jk)[idx] = v;
  }
}

// ---------------- layer-2: BN inline + jk-max + fused per-graph pooling ----------------
// grid (79 row-blocks, 4 col-blocks); block tile 128 rows x 128 cols.
// g layout: g[graph][0..511] = max (as float bits via int atomicMax), [512..1023] = sum.
__global__ __launch_bounds__(256) void jk_pool_kernel(
    const float* __restrict__ hlin, const float* __restrict__ stats,
    const float* __restrict__ gamma, const float* __restrict__ beta,
    const float* __restrict__ jk, const int* __restrict__ batch,
    float* __restrict__ g) {
  int tid = threadIdx.x;
  int f4l = tid & 31;   // 0..31 within col block
  int rs = tid >> 5;    // 0..7 row slice
  int row0 = blockIdx.x * 128;
  int c4 = blockIdx.y * 32 + f4l;  // global float4 col (0..127)

  __shared__ int s_batch[128];
  __shared__ int lmax[4][32][4];
  __shared__ float lsum[4][32][4];
  if (tid < 128) {
    int r = row0 + tid;
    s_batch[tid] = (r < N_NODES) ? batch[r] : -1;
  }
  for (int i = tid; i < 512; i += 256) {
    ((int*)lmax)[i] = 0;
    ((float*)lsum)[i] = 0.f;
  }
  __syncthreads();
  int g_first = s_batch[0];

  // inline BN affine for this thread's 4 columns
  const float invN = 1.0f / (float)N_NODES;
  float4 s4 = ((const float4*)stats)[c4];
  float4 q4 = ((const float4*)(stats + D_H))[c4];
  float4 g4 = ((const float4*)gamma)[c4];
  float4 b4 = ((const float4*)beta)[c4];
  float4 sc, sh;
  {
    float m0 = s4.x * invN, m1 = s4.y * invN, m2 = s4.z * invN, m3 = s4.w * invN;
    sc.x = rsqrtf(q4.x * invN - m0 * m0 + BN_EPS) * g4.x;
    sc.y = rsqrtf(q4.y * invN - m1 * m1 + BN_EPS) * g4.y;
    sc.z = rsqrtf(q4.z * invN - m2 * m2 + BN_EPS) * g4.z;
    sc.w = rsqrtf(q4.w * invN - m3 * m3 + BN_EPS) * g4.w;
    sh.x = b4.x - m0 * sc.x;
    sh.y = b4.y - m1 * sc.y;
    sh.z = b4.z - m2 * sc.z;
    sh.w = b4.w - m3 * sc.w;
  }

  float4 mx = make_float4(0.f, 0.f, 0.f, 0.f);
  float4 sm = make_float4(0.f, 0.f, 0.f, 0.f);
  int cur = -1;

#define FLUSH()                                                              \
  do {                                                                       \
    int slot = cur - g_first;                                                \
    if (slot < 4) {                                                          \
      atomicMax(&lmax[slot][f4l][0], __float_as_int(mx.x));                  \
      atomicMax(&lmax[slot][f4l][1], __float_as_int(mx.y));                  \
      atomicMax(&lmax[slot][f4l][2], __float_as_int(mx.z));                  \
      atomicMax(&lmax[slot][f4l][3], __float_as_int(mx.w));                  \
      atomicAdd(&lsum[slot][f4l][0], sm.x);                                  \
      atomicAdd(&lsum[slot][f4l][1], sm.y);                                  \
      atomicAdd(&lsum[slot][f4l][2], sm.z);                                  \
      atomicAdd(&lsum[slot][f4l][3], sm.w);                                  \
    } else {                                                                 \
      int cb = c4 * 4;                                                       \
      atomicMax((int*)&g[(size_t)cur * 1024 + cb + 0], __float_as_int(mx.x)); \
      atomicMax((int*)&g[(size_t)cur * 1024 + cb + 1], __float_as_int(mx.y)); \
      atomicMax((int*)&g[(size_t)cur * 1024 + cb + 2], __float_as_int(mx.z)); \
      atomicMax((int*)&g[(size_t)cur * 1024 + cb + 3], __float_as_int(mx.w)); \
      atomicAdd(&g[(size_t)cur * 1024 + 512 + cb + 0], sm.x);                \
      atomicAdd(&g[(size_t)cur * 1024 + 512 + cb + 1], sm.y);                \
      atomicAdd(&g[(size_t)cur * 1024 + 512 + cb + 2], sm.z);                \
      atomicAdd(&g[(size_t)cur * 1024 + 512 + cb + 3], sm.w);                \
    }                                                                        \
  } while (0)

  for (int i = 0; i < 16; i++) {
    int r = row0 + rs + i * 8;
    if (r >= N_NODES) break;
    int gg = s_batch[rs + i * 8];
    if (gg != cur) {
      if (cur >= 0) FLUSH();
      cur = gg;
      mx = make_float4(0.f, 0.f, 0.f, 0.f);
      sm = make_float4(0.f, 0.f, 0.f, 0.f);
    }
    float4 x = ((const float4*)hlin)[(size_t)r * 128 + c4];
    float4 j4 = ((const float4*)jk)[(size_t)r * 128 + c4];
    float4 v;
    v.x = fmaxf(fmaxf(x.x * sc.x + sh.x, 0.f), j4.x);
    v.y = fmaxf(fmaxf(x.y * sc.y + sh.y, 0.f), j4.y);
    v.z = fmaxf(fmaxf(x.z * sc.z + sh.z, 0.f), j4.z);
    v.w = fmaxf(fmaxf(x.w * sc.w + sh.w, 0.f), j4.w);
    mx.x = fmaxf(mx.x, v.x); mx.y = fmaxf(mx.y, v.y);
    mx.z = fmaxf(mx.z, v.z); mx.w = fmaxf(mx.w, v.w);
    sm.x += v.x; sm.y += v.y; sm.z += v.z; sm.w += v.w;
  }
  if (cur >= 0) FLUSH();
#undef FLUSH
  __syncthreads();

  // LDS slots -> global
  int last = min(127, N_NODES - 1 - row0);
  int g_last = s_batch[last];
  int ns = min(3, g_last - g_first);
  for (int s = 0; s <= ns; s++) {
    int gi = g_first + s;
    if (tid < 128) {
      int fc = tid >> 2, comp = tid & 3;
      int col = (blockIdx.y * 32 + fc) * 4 + comp;
      atomicMax((int*)&g[(size_t)gi * 1024 + col], lmax[s][fc][comp]);
    } else {
      int t = tid - 128;
      int fc = t >> 2, comp = t & 3;
      int col = (blockIdx.y * 32 + fc) * 4 + comp;
      atomicAdd(&g[(size_t)gi * 1024 + 512 + col], lsum[s][fc][comp]);
    }
  }
}

// ---------------- fc1 (+ fused column stats for bn4) ----------------
__device__ __forceinline__ int lower_bound_i(const int* a, int n, int v) {
  int lo = 0, hi = n;
  while (lo < hi) {
    int mid = (lo + hi) >> 1;
    if (a[mid] < v) lo = mid + 1; else hi = mid;
  }
  return lo;
}

__global__ __launch_bounds__(256) void fc1_kernel(const float* __restrict__ g,
                                                  const int* __restrict__ batch,
                                                  const float* __restrict__ W,
                                                  const float* __restrict__ b,
                                                  float* __restrict__ out,
                                                  float* __restrict__ stats4) {
  __shared__ float sg[1024];
  __shared__ float sred[4][64];
  int gid = blockIdx.x;
  int tid = threadIdx.x;
  int lo = lower_bound_i(batch, N_NODES, gid);
  int hi = lower_bound_i(batch, N_NODES, gid + 1);
  float inv_cnt = 1.0f / fmaxf((float)(hi - lo), 1.0f);
  float4 gv = ((const float4*)(g + (size_t)gid * 1024))[tid];
  if (tid >= 128) {  // mean half: divide sums by count
    gv.x *= inv_cnt; gv.y *= inv_cnt; gv.z *= inv_cnt; gv.w *= inv_cnt;
  }
  ((float4*)sg)[tid] = gv;
  __syncthreads();
  int cl = tid & 63;
  int slice = tid >> 6;
  int col = blockIdx.y * 64 + cl;
  int k0 = slice * 256;
  float acc = 0.f;
#pragma unroll 4
  for (int k = k0; k < k0 + 256; k++) acc += sg[k] * W[(size_t)k * D_H + col];
  sred[slice][cl] = acc;
  __syncthreads();
  if (slice == 0) {
    float v = sred[0][cl] + sred[1][cl] + sred[2][cl] + sred[3][cl] + b[col];
    out[(size_t)gid * D_H + col] = v;
    atomicAdd(&stats4[col], v);
    atomicAdd(&stats4[D_H + col], v * v);
  }
}

// ---------------- fc2 with inline bn4 (stats4) ----------------
__global__ __launch_bounds__(64) void fc2_kernel(const float* __restrict__ y,
                                                 const float* __restrict__ stats4,
                                                 const float* __restrict__ gmm,
                                                 const float* __restrict__ bb,
                                                 const float* __restrict__ W,
                                                 const float* __restrict__ b,
                                                 float* __restrict__ out) {
  int gid = blockIdx.x;
  int lane = threadIdx.x;
  const float invG = 1.0f / (float)N_GRAPHS;
  float a0 = 0.f, a1 = 0.f;
#pragma unroll
  for (int j = 0; j < 8; j++) {
    int k = lane + j * 64;
    float mean = stats4[k] * invG;
    float var = stats4[D_H + k] * invG - mean * mean;
    float sc = rsqrtf(var + BN_EPS) * gmm[k];
    float v = fmaxf(y[(size_t)gid * D_H + k] * sc + bb[k] - mean * sc, 0.f);
    a0 += v * W[k * 2 + 0];
    a1 += v * W[k * 2 + 1];
  }
  for (int off = 32; off; off >>= 1) {
    a0 += __shfl_down(a0, off);
    a1 += __shfl_down(a1, off);
  }
  if (lane == 0) {
    out[gid * 2 + 0] = a0 + b[0];
    out[gid * 2 + 1] = a1 + b[1];
  }
}

extern "C" void kernel_launch(void* const* d_in, const int* in_sizes, int n_in,
                              void* d_out, int out_size, void* d_ws, size_t ws_size,
                              hipStream_t stream) {
  const float* x       = (const float*)d_in[0];
  const float* W0      = (const float*)d_in[1];
  const float* Wrest   = (const float*)d_in[2];
  const float* bconv   = (const float*)d_in[3];
  const float* p       = (const float*)d_in[4];
  const float* mscale  = (const float*)d_in[5];
  const float* bn_g    = (const float*)d_in[6];
  const float* bn_b    = (const float*)d_in[7];
  const float* fc1_W   = (const float*)d_in[8];
  const float* fc1_b   = (const float*)d_in[9];
  const float* bn4_g   = (const float*)d_in[10];
  const float* bn4_b   = (const float*)d_in[11];
  const float* fc2_W   = (const float*)d_in[12];
  const float* fc2_b   = (const float*)d_in[13];
  const int*   eidx    = (const int*)d_in[14];
  const int*   batch   = (const int*)d_in[15];
  float* out = (float*)d_out;

  const int* src = eidx;
  const int* dst = eidx + N_EDGES;

  float* ws = (float*)d_ws;
  const size_t NH = (size_t)N_NODES * D_H;
  float* hlin   = ws;
  float* jk     = hlin + NH;
  float* stats  = jk + NH;            // 3 x 1024
  float* stats4 = stats + 3072;       // 1024
  float* aff    = stats4 + 1024;      // 1024
  __hip_bfloat16* residb = (__hip_bfloat16*)(aff + 1024);   // [M_PAD][512]
  __hip_bfloat16* msgb = residb + (size_t)M_PAD * D_H;      // [N_NODES][512]
  __hip_bfloat16* w0t = msgb + NH;
  __hip_bfloat16* w1t = w0t + 512 * 128;
  __hip_bfloat16* w2t = w1t + 512 * 512;
  int* cnt     = (int*)(w2t + 512 * 512);
  int* rowptr  = cnt + N_NODES;
  int* csr_src = rowptr + N_NODES + 1;
  float* g     = (float*)(csr_src + N_EDGES);   // [64][1024]: max | sum
  float* g2lin = g + 64 * 1024;                 // [64][512]

  // weights + zero {cnt, stats, stats4, g}
  convert_all<<<dim3(16, 16, 3), 256, 0, stream>>>(W0, Wrest, w0t, w1t, w2t,
                                                   cnt, stats, stats4, g);
  // CSR + layer-0 msg table (fused hist+msg0)
  hist_msg0<<<1875, 256, 0, stream>>>(dst, cnt, x, p, msgb);
  scan_kernel<<<1, 256, 0, stream>>>(cnt, rowptr);
  scatter_kernel<<<(N_EDGES + 255) / 256, 256, 0, stream>>>(src, dst, rowptr, cnt, csr_src);

  for (int layer = 0; layer < 3; layer++) {
    if (layer == 0)
      agg_msgnorm_kernel<D_INPUT, false><<<N_NODES, 256, 0, stream>>>(
          x, nullptr, msgb, rowptr, csr_src, p + layer, mscale + layer, residb);
    else
      agg_msgnorm_kernel<D_H, true><<<N_NODES, 256, 0, stream>>>(
          hlin, aff, msgb, rowptr, csr_src, p + layer, mscale + layer, residb);
    const __hip_bfloat16* Wt = (layer == 0) ? w0t : (layer == 1 ? w1t : w2t);
    int K = (layer == 0) ? D_INPUT : D_H;
    float* stats_l = stats + layer * 1024;
    mfma_gemm<<<dim3(M_PAD / 128, D_H / 128), 256, 0, stream>>>(
        residb, Wt, bconv + (size_t)layer * D_H, hlin, stats_l, N_NODES, K);
    if (layer < 2)
      jk_msg_update<<<2048, 256, 0, stream>>>(hlin, stats_l, bn_g + (size_t)layer * D_H,
                                              bn_b + (size_t)layer * D_H, jk,
                                              p + layer + 1, msgb, aff, layer);
    else
      jk_pool_kernel<<<dim3(79, 4), 256, 0, stream>>>(hlin, stats_l,
                                                      bn_g + (size_t)layer * D_H,
                                                      bn_b + (size_t)layer * D_H,
                                                      jk, batch, g);
  }

  fc1_kernel<<<dim3(N_GRAPHS, 8), 256, 0, stream>>>(g, batch, fc1_W, fc1_b, g2lin, stats4);
  fc2_kernel<<<N_GRAPHS, 64, 0, stream>>>(g2lin, stats4, bn4_g, bn4_b, fc2_W, fc2_b, out);
}